// Round 1
// baseline (2150.075 us; speedup 1.0000x reference)
//
#include <hip/hip_runtime.h>
#include <math.h>

// ---------------------------------------------------------------------------
// VQ-VAE forward, fp32 baseline.
// Buffers in d_ws (floats):
//   A   = 33,554,432  (a1 [8,64,256,256] -> later t2)
//   B   =  8,388,608  (a2 [8,64,128,128] -> later t1)
//   C   =  2,097,152  (a3 [8,64,64,64]   -> later d1)
//   Z   = 16,777,216  (z  [8,512,64,64]  -> later z_q in place)
//   cbT =    262,144  (codebook transposed [c][k])
//   cn2 =        512  (0.5*||c_k||^2)
//   idx =     32,768  ints
//   lacc=          1  (loss accumulator)
// ---------------------------------------------------------------------------

// ---- codebook transpose + 0.5*||c||^2 + zero loss accumulator -------------
__global__ __launch_bounds__(64) void k_prep(const float* __restrict__ cb,
    float* __restrict__ cbT, float* __restrict__ cn2, float* __restrict__ lacc)
{
    int k = blockIdx.x;      // 512
    int t = threadIdx.x;     // 64
    float s = 0.f;
#pragma unroll
    for (int i = 0; i < 8; ++i) {
        int c = t + i * 64;
        float v = cb[k * 512 + c];
        cbT[c * 512 + k] = v;
        s = fmaf(v, v, s);
    }
#pragma unroll
    for (int off = 32; off > 0; off >>= 1) s += __shfl_xor(s, off);
    if (t == 0) cn2[k] = 0.5f * s;
    if (k == 0 && t == 0) *lacc = 0.f;
}

// ---- enc conv1: Cin=1, 4x4 s2 p1, ReLU. x[8,1,512,512] -> [8,64,256,256] ---
__global__ __launch_bounds__(256) void k_conv1(const float* __restrict__ x,
    const float* __restrict__ w, const float* __restrict__ b, float* __restrict__ out)
{
    __shared__ float ws[1024];
    __shared__ float bs[64];
    int t = threadIdx.x;
#pragma unroll
    for (int i = 0; i < 4; ++i) ws[t + 256 * i] = w[t + 256 * i];
    if (t < 64) bs[t] = b[t];
    __syncthreads();
    int bx = blockIdx.x;                 // 2048 = 8n * 256 rows
    int n = bx >> 8, oh = bx & 255;
    int ow = t;
    const float* xn = x + (size_t)n * 512 * 512;
    float xv[16];
#pragma unroll
    for (int kh = 0; kh < 4; ++kh) {
        int ih = 2 * oh - 1 + kh;
        bool rok = (unsigned)ih < 512u;
        int ihc = min(max(ih, 0), 511);
#pragma unroll
        for (int kw = 0; kw < 4; ++kw) {
            int iw = 2 * ow - 1 + kw;
            bool ok = rok && ((unsigned)iw < 512u);
            int iwc = min(max(iw, 0), 511);
            float v = xn[ihc * 512 + iwc];
            xv[kh * 4 + kw] = ok ? v : 0.f;
        }
    }
    float* on = out + (((size_t)n * 64) * 256 + oh) * 256 + ow;
    for (int co = 0; co < 64; ++co) {
        float a = bs[co];
#pragma unroll
        for (int q = 0; q < 16; ++q) a = fmaf(xv[q], ws[co * 16 + q], a);
        a = fmaxf(a, 0.f);
        on[(size_t)co * 65536] = a;
    }
}

// ---- generic Cin=64 -> Cout=64, 4x4 s2 p1, ReLU ---------------------------
__global__ __launch_bounds__(256) void k_conv4x4s2(const float* __restrict__ x,
    const float* __restrict__ w, const float* __restrict__ b, float* __restrict__ out,
    int Hin, int Win, int Hout, int Wout, int l2w)
{
    __shared__ float ws[8192];           // [ci][tap][co8]
    int t = threadIdx.x;
    int co0 = blockIdx.y * 8;
    int n = blockIdx.z;
    // co-group weights are contiguous in global ([co][ci][4][4])
    const float* g = w + (size_t)co0 * 1024;
    for (int q = t; q < 8192; q += 256) {
        int j = q >> 10;                 // which co
        int rest = q & 1023;             // ci*16+tap
        ws[rest * 8 + j] = g[q];
    }
    __syncthreads();
    int p = blockIdx.x * 256 + t;
    int ow = p & (Wout - 1), oh = p >> l2w;
    int roff[4], coff[4];
    unsigned rmask = 0, cmask = 0;
#pragma unroll
    for (int kh = 0; kh < 4; ++kh) {
        int ih = 2 * oh - 1 + kh;
        if ((unsigned)ih < (unsigned)Hin) rmask |= (1u << kh);
        roff[kh] = min(max(ih, 0), Hin - 1) * Win;
    }
#pragma unroll
    for (int kw = 0; kw < 4; ++kw) {
        int iw = 2 * ow - 1 + kw;
        if ((unsigned)iw < (unsigned)Win) cmask |= (1u << kw);
        coff[kw] = min(max(iw, 0), Win - 1);
    }
    float acc[8];
#pragma unroll
    for (int j = 0; j < 8; ++j) acc[j] = b[co0 + j];
    const float* xn = x + (size_t)(n * 64) * Hin * Win;
    for (int ci = 0; ci < 64; ++ci) {
        const float* xb = xn + (size_t)ci * Hin * Win;
        const float4* w4 = (const float4*)&ws[ci * 128];
#pragma unroll
        for (int kh = 0; kh < 4; ++kh) {
#pragma unroll
            for (int kw = 0; kw < 4; ++kw) {
                float v = xb[roff[kh] + coff[kw]];
                if (!((rmask >> kh) & (cmask >> kw) & 1u)) v = 0.f;
                float4 wa = w4[(kh * 4 + kw) * 2];
                float4 wb = w4[(kh * 4 + kw) * 2 + 1];
                acc[0] = fmaf(v, wa.x, acc[0]);
                acc[1] = fmaf(v, wa.y, acc[1]);
                acc[2] = fmaf(v, wa.z, acc[2]);
                acc[3] = fmaf(v, wa.w, acc[3]);
                acc[4] = fmaf(v, wb.x, acc[4]);
                acc[5] = fmaf(v, wb.y, acc[5]);
                acc[6] = fmaf(v, wb.z, acc[6]);
                acc[7] = fmaf(v, wb.w, acc[7]);
            }
        }
    }
    size_t HW = (size_t)Hout * Wout;
    float* on = out + (size_t)(n * 64 + co0) * HW + p;
#pragma unroll
    for (int j = 0; j < 8; ++j) on[j * HW] = fmaxf(acc[j], 0.f);
}

// ---- 3x3 s1 p1 conv on 64x64 spatial, Cin in {64,512}, chunked by 64 -------
__global__ __launch_bounds__(256) void k_conv3x3(const float* __restrict__ x,
    const float* __restrict__ w, const float* __restrict__ b, float* __restrict__ out,
    int Cin, int relu)
{
    __shared__ float ws[4608];           // [ci64][tap9][co8]
    int t = threadIdx.x;
    int co0 = blockIdx.y * 8;
    int Cout = gridDim.y * 8;
    int n = blockIdx.z;
    int p = blockIdx.x * 256 + t;
    int ow = p & 63, oh = p >> 6;
    int roff[3], coff[3];
    unsigned rmask = 0, cmask = 0;
#pragma unroll
    for (int kh = 0; kh < 3; ++kh) {
        int ih = oh - 1 + kh;
        if ((unsigned)ih < 64u) rmask |= (1u << kh);
        roff[kh] = min(max(ih, 0), 63) * 64;
    }
#pragma unroll
    for (int kw = 0; kw < 3; ++kw) {
        int iw = ow - 1 + kw;
        if ((unsigned)iw < 64u) cmask |= (1u << kw);
        coff[kw] = min(max(iw, 0), 63);
    }
    float acc[8];
#pragma unroll
    for (int j = 0; j < 8; ++j) acc[j] = b[co0 + j];
    int nchunk = Cin >> 6;
    for (int cc = 0; cc < nchunk; ++cc) {
        __syncthreads();
        for (int q = t; q < 4608; q += 256) {
            int j = q / 576;
            int rem = q - j * 576;       // ci*9+tap
            ws[rem * 8 + j] = w[(size_t)(co0 + j) * Cin * 9 + cc * 576 + rem];
        }
        __syncthreads();
        const float* xb = x + ((size_t)n * Cin + cc * 64) * 4096;
        for (int ci = 0; ci < 64; ++ci) {
            const float* xc = xb + ci * 4096;
            const float* wt = &ws[ci * 72];
#pragma unroll
            for (int kh = 0; kh < 3; ++kh) {
#pragma unroll
                for (int kw = 0; kw < 3; ++kw) {
                    float v = xc[roff[kh] + coff[kw]];
                    if (!((rmask >> kh) & (cmask >> kw) & 1u)) v = 0.f;
                    const float4 wa = *(const float4*)&wt[(kh * 3 + kw) * 8];
                    const float4 wb = *(const float4*)&wt[(kh * 3 + kw) * 8 + 4];
                    acc[0] = fmaf(v, wa.x, acc[0]);
                    acc[1] = fmaf(v, wa.y, acc[1]);
                    acc[2] = fmaf(v, wa.z, acc[2]);
                    acc[3] = fmaf(v, wa.w, acc[3]);
                    acc[4] = fmaf(v, wb.x, acc[4]);
                    acc[5] = fmaf(v, wb.y, acc[5]);
                    acc[6] = fmaf(v, wb.z, acc[6]);
                    acc[7] = fmaf(v, wb.w, acc[7]);
                }
            }
        }
    }
    float* on = out + ((size_t)n * Cout + co0) * 4096 + p;
#pragma unroll
    for (int j = 0; j < 8; ++j) {
        float a = acc[j];
        if (relu) a = fmaxf(a, 0.f);
        on[(size_t)j * 4096] = a;
    }
}

// ---- VQ: per 16 z-rows, argmax(z.c - 0.5||c||^2) + loss --------------------
__global__ __launch_bounds__(256) void k_vq(const float* __restrict__ z,
    const float* __restrict__ cb, const float* __restrict__ cbT,
    const float* __restrict__ cn2, int* __restrict__ idx, float* __restrict__ lacc)
{
    __shared__ float zs[16][516];
    __shared__ float pval[16][4];
    __shared__ int   pk[16][4];
    __shared__ int   bestk[16];
    __shared__ float lred[4];
    int t = threadIdx.x;
    int row0 = blockIdx.x * 16;
    int n = row0 >> 12;
    int sp0 = row0 & 4095;
    const float* zn = z + (size_t)n * 512 * 4096 + sp0;
    int rr = t & 15, ccol = t >> 4;
#pragma unroll 4
    for (int i = 0; i < 32; ++i) {
        int c = i * 16 + ccol;
        zs[rr][c] = zn[(size_t)c * 4096 + rr];
    }
    __syncthreads();
    int k0 = t, k1 = t + 256;
    float s0[16], s1[16];
    {
        float c0 = cn2[k0], c1 = cn2[k1];
#pragma unroll
        for (int r = 0; r < 16; ++r) { s0[r] = -c0; s1[r] = -c1; }
    }
    for (int c = 0; c < 512; c += 4) {
        float a0 = cbT[(size_t)(c + 0) * 512 + k0];
        float a1 = cbT[(size_t)(c + 1) * 512 + k0];
        float a2 = cbT[(size_t)(c + 2) * 512 + k0];
        float a3 = cbT[(size_t)(c + 3) * 512 + k0];
        float b0 = cbT[(size_t)(c + 0) * 512 + k1];
        float b1 = cbT[(size_t)(c + 1) * 512 + k1];
        float b2 = cbT[(size_t)(c + 2) * 512 + k1];
        float b3 = cbT[(size_t)(c + 3) * 512 + k1];
#pragma unroll
        for (int r = 0; r < 16; ++r) {
            float4 z4 = *(const float4*)&zs[r][c];
            s0[r] = fmaf(z4.x, a0, fmaf(z4.y, a1, fmaf(z4.z, a2, fmaf(z4.w, a3, s0[r]))));
            s1[r] = fmaf(z4.x, b0, fmaf(z4.y, b1, fmaf(z4.z, b2, fmaf(z4.w, b3, s1[r]))));
        }
    }
    int lane = t & 63, wv = t >> 6;
#pragma unroll
    for (int r = 0; r < 16; ++r) {
        float v = s0[r]; int k = k0;
        if (s1[r] > v) { v = s1[r]; k = k1; }       // k1 > k0, tie keeps k0
#pragma unroll
        for (int off = 32; off > 0; off >>= 1) {
            float ov = __shfl_xor(v, off);
            int   ok_ = __shfl_xor(k, off);
            if (ov > v || (ov == v && ok_ < k)) { v = ov; k = ok_; }
        }
        if (lane == 0) { pval[r][wv] = v; pk[r][wv] = k; }
    }
    __syncthreads();
    if (t < 16) {
        float v = pval[t][0]; int k = pk[t][0];
#pragma unroll
        for (int w2 = 1; w2 < 4; ++w2) {
            float ov = pval[t][w2]; int ok_ = pk[t][w2];
            if (ov > v || (ov == v && ok_ < k)) { v = ov; k = ok_; }
        }
        bestk[t] = k;
        idx[row0 + t] = k;
    }
    __syncthreads();
    float lsum = 0.f;
#pragma unroll
    for (int r = 0; r < 16; ++r) {
        int bk = bestk[r];
        float d1 = zs[r][t]       - cb[(size_t)bk * 512 + t];
        float d2 = zs[r][t + 256] - cb[(size_t)bk * 512 + t + 256];
        lsum = fmaf(d1, d1, fmaf(d2, d2, lsum));
    }
#pragma unroll
    for (int off = 32; off > 0; off >>= 1) lsum += __shfl_xor(lsum, off);
    if (lane == 0) lred[wv] = lsum;
    __syncthreads();
    if (t == 0) atomicAdd(lacc, lred[0] + lred[1] + lred[2] + lred[3]);
}

// ---- gather z_q (in place over z) -----------------------------------------
__global__ __launch_bounds__(256) void k_gather(const int* __restrict__ idx,
    const float* __restrict__ cb, float* __restrict__ z)
{
    int sp = blockIdx.x * 256 + threadIdx.x;   // 32768
    int n = sp >> 12, hw = sp & 4095;
    int k = idx[sp];
    const float* cr = cb + (size_t)k * 512;
    float* zp = z + (size_t)n * 512 * 4096 + hw;
    for (int c = 0; c < 512; ++c) zp[(size_t)c * 4096] = cr[c];
}

// ---- conv-transpose 4x4 s2 p1, Cin=64 -> Cout=64, ReLU (gather form) -------
__global__ __launch_bounds__(256) void k_convt(const float* __restrict__ x,
    const float* __restrict__ w, const float* __restrict__ b, float* __restrict__ out,
    int Hin, int Win, int Hout, int Wout, int l2w)
{
    __shared__ float ws[8192];           // [ci][kh*4+kw][co8]
    int t = threadIdx.x;
    int co0 = blockIdx.y * 8;
    int n = blockIdx.z;
    for (int q = t; q < 8192; q += 256) {
        int ci = q >> 7;
        int rest = q & 127;              // j*16 + tap
        int j = rest >> 4, tap = rest & 15;
        ws[((ci * 16 + tap) * 8) + j] = w[((size_t)(ci * 64) + co0) * 16 + rest];
    }
    __syncthreads();
    int p = blockIdx.x * 256 + t;
    int ow = p & (Wout - 1), oh = p >> l2w;
    int ihA = (oh + 1) >> 1, khA = (oh + 1) & 1;
    int ihB = ihA - 1,       khB = khA + 2;
    int iwA = (ow + 1) >> 1, kwA = (ow + 1) & 1;
    int iwB = iwA - 1,       kwB = kwA + 2;
    bool rAok = ihA < Hin, rBok = ihB >= 0;
    bool cAok = iwA < Win, cBok = iwB >= 0;
    int rA = min(ihA, Hin - 1) * Win, rB = max(ihB, 0) * Win;
    int cA = min(iwA, Win - 1),       cB = max(iwB, 0);
    int tAA = khA * 4 + kwA, tAB = khA * 4 + kwB;
    int tBA = khB * 4 + kwA, tBB = khB * 4 + kwB;
    float acc[8];
#pragma unroll
    for (int j = 0; j < 8; ++j) acc[j] = b[co0 + j];
    const float* xn = x + (size_t)(n * 64) * Hin * Win;
    for (int ci = 0; ci < 64; ++ci) {
        const float* xb = xn + (size_t)ci * Hin * Win;
        float vAA = xb[rA + cA]; if (!(rAok & cAok)) vAA = 0.f;
        float vAB = xb[rA + cB]; if (!(rAok & cBok)) vAB = 0.f;
        float vBA = xb[rB + cA]; if (!(rBok & cAok)) vBA = 0.f;
        float vBB = xb[rB + cB]; if (!(rBok & cBok)) vBB = 0.f;
        const float4* w4 = (const float4*)&ws[ci * 128];
#pragma unroll
        for (int hlf = 0; hlf < 1; ++hlf) { } // keep structure flat
        {
            float4 wa = w4[tAA * 2], wb = w4[tAA * 2 + 1];
            acc[0] = fmaf(vAA, wa.x, acc[0]); acc[1] = fmaf(vAA, wa.y, acc[1]);
            acc[2] = fmaf(vAA, wa.z, acc[2]); acc[3] = fmaf(vAA, wa.w, acc[3]);
            acc[4] = fmaf(vAA, wb.x, acc[4]); acc[5] = fmaf(vAA, wb.y, acc[5]);
            acc[6] = fmaf(vAA, wb.z, acc[6]); acc[7] = fmaf(vAA, wb.w, acc[7]);
        }
        {
            float4 wa = w4[tAB * 2], wb = w4[tAB * 2 + 1];
            acc[0] = fmaf(vAB, wa.x, acc[0]); acc[1] = fmaf(vAB, wa.y, acc[1]);
            acc[2] = fmaf(vAB, wa.z, acc[2]); acc[3] = fmaf(vAB, wa.w, acc[3]);
            acc[4] = fmaf(vAB, wb.x, acc[4]); acc[5] = fmaf(vAB, wb.y, acc[5]);
            acc[6] = fmaf(vAB, wb.z, acc[6]); acc[7] = fmaf(vAB, wb.w, acc[7]);
        }
        {
            float4 wa = w4[tBA * 2], wb = w4[tBA * 2 + 1];
            acc[0] = fmaf(vBA, wa.x, acc[0]); acc[1] = fmaf(vBA, wa.y, acc[1]);
            acc[2] = fmaf(vBA, wa.z, acc[2]); acc[3] = fmaf(vBA, wa.w, acc[3]);
            acc[4] = fmaf(vBA, wb.x, acc[4]); acc[5] = fmaf(vBA, wb.y, acc[5]);
            acc[6] = fmaf(vBA, wb.z, acc[6]); acc[7] = fmaf(vBA, wb.w, acc[7]);
        }
        {
            float4 wa = w4[tBB * 2], wb = w4[tBB * 2 + 1];
            acc[0] = fmaf(vBB, wa.x, acc[0]); acc[1] = fmaf(vBB, wa.y, acc[1]);
            acc[2] = fmaf(vBB, wa.z, acc[2]); acc[3] = fmaf(vBB, wa.w, acc[3]);
            acc[4] = fmaf(vBB, wb.x, acc[4]); acc[5] = fmaf(vBB, wb.y, acc[5]);
            acc[6] = fmaf(vBB, wb.z, acc[6]); acc[7] = fmaf(vBB, wb.w, acc[7]);
        }
    }
    size_t HW = (size_t)Hout * Wout;
    float* on = out + (size_t)(n * 64 + co0) * HW + p;
#pragma unroll
    for (int j = 0; j < 8; ++j) on[j * HW] = fmaxf(acc[j], 0.f);
}

// ---- final conv-transpose 64 -> 1, sigmoid, writes d_out -------------------
__global__ __launch_bounds__(256) void k_convt_final(const float* __restrict__ x,
    const float* __restrict__ w, const float* __restrict__ b, float* __restrict__ out)
{
    __shared__ float ws[1024];
    int t = threadIdx.x;
#pragma unroll
    for (int i = 0; i < 4; ++i) ws[t + 256 * i] = w[t + 256 * i];
    __syncthreads();
    int p = blockIdx.x * 256 + t;        // 512*512 per n, grid.x = 1024
    int n = blockIdx.z;
    int ow = p & 511, oh = p >> 9;
    const int Hin = 256, Win = 256;
    int ihA = (oh + 1) >> 1, khA = (oh + 1) & 1;
    int ihB = ihA - 1,       khB = khA + 2;
    int iwA = (ow + 1) >> 1, kwA = (ow + 1) & 1;
    int iwB = iwA - 1,       kwB = kwA + 2;
    bool rAok = ihA < Hin, rBok = ihB >= 0;
    bool cAok = iwA < Win, cBok = iwB >= 0;
    int rA = min(ihA, Hin - 1) * Win, rB = max(ihB, 0) * Win;
    int cA = min(iwA, Win - 1),       cB = max(iwB, 0);
    int tAA = khA * 4 + kwA, tAB = khA * 4 + kwB;
    int tBA = khB * 4 + kwA, tBB = khB * 4 + kwB;
    float a = b[0];
    const float* xn = x + (size_t)(n * 64) * Hin * Win;
    for (int ci = 0; ci < 64; ++ci) {
        const float* xb = xn + (size_t)ci * Hin * Win;
        float vAA = xb[rA + cA]; if (!(rAok & cAok)) vAA = 0.f;
        float vAB = xb[rA + cB]; if (!(rAok & cBok)) vAB = 0.f;
        float vBA = xb[rB + cA]; if (!(rBok & cAok)) vBA = 0.f;
        float vBB = xb[rB + cB]; if (!(rBok & cBok)) vBB = 0.f;
        const float* wt = &ws[ci * 16];
        a = fmaf(vAA, wt[tAA], a);
        a = fmaf(vAB, wt[tAB], a);
        a = fmaf(vBA, wt[tBA], a);
        a = fmaf(vBB, wt[tBB], a);
    }
    out[(size_t)n * 262144 + p] = 1.0f / (1.0f + expf(-a));
}

// ---- finalize loss ---------------------------------------------------------
__global__ void k_loss_final(const float* __restrict__ lacc, float* __restrict__ out)
{
    if (threadIdx.x == 0 && blockIdx.x == 0)
        out[0] = 1.25f * lacc[0] * (1.0f / 16777216.0f);
}

// ---------------------------------------------------------------------------
extern "C" void kernel_launch(void* const* d_in, const int* in_sizes, int n_in,
                              void* d_out, int out_size, void* d_ws, size_t ws_size,
                              hipStream_t stream)
{
    const float* x      = (const float*)d_in[0];
    const float* enc_w1 = (const float*)d_in[1];
    const float* enc_b1 = (const float*)d_in[2];
    const float* enc_w2 = (const float*)d_in[3];
    const float* enc_b2 = (const float*)d_in[4];
    const float* enc_w3 = (const float*)d_in[5];
    const float* enc_b3 = (const float*)d_in[6];
    const float* enc_w4 = (const float*)d_in[7];
    const float* enc_b4 = (const float*)d_in[8];
    const float* cb     = (const float*)d_in[9];
    const float* dec_w1 = (const float*)d_in[10];
    const float* dec_b1 = (const float*)d_in[11];
    const float* tw1    = (const float*)d_in[12];
    const float* tb1    = (const float*)d_in[13];
    const float* tw2    = (const float*)d_in[14];
    const float* tb2    = (const float*)d_in[15];
    const float* tw3    = (const float*)d_in[16];
    const float* tb3    = (const float*)d_in[17];
    float* out = (float*)d_out;

    float* ws   = (float*)d_ws;
    float* A    = ws;                       // 33,554,432
    float* Bb   = A + 33554432;             //  8,388,608
    float* Cc   = Bb + 8388608;             //  2,097,152
    float* Z    = Cc + 2097152;             // 16,777,216
    float* cbT  = Z + 16777216;             //    262,144
    float* cn2  = cbT + 262144;             //        512
    int*   vidx = (int*)(cn2 + 512);        //     32,768
    float* lacc = (float*)(vidx + 32768);   //          1

    k_prep<<<512, 64, 0, stream>>>(cb, cbT, cn2, lacc);
    k_conv1<<<2048, 256, 0, stream>>>(x, enc_w1, enc_b1, A);
    k_conv4x4s2<<<dim3(64, 8, 8), 256, 0, stream>>>(A, enc_w2, enc_b2, Bb, 256, 256, 128, 128, 7);
    k_conv4x4s2<<<dim3(16, 8, 8), 256, 0, stream>>>(Bb, enc_w3, enc_b3, Cc, 128, 128, 64, 64, 6);
    k_conv3x3<<<dim3(16, 64, 8), 256, 0, stream>>>(Cc, enc_w4, enc_b4, Z, 64, 0);
    k_vq<<<2048, 256, 0, stream>>>(Z, cb, cbT, cn2, vidx, lacc);
    k_gather<<<128, 256, 0, stream>>>(vidx, cb, Z);
    k_conv3x3<<<dim3(16, 8, 8), 256, 0, stream>>>(Z, dec_w1, dec_b1, Cc, 512, 1);
    k_convt<<<dim3(64, 8, 8), 256, 0, stream>>>(Cc, tw1, tb1, Bb, 64, 64, 128, 128, 7);
    k_convt<<<dim3(256, 8, 8), 256, 0, stream>>>(Bb, tw2, tb2, A, 128, 128, 256, 256, 8);
    k_convt_final<<<dim3(1024, 1, 8), 256, 0, stream>>>(A, tw3, tb3, out);
    k_loss_final<<<1, 64, 0, stream>>>(lacc, out + 2097152);
}

// Round 2
// 771.312 us; speedup vs baseline: 2.7876x; 2.7876x over previous
//
#include <hip/hip_runtime.h>
#include <math.h>

// ---------------------------------------------------------------------------
// VQ-VAE forward, bf16-MFMA version.
// Activations: NHWC bf16 (ushort), 1-pixel zero halo, pixel stride = C (64/512).
// Conv layers via implicit-GEMM mfma_f32_16x16x32_bf16.
// LDS input staging via global_load_lds(16B) with per-pixel 16B ci-rotation
// (rot = pixel_local & 7 slots) for conflict-free ds_read_b128 B-fragments.
// Weights pre-swizzled to fragment order: wP[(s*4+g)*Cout + co][8], k=s*32+g*8+j,
// k-order = chunk-major, tap-major, ci-inner.
// VQ kept fp32 (argmin robustness), z written dense fp32 [sp][512] by enc4.
// ---------------------------------------------------------------------------

typedef __bf16 bf16x8_t __attribute__((ext_vector_type(8)));
typedef float f32x4_t __attribute__((ext_vector_type(4)));

union FragU { uint4 u; bf16x8_t b; };

__device__ inline f32x4_t mfma16(bf16x8_t a, bf16x8_t b, f32x4_t c) {
    return __builtin_amdgcn_mfma_f32_16x16x32_bf16(a, b, c, 0, 0, 0);
}

__device__ inline void gl_lds16(const unsigned short* g, unsigned short* l) {
    __builtin_amdgcn_global_load_lds((const __attribute__((address_space(1))) void*)g,
                                     (__attribute__((address_space(3))) void*)l, 16, 0, 0);
}

__device__ inline unsigned bf16rne(float f) {
    unsigned u = __float_as_uint(f);
    u += 0x7FFFu + ((u >> 16) & 1u);
    return u >> 16;
}
__device__ inline unsigned pack2(float lo, float hi) {
    return bf16rne(lo) | (bf16rne(hi) << 16);
}
__device__ inline float bl(unsigned u) { return __uint_as_float(u << 16); }
__device__ inline float bh(unsigned u) { return __uint_as_float(u & 0xffff0000u); }

// ---- generic implicit-GEMM conv -------------------------------------------
// Block: 64 co x SPT spatial (one output row), 4 waves = 2 co-halves x 2 sp-halves.
// NR=KH rows staged; SW = conv stride; CIC = ci chunk; NT = 16-wide n-tiles/wave.
template<int NR, int KW_, int SW, int CIC, int SPT, int NT, bool PHASED, bool OUTF32>
__global__ __launch_bounds__(256) void conv_mfma(
    const unsigned short* __restrict__ in, const unsigned short* __restrict__ wp,
    const float* __restrict__ bias, void* __restrict__ outp,
    int Hp, int Wp, int PS, int nchunks, int Cout, int ncog,
    int Hpo, int Wpo, int relu)
{
    constexpr int W_ST = SW * (SPT - 1) + KW_;
    constexpr int SLOTS_PP = CIC / 8;
    constexpr int ROW_SLOTS = W_ST * SLOTS_PP;
    constexpr int SEGS = (ROW_SLOTS + 63) / 64;
    constexpr int KT = NR * KW_;
    constexpr int CSTEPS = CIC / 32;
    __shared__ __align__(16) unsigned short sh[NR * W_ST * CIC];

    int t = threadIdx.x, lane = t & 63, wv = t >> 6;
    int bx = blockIdx.x;
    int ph = 0, pw = 0, owt = bx;
    if (PHASED) { int phs = bx & 3; ph = phs >> 1; pw = phs & 1; owt = bx >> 2; }
    int ohg = blockIdx.y;
    int bz = blockIdx.z; int nb = bz / ncog; int cog = bz % ncog;
    int ow0 = owt * SPT;
    int row0 = SW * ohg + (PHASED ? ph : 0);
    int col0 = SW * ow0 + (PHASED ? pw : 0);
    int coh = wv & 1;
    int sph = wv >> 1;
    int m = lane & 15, g = lane >> 4;

    if (PHASED) wp += (size_t)(ph * 2 + pw) * Cout * KT * CIC;

    f32x4_t acc[2][NT];
#pragma unroll
    for (int a = 0; a < 2; ++a)
#pragma unroll
        for (int u2 = 0; u2 < NT; ++u2) acc[a][u2] = (f32x4_t){0.f, 0.f, 0.f, 0.f};

    for (int ch = 0; ch < nchunks; ++ch) {
        if (ch) __syncthreads();
        // ---- stage NR rows of W_ST pixels x CIC channels, 16B-rotated -----
        for (int u_ = wv; u_ < NR * SEGS; u_ += 4) {
            int r = u_ / SEGS, seg = u_ - r * SEGS;
            int slot = seg * 64 + lane;
            int p = slot / SLOTS_PP;
            int uu = slot & (SLOTS_PP - 1);
            if (p < W_ST) {
                int su = (uu - (p & 7)) & (SLOTS_PP - 1);
                const unsigned short* gsrc = in +
                    (((size_t)nb * Hp + (row0 + r)) * Wp + (col0 + p)) * PS + ch * CIC + su * 8;
                unsigned short* ldst = sh + ((size_t)(r * ROW_SLOTS + seg * 64 + lane)) * 8;
                gl_lds16(gsrc, ldst);
            }
        }
        __syncthreads();
        // ---- K loop -------------------------------------------------------
        int sbase = ch * (KT * CSTEPS);
#pragma unroll
        for (int tap = 0; tap < KT; ++tap) {
            const int r_l = tap / KW_, kwp = tap % KW_;
#pragma unroll
            for (int cs = 0; cs < CSTEPS; ++cs) {
                int s = sbase + tap * CSTEPS + cs;
                const uint4* wr = (const uint4*)wp + (size_t)(s * 4 + g) * Cout + cog * 64 + coh * 32 + m;
                FragU a0, a1;
                a0.u = wr[0];
                a1.u = wr[16];
#pragma unroll
                for (int u2 = 0; u2 < NT; ++u2) {
                    int sp_l = sph * (SPT / 2) + u2 * 16 + m;
                    int p = SW * sp_l + kwp;
                    int off = (cs * 32 + g * 8 + ((p & 7) << 3)) & (CIC - 1);
                    FragU bb;
                    bb.u = *(const uint4*)(sh + (size_t)(r_l * W_ST + p) * CIC + off);
                    acc[0][u2] = mfma16(a0.b, bb.b, acc[0][u2]);
                    acc[1][u2] = mfma16(a1.b, bb.b, acc[1][u2]);
                }
            }
        }
    }
    // ---- epilogue: bias, relu, store --------------------------------------
#pragma unroll
    for (int a = 0; a < 2; ++a) {
        int co = cog * 64 + coh * 32 + a * 16 + g * 4;
        float4 bv = *(const float4*)(bias + co);
#pragma unroll
        for (int u2 = 0; u2 < NT; ++u2) {
            int ow = ow0 + sph * (SPT / 2) + u2 * 16 + m;
            float v0 = acc[a][u2][0] + bv.x;
            float v1 = acc[a][u2][1] + bv.y;
            float v2 = acc[a][u2][2] + bv.z;
            float v3 = acc[a][u2][3] + bv.w;
            if (relu) {
                v0 = fmaxf(v0, 0.f); v1 = fmaxf(v1, 0.f);
                v2 = fmaxf(v2, 0.f); v3 = fmaxf(v3, 0.f);
            }
            if (OUTF32) {
                float* zo = (float*)outp;
                size_t spg = ((size_t)nb * 64 + ohg) * 64 + ow;
                float4 st = {v0, v1, v2, v3};
                *(float4*)(zo + spg * 512 + co) = st;
            } else {
                unsigned short* ob = (unsigned short*)outp;
                int oho = PHASED ? 2 * ohg + ph : ohg;
                int owo = PHASED ? 2 * ow + pw : ow;
                uint2 st = {pack2(v0, v1), pack2(v2, v3)};
                *(uint2*)(ob + (((size_t)nb * Hpo + oho + 1) * Wpo + (owo + 1)) * 64
                          + (coh * 32 + a * 16 + g * 4)) = st;
            }
        }
    }
}

// ---- halo zeroing ----------------------------------------------------------
__global__ __launch_bounds__(256) void k_halo(unsigned short* buf, int Hp, int Wp, int PS)
{
    int per = 2 * Wp + 2 * (Hp - 2);
    int chunks = PS >> 3;
    int total = per * chunks;
    int n = blockIdx.y;
    for (int i = blockIdx.x * 256 + threadIdx.x; i < total; i += gridDim.x * 256) {
        int pix = i / chunks, c = i - pix * chunks;
        int h, w;
        if (pix < Wp) { h = 0; w = pix; }
        else if (pix < 2 * Wp) { h = Hp - 1; w = pix - Wp; }
        else { int q = pix - 2 * Wp; h = 1 + (q >> 1); w = (q & 1) ? (Wp - 1) : 0; }
        uint4 zz = {0, 0, 0, 0};
        *(uint4*)(buf + (((size_t)n * Hp + h) * Wp + w) * PS + c * 8) = zz;
    }
}

// ---- weight prep: conv [co][ci][kh][kw] fp32 -> fragment-order bf16 --------
__global__ __launch_bounds__(256) void k_prep_conv(const float* __restrict__ w,
    unsigned short* __restrict__ o, int Cout, int Cin, int T, int CIC)
{
    int idx = blockIdx.x * 256 + threadIdx.x;
    if (idx >= Cout * Cin * T) return;
    int tap = idx % T; int r = idx / T; int ci = r % Cin; int co = r / Cin;
    int chunk = ci / CIC, cil = ci % CIC;
    int k = chunk * (T * CIC) + tap * CIC + cil;
    int s = k >> 5, g = (k >> 3) & 3, j = k & 7;
    o[((size_t)(s * 4 + g) * Cout + co) * 8 + j] = (unsigned short)bf16rne(w[idx]);
}

// ---- weight prep: convT [ci][co][4][4] -> per-phase 2x2 fragment order -----
__global__ __launch_bounds__(256) void k_prep_wT(const float* __restrict__ w,
    unsigned short* __restrict__ o)
{
    int idx = blockIdx.x * 256 + threadIdx.x;     // 65536
    int ci = idx & 63; int r = idx >> 6;
    int jw = r & 1; r >>= 1;
    int jh = r & 1; r >>= 1;
    int co = r & 63; r >>= 6;
    int pw = r & 1; int ph = (r >> 1) & 1;
    int kh = (1 - ph) + 2 * (1 - jh);
    int kw = (1 - pw) + 2 * (1 - jw);
    int k = (jh * 2 + jw) * 64 + ci;
    int s = k >> 5, g = (k >> 3) & 3, j = k & 7;
    o[(size_t)(ph * 2 + pw) * 16384 + ((size_t)(s * 4 + g) * 64 + co) * 8 + j] =
        (unsigned short)bf16rne(w[((ci * 64 + co) * 4 + kh) * 4 + kw]);
}

// ---- codebook transpose + 0.5*||c||^2 + zero loss accumulator --------------
__global__ __launch_bounds__(64) void k_prep(const float* __restrict__ cb,
    float* __restrict__ cbT, float* __restrict__ cn2, float* __restrict__ lacc)
{
    int k = blockIdx.x; int t = threadIdx.x;
    float s = 0.f;
#pragma unroll
    for (int i = 0; i < 8; ++i) {
        int c = t + i * 64;
        float v = cb[k * 512 + c];
        cbT[c * 512 + k] = v;
        s = fmaf(v, v, s);
    }
#pragma unroll
    for (int off = 32; off > 0; off >>= 1) s += __shfl_xor(s, off);
    if (t == 0) cn2[k] = 0.5f * s;
    if (k == 0 && t == 0) *lacc = 0.f;
}

// ---- enc conv1: Cin=1, 4x4 s2 p1, ReLU -> bf16 NHWC padded ----------------
__global__ __launch_bounds__(256) void k_conv1(const float* __restrict__ x,
    const float* __restrict__ w, const float* __restrict__ b, unsigned short* __restrict__ out)
{
    __shared__ float ws[1024];
    __shared__ float bs[64];
    int t = threadIdx.x;
#pragma unroll
    for (int i = 0; i < 4; ++i) ws[t + 256 * i] = w[t + 256 * i];
    if (t < 64) bs[t] = b[t];
    __syncthreads();
    int oh = blockIdx.x;
    int n = blockIdx.y;
    int ow = t;
    const float* xn = x + (size_t)n * 262144;
    float xv[16];
#pragma unroll
    for (int kh = 0; kh < 4; ++kh) {
        int ih = 2 * oh - 1 + kh;
        bool rok = (unsigned)ih < 512u;
        int ihc = min(max(ih, 0), 511);
#pragma unroll
        for (int kw = 0; kw < 4; ++kw) {
            int iw = 2 * ow - 1 + kw;
            bool ok = rok && ((unsigned)iw < 512u);
            int iwc = min(max(iw, 0), 511);
            float v = xn[ihc * 512 + iwc];
            xv[kh * 4 + kw] = ok ? v : 0.f;
        }
    }
    unsigned short* on = out + (((size_t)n * 258 + oh + 1) * 258 + (ow + 1)) * 64;
    unsigned uo[32];
#pragma unroll
    for (int co2 = 0; co2 < 32; ++co2) {
        float a0 = bs[2 * co2], a1 = bs[2 * co2 + 1];
#pragma unroll
        for (int q = 0; q < 16; ++q) {
            a0 = fmaf(xv[q], ws[(2 * co2) * 16 + q], a0);
            a1 = fmaf(xv[q], ws[(2 * co2 + 1) * 16 + q], a1);
        }
        uo[co2] = pack2(fmaxf(a0, 0.f), fmaxf(a1, 0.f));
    }
#pragma unroll
    for (int i = 0; i < 8; ++i) {
        uint4 st = {uo[4 * i], uo[4 * i + 1], uo[4 * i + 2], uo[4 * i + 3]};
        *(uint4*)(on + i * 8) = st;
    }
}

// ---- VQ: per 16 z-rows, argmax(z.c - 0.5||c||^2) + loss --------------------
__global__ __launch_bounds__(256) void k_vq(const float* __restrict__ z,
    const float* __restrict__ cb, const float* __restrict__ cbT,
    const float* __restrict__ cn2, int* __restrict__ idx, float* __restrict__ lacc)
{
    __shared__ float zs[16][516];
    __shared__ float pval[16][4];
    __shared__ int   pk[16][4];
    __shared__ int   bestk[16];
    __shared__ float lred[4];
    int t = threadIdx.x;
    int row0 = blockIdx.x * 16;
#pragma unroll
    for (int i = 0; i < 8; ++i) {
        int f = i * 256 + t;            // 2048 float4 total
        int r = f >> 7;
        int c4 = f & 127;
        float4 v = *(const float4*)(z + (size_t)(row0 + r) * 512 + c4 * 4);
        *(float4*)&zs[r][c4 * 4] = v;
    }
    __syncthreads();
    int k0 = t, k1 = t + 256;
    float s0[16], s1[16];
    {
        float c0 = cn2[k0], c1 = cn2[k1];
#pragma unroll
        for (int r = 0; r < 16; ++r) { s0[r] = -c0; s1[r] = -c1; }
    }
    for (int c = 0; c < 512; c += 4) {
        float a0 = cbT[(size_t)(c + 0) * 512 + k0];
        float a1 = cbT[(size_t)(c + 1) * 512 + k0];
        float a2 = cbT[(size_t)(c + 2) * 512 + k0];
        float a3 = cbT[(size_t)(c + 3) * 512 + k0];
        float b0 = cbT[(size_t)(c + 0) * 512 + k1];
        float b1 = cbT[(size_t)(c + 1) * 512 + k1];
        float b2 = cbT[(size_t)(c + 2) * 512 + k1];
        float b3 = cbT[(size_t)(c + 3) * 512 + k1];
#pragma unroll
        for (int r = 0; r < 16; ++r) {
            float4 z4 = *(const float4*)&zs[r][c];
            s0[r] = fmaf(z4.x, a0, fmaf(z4.y, a1, fmaf(z4.z, a2, fmaf(z4.w, a3, s0[r]))));
            s1[r] = fmaf(z4.x, b0, fmaf(z4.y, b1, fmaf(z4.z, b2, fmaf(z4.w, b3, s1[r]))));
        }
    }
    int lane = t & 63, wv = t >> 6;
#pragma unroll
    for (int r = 0; r < 16; ++r) {
        float v = s0[r]; int k = k0;
        if (s1[r] > v) { v = s1[r]; k = k1; }
#pragma unroll
        for (int off = 32; off > 0; off >>= 1) {
            float ov = __shfl_xor(v, off);
            int   ok_ = __shfl_xor(k, off);
            if (ov > v || (ov == v && ok_ < k)) { v = ov; k = ok_; }
        }
        if (lane == 0) { pval[r][wv] = v; pk[r][wv] = k; }
    }
    __syncthreads();
    if (t < 16) {
        float v = pval[t][0]; int k = pk[t][0];
#pragma unroll
        for (int w2 = 1; w2 < 4; ++w2) {
            float ov = pval[t][w2]; int ok_ = pk[t][w2];
            if (ov > v || (ov == v && ok_ < k)) { v = ov; k = ok_; }
        }
        bestk[t] = k;
        idx[row0 + t] = k;
    }
    __syncthreads();
    float lsum = 0.f;
#pragma unroll
    for (int r = 0; r < 16; ++r) {
        int bk = bestk[r];
        float d1 = zs[r][t]       - cb[(size_t)bk * 512 + t];
        float d2 = zs[r][t + 256] - cb[(size_t)bk * 512 + t + 256];
        lsum = fmaf(d1, d1, fmaf(d2, d2, lsum));
    }
#pragma unroll
    for (int off = 32; off > 0; off >>= 1) lsum += __shfl_xor(lsum, off);
    if (lane == 0) lred[wv] = lsum;
    __syncthreads();
    if (t == 0) atomicAdd(lacc, lred[0] + lred[1] + lred[2] + lred[3]);
}

// ---- gather z_q -> padded NHWC bf16 [8,66,66,512] --------------------------
__global__ __launch_bounds__(256) void k_gather(const int* __restrict__ idx,
    const float* __restrict__ cb, unsigned short* __restrict__ zq)
{
    int t = threadIdx.x;
    int sp = blockIdx.x * 4 + (t >> 6);
    int lane = t & 63;
    int k = idx[sp];
    int n = sp >> 12, hw = sp & 4095, h = hw >> 6, w = hw & 63;
    const float* src = cb + (size_t)k * 512 + lane * 8;
    unsigned short* dst = zq + (((size_t)n * 66 + h + 1) * 66 + (w + 1)) * 512 + lane * 8;
    float4 v0 = *(const float4*)src, v1 = *(const float4*)(src + 4);
    uint4 st = {pack2(v0.x, v0.y), pack2(v0.z, v0.w), pack2(v1.x, v1.y), pack2(v1.z, v1.w)};
    *(uint4*)dst = st;
}

// ---- final conv-transpose 64 -> 1, sigmoid ---------------------------------
__global__ __launch_bounds__(256) void k_convt_final(const unsigned short* __restrict__ xp,
    const float* __restrict__ w, const float* __restrict__ b, float* __restrict__ out)
{
    __shared__ float ws2[1024];          // [tap][ci]
    int t = threadIdx.x;
#pragma unroll
    for (int i = 0; i < 4; ++i) {
        int q = t + 256 * i;
        ws2[q] = w[((q & 63) * 16) + (q >> 6)];
    }
    __syncthreads();
    int p = blockIdx.x * 256 + t;
    int n = blockIdx.y;
    int ow = p & 511, oh = p >> 9;
    int ihA = (oh + 1) >> 1, khA = (oh + 1) & 1;
    int ihB = ihA - 1,       khB = khA + 2;
    int iwA = (ow + 1) >> 1, kwA = (ow + 1) & 1;
    int iwB = iwA - 1,       kwB = kwA + 2;
    const uint4* pp[4];
    int tt[4];
    pp[0] = (const uint4*)(xp + (((size_t)n * 258 + ihA + 1) * 258 + iwA + 1) * 64); tt[0] = khA * 4 + kwA;
    pp[1] = (const uint4*)(xp + (((size_t)n * 258 + ihA + 1) * 258 + iwB + 1) * 64); tt[1] = khA * 4 + kwB;
    pp[2] = (const uint4*)(xp + (((size_t)n * 258 + ihB + 1) * 258 + iwA + 1) * 64); tt[2] = khB * 4 + kwA;
    pp[3] = (const uint4*)(xp + (((size_t)n * 258 + ihB + 1) * 258 + iwB + 1) * 64); tt[3] = khB * 4 + kwB;
    float a = b[0];
#pragma unroll
    for (int tpix = 0; tpix < 4; ++tpix) {
        const uint4* P = pp[tpix]; int tp = tt[tpix];
#pragma unroll
        for (int c8 = 0; c8 < 8; ++c8) {
            uint4 v = P[c8];
            const float4 w0 = *(const float4*)&ws2[tp * 64 + c8 * 8];
            const float4 w1 = *(const float4*)&ws2[tp * 64 + c8 * 8 + 4];
            a = fmaf(bl(v.x), w0.x, a); a = fmaf(bh(v.x), w0.y, a);
            a = fmaf(bl(v.y), w0.z, a); a = fmaf(bh(v.y), w0.w, a);
            a = fmaf(bl(v.z), w1.x, a); a = fmaf(bh(v.z), w1.y, a);
            a = fmaf(bl(v.w), w1.z, a); a = fmaf(bh(v.w), w1.w, a);
        }
    }
    out[(size_t)n * 262144 + p] = 1.0f / (1.0f + __expf(-a));
}

// ---- finalize loss ---------------------------------------------------------
__global__ void k_loss_final(const float* __restrict__ lacc, float* __restrict__ out)
{
    if (threadIdx.x == 0 && blockIdx.x == 0)
        out[0] = 1.25f * lacc[0] * (1.0f / 16777216.0f);
}

// ---------------------------------------------------------------------------
extern "C" void kernel_launch(void* const* d_in, const int* in_sizes, int n_in,
                              void* d_out, int out_size, void* d_ws, size_t ws_size,
                              hipStream_t stream)
{
    const float* x      = (const float*)d_in[0];
    const float* enc_w1 = (const float*)d_in[1];
    const float* enc_b1 = (const float*)d_in[2];
    const float* enc_w2 = (const float*)d_in[3];
    const float* enc_b2 = (const float*)d_in[4];
    const float* enc_w3 = (const float*)d_in[5];
    const float* enc_b3 = (const float*)d_in[6];
    const float* enc_w4 = (const float*)d_in[7];
    const float* enc_b4 = (const float*)d_in[8];
    const float* cb     = (const float*)d_in[9];
    const float* dec_w1 = (const float*)d_in[10];
    const float* dec_b1 = (const float*)d_in[11];
    const float* tw1    = (const float*)d_in[12];
    const float* tb1    = (const float*)d_in[13];
    const float* tw2    = (const float*)d_in[14];
    const float* tb2    = (const float*)d_in[15];
    const float* tw3    = (const float*)d_in[16];
    const float* tb3    = (const float*)d_in[17];
    float* out = (float*)d_out;

    unsigned short* a1 = (unsigned short*)d_ws;        // 8*258*258*64
    unsigned short* a2 = a1 + 34076672;                // 8*130*130*64
    unsigned short* a3 = a2 + 8652800;                 // 8*66*66*64
    float*  z  = (float*)(a3 + 2230272);               // 32768*512 f32
    unsigned short* zq = (unsigned short*)(z + 16777216); // 8*66*66*512
    unsigned short* d1 = zq + 17842176;                // 8*66*66*64
    unsigned short* wA2 = d1 + 2230272;                // 65536
    unsigned short* wA3 = wA2 + 65536;
    unsigned short* wB1 = wA3 + 65536;                 // 294912
    unsigned short* wB2 = wB1 + 294912;                // 294912
    unsigned short* wC1 = wB2 + 294912;                // 65536
    unsigned short* wC2 = wC1 + 65536;                 // 65536
    float* cbT = (float*)(wC2 + 65536);                // 262144
    float* cn2 = cbT + 262144;                         // 512
    int*   vidx = (int*)(cn2 + 512);                   // 32768
    float* lacc = (float*)(vidx + 32768);

    // halos + preps
    k_halo<<<dim3(33, 8), 256, 0, stream>>>(a1, 258, 258, 64);
    k_halo<<<dim3(17, 8), 256, 0, stream>>>(a2, 130, 130, 64);
    k_halo<<<dim3(9, 8), 256, 0, stream>>>(a3, 66, 66, 64);
    k_halo<<<dim3(65, 8), 256, 0, stream>>>(zq, 66, 66, 512);
    k_halo<<<dim3(9, 8), 256, 0, stream>>>(d1, 66, 66, 64);
    k_prep<<<512, 64, 0, stream>>>(cb, cbT, cn2, lacc);
    k_prep_conv<<<256, 256, 0, stream>>>(enc_w2, wA2, 64, 64, 16, 64);
    k_prep_conv<<<256, 256, 0, stream>>>(enc_w3, wA3, 64, 64, 16, 64);
    k_prep_conv<<<1152, 256, 0, stream>>>(enc_w4, wB1, 512, 64, 9, 64);
    k_prep_conv<<<1152, 256, 0, stream>>>(dec_w1, wB2, 64, 512, 9, 128);
    k_prep_wT<<<256, 256, 0, stream>>>(tw1, wC1);
    k_prep_wT<<<256, 256, 0, stream>>>(tw2, wC2);

    // pipeline
    k_conv1<<<dim3(256, 8), 256, 0, stream>>>(x, enc_w1, enc_b1, a1);
    conv_mfma<4, 4, 2, 64, 32, 1, false, false><<<dim3(4, 128, 8), 256, 0, stream>>>(
        a1, wA2, enc_b2, a2, 258, 258, 64, 1, 64, 1, 130, 130, 1);
    conv_mfma<4, 4, 2, 64, 32, 1, false, false><<<dim3(2, 64, 8), 256, 0, stream>>>(
        a2, wA3, enc_b3, a3, 130, 130, 64, 1, 64, 1, 66, 66, 1);
    conv_mfma<3, 3, 1, 64, 64, 2, false, true><<<dim3(1, 64, 64), 256, 0, stream>>>(
        a3, wB1, enc_b4, z, 66, 66, 64, 1, 512, 8, 0, 0, 0);
    k_vq<<<2048, 256, 0, stream>>>(z, cb, cbT, cn2, vidx, lacc);
    k_gather<<<8192, 256, 0, stream>>>(vidx, cb, zq);
    conv_mfma<3, 3, 1, 128, 64, 2, false, false><<<dim3(1, 64, 8), 256, 0, stream>>>(
        zq, wB2, dec_b1, d1, 66, 66, 512, 4, 64, 1, 66, 66, 1);
    conv_mfma<2, 2, 1, 64, 64, 2, true, false><<<dim3(4, 64, 8), 256, 0, stream>>>(
        d1, wC1, tb1, a2, 66, 66, 64, 1, 64, 1, 130, 130, 1);
    conv_mfma<2, 2, 1, 64, 64, 2, true, false><<<dim3(8, 128, 8), 256, 0, stream>>>(
        a2, wC2, tb2, a1, 130, 130, 64, 1, 64, 1, 258, 258, 1);
    k_convt_final<<<dim3(1024, 8), 256, 0, stream>>>(a1, tw3, tb3, out);
    k_loss_final<<<1, 64, 0, stream>>>(lacc, out + 2097152);
}

// Round 3
// 653.766 us; speedup vs baseline: 3.2888x; 1.1798x over previous
//
#include <hip/hip_runtime.h>
#include <math.h>

// ---------------------------------------------------------------------------
// VQ-VAE forward, bf16-MFMA version. Round 3: VQ via split-bf16 MFMA GEMM.
// ---------------------------------------------------------------------------

typedef __bf16 bf16x8_t __attribute__((ext_vector_type(8)));
typedef float f32x4_t __attribute__((ext_vector_type(4)));

union FragU { uint4 u; bf16x8_t b; };

__device__ inline f32x4_t mfma16(bf16x8_t a, bf16x8_t b, f32x4_t c) {
    return __builtin_amdgcn_mfma_f32_16x16x32_bf16(a, b, c, 0, 0, 0);
}

__device__ inline void gl_lds16(const void* g, void* l) {
    __builtin_amdgcn_global_load_lds((const __attribute__((address_space(1))) void*)g,
                                     (__attribute__((address_space(3))) void*)l, 16, 0, 0);
}

__device__ inline unsigned bf16rne(float f) {
    unsigned u = __float_as_uint(f);
    u += 0x7FFFu + ((u >> 16) & 1u);
    return u >> 16;
}
__device__ inline unsigned pack2(float lo, float hi) {
    return bf16rne(lo) | (bf16rne(hi) << 16);
}
__device__ inline float bl(unsigned u) { return __uint_as_float(u << 16); }
__device__ inline float bh(unsigned u) { return __uint_as_float(u & 0xffff0000u); }
// split x,y into packed bf16 hi + bf16 lo(residual)
__device__ inline void split2(float x, float y, unsigned& h, unsigned& l) {
    unsigned hx = bf16rne(x), hy = bf16rne(y);
    float rx = x - __uint_as_float(hx << 16);
    float ry = y - __uint_as_float(hy << 16);
    h = hx | (hy << 16);
    l = bf16rne(rx) | (bf16rne(ry) << 16);
}

// ---- generic implicit-GEMM conv -------------------------------------------
template<int NR, int KW_, int SW, int CIC, int SPT, int NT, bool PHASED, bool OUTF32>
__global__ __launch_bounds__(256) void conv_mfma(
    const unsigned short* __restrict__ in, const unsigned short* __restrict__ wp,
    const float* __restrict__ bias, void* __restrict__ outp,
    int Hp, int Wp, int PS, int nchunks, int Cout, int ncog,
    int Hpo, int Wpo, int relu)
{
    constexpr int W_ST = SW * (SPT - 1) + KW_;
    constexpr int SLOTS_PP = CIC / 8;
    constexpr int ROW_SLOTS = W_ST * SLOTS_PP;
    constexpr int SEGS = (ROW_SLOTS + 63) / 64;
    constexpr int KT = NR * KW_;
    constexpr int CSTEPS = CIC / 32;
    __shared__ __align__(16) unsigned short sh[NR * W_ST * CIC];

    int t = threadIdx.x, lane = t & 63, wv = t >> 6;
    int bx = blockIdx.x;
    int ph = 0, pw = 0, owt = bx;
    if (PHASED) { int phs = bx & 3; ph = phs >> 1; pw = phs & 1; owt = bx >> 2; }
    int ohg = blockIdx.y;
    int bz = blockIdx.z; int nb = bz / ncog; int cog = bz % ncog;
    int ow0 = owt * SPT;
    int row0 = SW * ohg + (PHASED ? ph : 0);
    int col0 = SW * ow0 + (PHASED ? pw : 0);
    int coh = wv & 1;
    int sph = wv >> 1;
    int m = lane & 15, g = lane >> 4;

    if (PHASED) wp += (size_t)(ph * 2 + pw) * Cout * KT * CIC;

    f32x4_t acc[2][NT];
#pragma unroll
    for (int a = 0; a < 2; ++a)
#pragma unroll
        for (int u2 = 0; u2 < NT; ++u2) acc[a][u2] = (f32x4_t){0.f, 0.f, 0.f, 0.f};

    for (int ch = 0; ch < nchunks; ++ch) {
        if (ch) __syncthreads();
        for (int u_ = wv; u_ < NR * SEGS; u_ += 4) {
            int r = u_ / SEGS, seg = u_ - r * SEGS;
            int slot = seg * 64 + lane;
            int p = slot / SLOTS_PP;
            int uu = slot & (SLOTS_PP - 1);
            if (p < W_ST) {
                int su = (uu - (p & 7)) & (SLOTS_PP - 1);
                const unsigned short* gsrc = in +
                    (((size_t)nb * Hp + (row0 + r)) * Wp + (col0 + p)) * PS + ch * CIC + su * 8;
                unsigned short* ldst = sh + ((size_t)(r * ROW_SLOTS + seg * 64 + lane)) * 8;
                gl_lds16(gsrc, ldst);
            }
        }
        __syncthreads();
        int sbase = ch * (KT * CSTEPS);
#pragma unroll
        for (int tap = 0; tap < KT; ++tap) {
            const int r_l = tap / KW_, kwp = tap % KW_;
#pragma unroll
            for (int cs = 0; cs < CSTEPS; ++cs) {
                int s = sbase + tap * CSTEPS + cs;
                const uint4* wr = (const uint4*)wp + (size_t)(s * 4 + g) * Cout + cog * 64 + coh * 32 + m;
                FragU a0, a1;
                a0.u = wr[0];
                a1.u = wr[16];
#pragma unroll
                for (int u2 = 0; u2 < NT; ++u2) {
                    int sp_l = sph * (SPT / 2) + u2 * 16 + m;
                    int p = SW * sp_l + kwp;
                    int off = (cs * 32 + g * 8 + ((p & 7) << 3)) & (CIC - 1);
                    FragU bb;
                    bb.u = *(const uint4*)(sh + (size_t)(r_l * W_ST + p) * CIC + off);
                    acc[0][u2] = mfma16(a0.b, bb.b, acc[0][u2]);
                    acc[1][u2] = mfma16(a1.b, bb.b, acc[1][u2]);
                }
            }
        }
    }
#pragma unroll
    for (int a = 0; a < 2; ++a) {
        int co = cog * 64 + coh * 32 + a * 16 + g * 4;
        float4 bv = *(const float4*)(bias + co);
#pragma unroll
        for (int u2 = 0; u2 < NT; ++u2) {
            int ow = ow0 + sph * (SPT / 2) + u2 * 16 + m;
            float v0 = acc[a][u2][0] + bv.x;
            float v1 = acc[a][u2][1] + bv.y;
            float v2 = acc[a][u2][2] + bv.z;
            float v3 = acc[a][u2][3] + bv.w;
            if (relu) {
                v0 = fmaxf(v0, 0.f); v1 = fmaxf(v1, 0.f);
                v2 = fmaxf(v2, 0.f); v3 = fmaxf(v3, 0.f);
            }
            if (OUTF32) {
                float* zo = (float*)outp;
                size_t spg = ((size_t)nb * 64 + ohg) * 64 + ow;
                float4 st = {v0, v1, v2, v3};
                *(float4*)(zo + spg * 512 + co) = st;
            } else {
                unsigned short* ob = (unsigned short*)outp;
                int oho = PHASED ? 2 * ohg + ph : ohg;
                int owo = PHASED ? 2 * ow + pw : ow;
                uint2 st = {pack2(v0, v1), pack2(v2, v3)};
                *(uint2*)(ob + (((size_t)nb * Hpo + oho + 1) * Wpo + (owo + 1)) * 64
                          + (coh * 32 + a * 16 + g * 4)) = st;
            }
        }
    }
}

// ---- halo zeroing ----------------------------------------------------------
__global__ __launch_bounds__(256) void k_halo(unsigned short* buf, int Hp, int Wp, int PS)
{
    int per = 2 * Wp + 2 * (Hp - 2);
    int chunks = PS >> 3;
    int total = per * chunks;
    int n = blockIdx.y;
    for (int i = blockIdx.x * 256 + threadIdx.x; i < total; i += gridDim.x * 256) {
        int pix = i / chunks, c = i - pix * chunks;
        int h, w;
        if (pix < Wp) { h = 0; w = pix; }
        else if (pix < 2 * Wp) { h = Hp - 1; w = pix - Wp; }
        else { int q = pix - 2 * Wp; h = 1 + (q >> 1); w = (q & 1) ? (Wp - 1) : 0; }
        uint4 zz = {0, 0, 0, 0};
        *(uint4*)(buf + (((size_t)n * Hp + h) * Wp + w) * PS + c * 8) = zz;
    }
}

// ---- weight prep: conv [co][ci][kh][kw] fp32 -> fragment-order bf16 --------
__global__ __launch_bounds__(256) void k_prep_conv(const float* __restrict__ w,
    unsigned short* __restrict__ o, int Cout, int Cin, int T, int CIC)
{
    int idx = blockIdx.x * 256 + threadIdx.x;
    if (idx >= Cout * Cin * T) return;
    int tap = idx % T; int r = idx / T; int ci = r % Cin; int co = r / Cin;
    int chunk = ci / CIC, cil = ci % CIC;
    int k = chunk * (T * CIC) + tap * CIC + cil;
    int s = k >> 5, g = (k >> 3) & 3, j = k & 7;
    o[((size_t)(s * 4 + g) * Cout + co) * 8 + j] = (unsigned short)bf16rne(w[idx]);
}

// ---- weight prep: convT [ci][co][4][4] -> per-phase 2x2 fragment order -----
__global__ __launch_bounds__(256) void k_prep_wT(const float* __restrict__ w,
    unsigned short* __restrict__ o)
{
    int idx = blockIdx.x * 256 + threadIdx.x;     // 65536
    int ci = idx & 63; int r = idx >> 6;
    int jw = r & 1; r >>= 1;
    int jh = r & 1; r >>= 1;
    int co = r & 63; r >>= 6;
    int pw = r & 1; int ph = (r >> 1) & 1;
    int kh = (1 - ph) + 2 * (1 - jh);
    int kw = (1 - pw) + 2 * (1 - jw);
    int k = (jh * 2 + jw) * 64 + ci;
    int s = k >> 5, g = (k >> 3) & 3, j = k & 7;
    o[(size_t)(ph * 2 + pw) * 16384 + ((size_t)(s * 4 + g) * 64 + co) * 8 + j] =
        (unsigned short)bf16rne(w[((ci * 64 + co) * 4 + kh) * 4 + kw]);
}

// ---- codebook fragment-order split bf16 (hi/lo) ----------------------------
// B[c][k]: frag offset = (((ntg*16+s)*4+g)*16+nl)*8+j, ntg=k>>4, nl=k&15,
// s=c>>5, g=(c>>3)&3, j=c&7.
__global__ __launch_bounds__(256) void k_prep_cb(const float* __restrict__ cb,
    unsigned short* __restrict__ cbH, unsigned short* __restrict__ cbL)
{
    int i = blockIdx.x * 256 + threadIdx.x;   // 262144
    int c = i & 511, k = i >> 9;
    float v = cb[i];
    unsigned h = bf16rne(v);
    float lo = v - __uint_as_float(h << 16);
    unsigned l = bf16rne(lo);
    int ntg = k >> 4, nl = k & 15, s = c >> 5, g = (c >> 3) & 3, j = c & 7;
    size_t off = ((((size_t)ntg * 16 + s) * 4 + g) * 16 + nl) * 8 + j;
    cbH[off] = (unsigned short)h;
    cbL[off] = (unsigned short)l;
}

// ---- 0.5*||c||^2 + zero loss accumulator -----------------------------------
__global__ __launch_bounds__(64) void k_prep(const float* __restrict__ cb,
    float* __restrict__ cn2, float* __restrict__ lacc)
{
    int k = blockIdx.x; int t = threadIdx.x;
    float s = 0.f;
#pragma unroll
    for (int i = 0; i < 8; ++i) {
        float v = cb[k * 512 + t + i * 64];
        s = fmaf(v, v, s);
    }
#pragma unroll
    for (int off = 32; off > 0; off >>= 1) s += __shfl_xor(s, off);
    if (t == 0) cn2[k] = 0.5f * s;
    if (k == 0 && t == 0) *lacc = 0.f;
}

// ---- enc conv1: Cin=1, 4x4 s2 p1, ReLU -> bf16 NHWC padded ----------------
__global__ __launch_bounds__(256) void k_conv1(const float* __restrict__ x,
    const float* __restrict__ w, const float* __restrict__ b, unsigned short* __restrict__ out)
{
    __shared__ float ws[1024];
    __shared__ float bs[64];
    int t = threadIdx.x;
#pragma unroll
    for (int i = 0; i < 4; ++i) ws[t + 256 * i] = w[t + 256 * i];
    if (t < 64) bs[t] = b[t];
    __syncthreads();
    int oh = blockIdx.x;
    int n = blockIdx.y;
    int ow = t;
    const float* xn = x + (size_t)n * 262144;
    float xv[16];
#pragma unroll
    for (int kh = 0; kh < 4; ++kh) {
        int ih = 2 * oh - 1 + kh;
        bool rok = (unsigned)ih < 512u;
        int ihc = min(max(ih, 0), 511);
#pragma unroll
        for (int kw = 0; kw < 4; ++kw) {
            int iw = 2 * ow - 1 + kw;
            bool ok = rok && ((unsigned)iw < 512u);
            int iwc = min(max(iw, 0), 511);
            float v = xn[ihc * 512 + iwc];
            xv[kh * 4 + kw] = ok ? v : 0.f;
        }
    }
    unsigned short* on = out + (((size_t)n * 258 + oh + 1) * 258 + (ow + 1)) * 64;
    unsigned uo[32];
#pragma unroll
    for (int co2 = 0; co2 < 32; ++co2) {
        float a0 = bs[2 * co2], a1 = bs[2 * co2 + 1];
#pragma unroll
        for (int q = 0; q < 16; ++q) {
            a0 = fmaf(xv[q], ws[(2 * co2) * 16 + q], a0);
            a1 = fmaf(xv[q], ws[(2 * co2 + 1) * 16 + q], a1);
        }
        uo[co2] = pack2(fmaxf(a0, 0.f), fmaxf(a1, 0.f));
    }
#pragma unroll
    for (int i = 0; i < 8; ++i) {
        uint4 st = {uo[4 * i], uo[4 * i + 1], uo[4 * i + 2], uo[4 * i + 3]};
        *(uint4*)(on + i * 8) = st;
    }
}

// ---- VQ via split-bf16 MFMA ------------------------------------------------
// Block: 32 z-rows x all 512 codes. Waves: (rh = wv&1) row-half, (nh = wv>>1)
// code-half. K=512 channels in 2 chunks of 256 (LDS fp32, padded stride 260).
// score = Ah*Bh + Ah*Bl + Al*Bh (fp32 acc); argmax + loss fused.
__global__ __launch_bounds__(256) void k_vq2(const float* __restrict__ z,
    const unsigned short* __restrict__ cbH, const unsigned short* __restrict__ cbL,
    const float* __restrict__ cn2, int* __restrict__ idx, float* __restrict__ lacc)
{
    __shared__ __align__(16) float zsh[32 * 260];
    __shared__ float wmax[4][16];
    __shared__ int   widx[4][16];
    __shared__ float rssq[32];
    int t = threadIdx.x, lane = t & 63, wv = t >> 6;
    int rh = wv & 1, nh = wv >> 1;
    int m = lane & 15, g = lane >> 4;
    int row0 = blockIdx.x * 32;

    f32x4_t acc[16];
#pragma unroll
    for (int i = 0; i < 16; ++i) acc[i] = (f32x4_t){0.f, 0.f, 0.f, 0.f};
    float ssq = 0.f;

    const uint4* bhp = (const uint4*)cbH + (size_t)nh * 16384;
    const uint4* blp = (const uint4*)cbL + (size_t)nh * 16384;

    for (int chunk = 0; chunk < 2; ++chunk) {
        if (chunk) __syncthreads();
        for (int r = wv; r < 32; r += 4) {
            const float* gs = z + (size_t)(row0 + r) * 512 + chunk * 256 + lane * 4;
            char* ld = (char*)zsh + r * 1040 + lane * 16;
            gl_lds16(gs, ld);
        }
        __syncthreads();
#pragma unroll
        for (int s = 0; s < 8; ++s) {
            const float* ap = zsh + (rh * 16 + m) * 260 + s * 32 + g * 8;
            float4 a0 = *(const float4*)ap;
            float4 a1 = *(const float4*)(ap + 4);
            ssq = fmaf(a0.x, a0.x, ssq); ssq = fmaf(a0.y, a0.y, ssq);
            ssq = fmaf(a0.z, a0.z, ssq); ssq = fmaf(a0.w, a0.w, ssq);
            ssq = fmaf(a1.x, a1.x, ssq); ssq = fmaf(a1.y, a1.y, ssq);
            ssq = fmaf(a1.z, a1.z, ssq); ssq = fmaf(a1.w, a1.w, ssq);
            FragU Ah, Al;
            split2(a0.x, a0.y, Ah.u.x, Al.u.x);
            split2(a0.z, a0.w, Ah.u.y, Al.u.y);
            split2(a1.x, a1.y, Ah.u.z, Al.u.z);
            split2(a1.z, a1.w, Ah.u.w, Al.u.w);
            int sg = chunk * 8 + s;
#pragma unroll
            for (int nt = 0; nt < 16; ++nt) {
                FragU Bh, Bl;
                Bh.u = bhp[nt * 1024 + sg * 64 + g * 16 + m];
                Bl.u = blp[nt * 1024 + sg * 64 + g * 16 + m];
                acc[nt] = mfma16(Ah.b, Bh.b, acc[nt]);
                acc[nt] = mfma16(Ah.b, Bl.b, acc[nt]);
                acc[nt] = mfma16(Al.b, Bh.b, acc[nt]);
            }
        }
    }
    // row sum-of-squares (waves 0,1 cover the two row halves)
    ssq += __shfl_xor(ssq, 16);
    ssq += __shfl_xor(ssq, 32);
    if (wv < 2 && lane < 16) rssq[rh * 16 + lane] = ssq;
    // per-lane argmax over this wave's 256 codes
    float mx[4]; int mi[4];
#pragma unroll
    for (int r = 0; r < 4; ++r) { mx[r] = -1e30f; mi[r] = 0; }
#pragma unroll
    for (int nt = 0; nt < 16; ++nt) {
        int n = nh * 256 + nt * 16 + m;
        float c2 = cn2[n];
#pragma unroll
        for (int r = 0; r < 4; ++r) {
            float v = acc[nt][r] - c2;
            if (v > mx[r]) { mx[r] = v; mi[r] = n; }
        }
    }
#pragma unroll
    for (int off = 1; off < 16; off <<= 1) {
#pragma unroll
        for (int r = 0; r < 4; ++r) {
            float ov = __shfl_xor(mx[r], off);
            int oi = __shfl_xor(mi[r], off);
            if (ov > mx[r] || (ov == mx[r] && oi < mi[r])) { mx[r] = ov; mi[r] = oi; }
        }
    }
    if (m == 0) {
#pragma unroll
        for (int r = 0; r < 4; ++r) { wmax[wv][g * 4 + r] = mx[r]; widx[wv][g * 4 + r] = mi[r]; }
    }
    __syncthreads();
    if (t < 32) {
        int rh2 = t >> 4, rl = t & 15;
        float v0 = wmax[rh2][rl]; int i0 = widx[rh2][rl];
        float v1 = wmax[2 + rh2][rl]; int i1 = widx[2 + rh2][rl];
        if (v1 > v0 || (v1 == v0 && i1 < i0)) { v0 = v1; i0 = i1; }
        idx[row0 + t] = i0;
        float dist = rssq[t] - 2.f * v0;
#pragma unroll
        for (int off = 1; off < 32; off <<= 1) dist += __shfl_xor(dist, off);
        if (t == 0) atomicAdd(lacc, dist);
    }
}

// ---- gather z_q -> padded NHWC bf16 [8,66,66,512] --------------------------
__global__ __launch_bounds__(256) void k_gather(const int* __restrict__ idx,
    const float* __restrict__ cb, unsigned short* __restrict__ zq)
{
    int t = threadIdx.x;
    int sp = blockIdx.x * 4 + (t >> 6);
    int lane = t & 63;
    int k = idx[sp];
    int n = sp >> 12, hw = sp & 4095, h = hw >> 6, w = hw & 63;
    const float* src = cb + (size_t)k * 512 + lane * 8;
    unsigned short* dst = zq + (((size_t)n * 66 + h + 1) * 66 + (w + 1)) * 512 + lane * 8;
    float4 v0 = *(const float4*)src, v1 = *(const float4*)(src + 4);
    uint4 st = {pack2(v0.x, v0.y), pack2(v0.z, v0.w), pack2(v1.x, v1.y), pack2(v1.z, v1.w)};
    *(uint4*)dst = st;
}

// ---- final conv-transpose 64 -> 1, sigmoid ---------------------------------
__global__ __launch_bounds__(256) void k_convt_final(const unsigned short* __restrict__ xp,
    const float* __restrict__ w, const float* __restrict__ b, float* __restrict__ out)
{
    __shared__ float ws2[1024];          // [tap][ci]
    int t = threadIdx.x;
#pragma unroll
    for (int i = 0; i < 4; ++i) {
        int q = t + 256 * i;
        ws2[q] = w[((q & 63) * 16) + (q >> 6)];
    }
    __syncthreads();
    int p = blockIdx.x * 256 + t;
    int n = blockIdx.y;
    int ow = p & 511, oh = p >> 9;
    int ihA = (oh + 1) >> 1, khA = (oh + 1) & 1;
    int ihB = ihA - 1,       khB = khA + 2;
    int iwA = (ow + 1) >> 1, kwA = (ow + 1) & 1;
    int iwB = iwA - 1,       kwB = kwA + 2;
    const uint4* pp[4];
    int tt[4];
    pp[0] = (const uint4*)(xp + (((size_t)n * 258 + ihA + 1) * 258 + iwA + 1) * 64); tt[0] = khA * 4 + kwA;
    pp[1] = (const uint4*)(xp + (((size_t)n * 258 + ihA + 1) * 258 + iwB + 1) * 64); tt[1] = khA * 4 + kwB;
    pp[2] = (const uint4*)(xp + (((size_t)n * 258 + ihB + 1) * 258 + iwA + 1) * 64); tt[2] = khB * 4 + kwA;
    pp[3] = (const uint4*)(xp + (((size_t)n * 258 + ihB + 1) * 258 + iwB + 1) * 64); tt[3] = khB * 4 + kwB;
    float a = b[0];
#pragma unroll
    for (int tpix = 0; tpix < 4; ++tpix) {
        const uint4* P = pp[tpix]; int tp = tt[tpix];
#pragma unroll
        for (int c8 = 0; c8 < 8; ++c8) {
            uint4 v = P[c8];
            const float4 w0 = *(const float4*)&ws2[tp * 64 + c8 * 8];
            const float4 w1 = *(const float4*)&ws2[tp * 64 + c8 * 8 + 4];
            a = fmaf(bl(v.x), w0.x, a); a = fmaf(bh(v.x), w0.y, a);
            a = fmaf(bl(v.y), w0.z, a); a = fmaf(bh(v.y), w0.w, a);
            a = fmaf(bl(v.z), w1.x, a); a = fmaf(bh(v.z), w1.y, a);
            a = fmaf(bl(v.w), w1.z, a); a = fmaf(bh(v.w), w1.w, a);
        }
    }
    out[(size_t)n * 262144 + p] = 1.0f / (1.0f + __expf(-a));
}

// ---- finalize loss ---------------------------------------------------------
__global__ void k_loss_final(const float* __restrict__ lacc, float* __restrict__ out)
{
    if (threadIdx.x == 0 && blockIdx.x == 0)
        out[0] = 1.25f * lacc[0] * (1.0f / 16777216.0f);
}

// ---------------------------------------------------------------------------
extern "C" void kernel_launch(void* const* d_in, const int* in_sizes, int n_in,
                              void* d_out, int out_size, void* d_ws, size_t ws_size,
                              hipStream_t stream)
{
    const float* x      = (const float*)d_in[0];
    const float* enc_w1 = (const float*)d_in[1];
    const float* enc_b1 = (const float*)d_in[2];
    const float* enc_w2 = (const float*)d_in[3];
    const float* enc_b2 = (const float*)d_in[4];
    const float* enc_w3 = (const float*)d_in[5];
    const float* enc_b3 = (const float*)d_in[6];
    const float* enc_w4 = (const float*)d_in[7];
    const float* enc_b4 = (const float*)d_in[8];
    const float* cb     = (const float*)d_in[9];
    const float* dec_w1 = (const float*)d_in[10];
    const float* dec_b1 = (const float*)d_in[11];
    const float* tw1    = (const float*)d_in[12];
    const float* tb1    = (const float*)d_in[13];
    const float* tw2    = (const float*)d_in[14];
    const float* tb2    = (const float*)d_in[15];
    const float* tw3    = (const float*)d_in[16];
    const float* tb3    = (const float*)d_in[17];
    float* out = (float*)d_out;

    unsigned short* a1 = (unsigned short*)d_ws;        // 8*258*258*64
    unsigned short* a2 = a1 + 34076672;                // 8*130*130*64
    unsigned short* a3 = a2 + 8652800;                 // 8*66*66*64
    float*  z  = (float*)(a3 + 2230272);               // 32768*512 f32
    unsigned short* zq = (unsigned short*)(z + 16777216); // 8*66*66*512
    unsigned short* d1 = zq + 17842176;                // 8*66*66*64
    unsigned short* wA2 = d1 + 2230272;                // 65536
    unsigned short* wA3 = wA2 + 65536;
    unsigned short* wB1 = wA3 + 65536;                 // 294912
    unsigned short* wB2 = wB1 + 294912;                // 294912
    unsigned short* wC1 = wB2 + 294912;                // 65536
    unsigned short* wC2 = wC1 + 65536;                 // 65536
    unsigned short* cbH = wC2 + 65536;                 // 262144 us
    unsigned short* cbL = cbH + 262144;                // 262144 us
    float* cn2 = (float*)(cbL + 262144);               // 512
    int*   vidx = (int*)(cn2 + 512);                   // 32768
    float* lacc = (float*)(vidx + 32768);

    // halos + preps
    k_halo<<<dim3(33, 8), 256, 0, stream>>>(a1, 258, 258, 64);
    k_halo<<<dim3(17, 8), 256, 0, stream>>>(a2, 130, 130, 64);
    k_halo<<<dim3(9, 8), 256, 0, stream>>>(a3, 66, 66, 64);
    k_halo<<<dim3(65, 8), 256, 0, stream>>>(zq, 66, 66, 512);
    k_halo<<<dim3(9, 8), 256, 0, stream>>>(d1, 66, 66, 64);
    k_prep<<<512, 64, 0, stream>>>(cb, cn2, lacc);
    k_prep_cb<<<1024, 256, 0, stream>>>(cb, cbH, cbL);
    k_prep_conv<<<256, 256, 0, stream>>>(enc_w2, wA2, 64, 64, 16, 64);
    k_prep_conv<<<256, 256, 0, stream>>>(enc_w3, wA3, 64, 64, 16, 64);
    k_prep_conv<<<1152, 256, 0, stream>>>(enc_w4, wB1, 512, 64, 9, 64);
    k_prep_conv<<<1152, 256, 0, stream>>>(dec_w1, wB2, 64, 512, 9, 128);
    k_prep_wT<<<256, 256, 0, stream>>>(tw1, wC1);
    k_prep_wT<<<256, 256, 0, stream>>>(tw2, wC2);

    // pipeline
    k_conv1<<<dim3(256, 8), 256, 0, stream>>>(x, enc_w1, enc_b1, a1);
    conv_mfma<4, 4, 2, 64, 32, 1, false, false><<<dim3(4, 128, 8), 256, 0, stream>>>(
        a1, wA2, enc_b2, a2, 258, 258, 64, 1, 64, 1, 130, 130, 1);
    conv_mfma<4, 4, 2, 64, 32, 1, false, false><<<dim3(2, 64, 8), 256, 0, stream>>>(
        a2, wA3, enc_b3, a3, 130, 130, 64, 1, 64, 1, 66, 66, 1);
    conv_mfma<3, 3, 1, 64, 64, 2, false, true><<<dim3(1, 64, 64), 256, 0, stream>>>(
        a3, wB1, enc_b4, z, 66, 66, 64, 1, 512, 8, 0, 0, 0);
    k_vq2<<<1024, 256, 0, stream>>>(z, cbH, cbL, cn2, vidx, lacc);
    k_gather<<<8192, 256, 0, stream>>>(vidx, cb, zq);
    conv_mfma<3, 3, 1, 128, 64, 2, false, false><<<dim3(1, 64, 8), 256, 0, stream>>>(
        zq, wB2, dec_b1, d1, 66, 66, 512, 4, 64, 1, 66, 66, 1);
    conv_mfma<2, 2, 1, 64, 64, 2, true, false><<<dim3(4, 64, 8), 256, 0, stream>>>(
        d1, wC1, tb1, a2, 66, 66, 64, 1, 64, 1, 130, 130, 1);
    conv_mfma<2, 2, 1, 64, 64, 2, true, false><<<dim3(8, 128, 8), 256, 0, stream>>>(
        a2, wC2, tb2, a1, 130, 130, 64, 1, 64, 1, 258, 258, 1);
    k_convt_final<<<dim3(1024, 8), 256, 0, stream>>>(a1, tw3, tb3, out);
    k_loss_final<<<1, 64, 0, stream>>>(lacc, out + 2097152);
}

// Round 4
// 596.356 us; speedup vs baseline: 3.6054x; 1.0963x over previous
//
#include <hip/hip_runtime.h>
#include <math.h>

// ---------------------------------------------------------------------------
// VQ-VAE forward, bf16-MFMA. Round 4: VQ as tiled split-bf16 GEMM + reduce.
// ---------------------------------------------------------------------------

typedef __bf16 bf16x8_t __attribute__((ext_vector_type(8)));
typedef float f32x4_t __attribute__((ext_vector_type(4)));

union FragU { uint4 u; bf16x8_t b; };

__device__ inline f32x4_t mfma16(bf16x8_t a, bf16x8_t b, f32x4_t c) {
    return __builtin_amdgcn_mfma_f32_16x16x32_bf16(a, b, c, 0, 0, 0);
}

__device__ inline void gl_lds16(const void* g, void* l) {
    __builtin_amdgcn_global_load_lds((const __attribute__((address_space(1))) void*)g,
                                     (__attribute__((address_space(3))) void*)l, 16, 0, 0);
}

__device__ inline unsigned bf16rne(float f) {
    unsigned u = __float_as_uint(f);
    u += 0x7FFFu + ((u >> 16) & 1u);
    return u >> 16;
}
__device__ inline unsigned pack2(float lo, float hi) {
    return bf16rne(lo) | (bf16rne(hi) << 16);
}
__device__ inline float bl(unsigned u) { return __uint_as_float(u << 16); }
__device__ inline float bh(unsigned u) { return __uint_as_float(u & 0xffff0000u); }
__device__ inline void split2(float x, float y, unsigned& h, unsigned& l) {
    unsigned hx = bf16rne(x), hy = bf16rne(y);
    float rx = x - __uint_as_float(hx << 16);
    float ry = y - __uint_as_float(hy << 16);
    h = hx | (hy << 16);
    l = bf16rne(rx) | (bf16rne(ry) << 16);
}

// ---- generic implicit-GEMM conv -------------------------------------------
// OUTM: 0 = bf16 NHWC halo store, 2 = split zH/zL + global ssq atomic.
template<int NR, int KW_, int SW, int CIC, int SPT, int NT, bool PHASED, int OUTM>
__global__ __launch_bounds__(256) void conv_mfma(
    const unsigned short* __restrict__ in, const unsigned short* __restrict__ wp,
    const float* __restrict__ bias, void* __restrict__ outp,
    int Hp, int Wp, int PS, int nchunks, int Cout, int ncog,
    int Hpo, int Wpo, int relu,
    unsigned short* __restrict__ outp2, float* __restrict__ ssqac)
{
    constexpr int W_ST = SW * (SPT - 1) + KW_;
    constexpr int SLOTS_PP = CIC / 8;
    constexpr int ROW_SLOTS = W_ST * SLOTS_PP;
    constexpr int SEGS = (ROW_SLOTS + 63) / 64;
    constexpr int KT = NR * KW_;
    constexpr int CSTEPS = CIC / 32;
    __shared__ __align__(16) unsigned short sh[NR * W_ST * CIC];
    __shared__ float redd[4];

    int t = threadIdx.x, lane = t & 63, wv = t >> 6;
    int bx = blockIdx.x;
    int ph = 0, pw = 0, owt = bx;
    if (PHASED) { int phs = bx & 3; ph = phs >> 1; pw = phs & 1; owt = bx >> 2; }
    int ohg = blockIdx.y;
    int bz = blockIdx.z; int nb = bz / ncog; int cog = bz % ncog;
    int ow0 = owt * SPT;
    int row0 = SW * ohg + (PHASED ? ph : 0);
    int col0 = SW * ow0 + (PHASED ? pw : 0);
    int coh = wv & 1;
    int sph = wv >> 1;
    int m = lane & 15, g = lane >> 4;

    if (PHASED) wp += (size_t)(ph * 2 + pw) * Cout * KT * CIC;

    f32x4_t acc[2][NT];
#pragma unroll
    for (int a = 0; a < 2; ++a)
#pragma unroll
        for (int u2 = 0; u2 < NT; ++u2) acc[a][u2] = (f32x4_t){0.f, 0.f, 0.f, 0.f};

    for (int ch = 0; ch < nchunks; ++ch) {
        if (ch) __syncthreads();
        for (int u_ = wv; u_ < NR * SEGS; u_ += 4) {
            int r = u_ / SEGS, seg = u_ - r * SEGS;
            int slot = seg * 64 + lane;
            int p = slot / SLOTS_PP;
            int uu = slot & (SLOTS_PP - 1);
            if (p < W_ST) {
                int su = (uu - (p & 7)) & (SLOTS_PP - 1);
                const unsigned short* gsrc = in +
                    (((size_t)nb * Hp + (row0 + r)) * Wp + (col0 + p)) * PS + ch * CIC + su * 8;
                unsigned short* ldst = sh + ((size_t)(r * ROW_SLOTS + seg * 64 + lane)) * 8;
                gl_lds16(gsrc, ldst);
            }
        }
        __syncthreads();
        int sbase = ch * (KT * CSTEPS);
#pragma unroll
        for (int tap = 0; tap < KT; ++tap) {
            const int r_l = tap / KW_, kwp = tap % KW_;
#pragma unroll
            for (int cs = 0; cs < CSTEPS; ++cs) {
                int s = sbase + tap * CSTEPS + cs;
                const uint4* wr = (const uint4*)wp + (size_t)(s * 4 + g) * Cout + cog * 64 + coh * 32 + m;
                FragU a0, a1;
                a0.u = wr[0];
                a1.u = wr[16];
#pragma unroll
                for (int u2 = 0; u2 < NT; ++u2) {
                    int sp_l = sph * (SPT / 2) + u2 * 16 + m;
                    int p = SW * sp_l + kwp;
                    int off = (cs * 32 + g * 8 + ((p & 7) << 3)) & (CIC - 1);
                    FragU bb;
                    bb.u = *(const uint4*)(sh + (size_t)(r_l * W_ST + p) * CIC + off);
                    acc[0][u2] = mfma16(a0.b, bb.b, acc[0][u2]);
                    acc[1][u2] = mfma16(a1.b, bb.b, acc[1][u2]);
                }
            }
        }
    }
    float ssql = 0.f;
#pragma unroll
    for (int a = 0; a < 2; ++a) {
        int co = cog * 64 + coh * 32 + a * 16 + g * 4;
        float4 bv = *(const float4*)(bias + co);
#pragma unroll
        for (int u2 = 0; u2 < NT; ++u2) {
            int ow = ow0 + sph * (SPT / 2) + u2 * 16 + m;
            float v0 = acc[a][u2][0] + bv.x;
            float v1 = acc[a][u2][1] + bv.y;
            float v2 = acc[a][u2][2] + bv.z;
            float v3 = acc[a][u2][3] + bv.w;
            if (relu) {
                v0 = fmaxf(v0, 0.f); v1 = fmaxf(v1, 0.f);
                v2 = fmaxf(v2, 0.f); v3 = fmaxf(v3, 0.f);
            }
            if constexpr (OUTM == 2) {
                unsigned short* zH = (unsigned short*)outp;
                size_t spg = ((size_t)nb * 64 + ohg) * 64 + ow;
                unsigned h0, l0, h1, l1;
                split2(v0, v1, h0, l0);
                split2(v2, v3, h1, l1);
                uint2 sth = {h0, h1}, stl = {l0, l1};
                *(uint2*)(zH + spg * 512 + co) = sth;
                *(uint2*)(outp2 + spg * 512 + co) = stl;
                ssql += v0 * v0 + v1 * v1 + v2 * v2 + v3 * v3;
            } else {
                unsigned short* ob = (unsigned short*)outp;
                int oho = PHASED ? 2 * ohg + ph : ohg;
                int owo = PHASED ? 2 * ow + pw : ow;
                uint2 st = {pack2(v0, v1), pack2(v2, v3)};
                *(uint2*)(ob + (((size_t)nb * Hpo + oho + 1) * Wpo + (owo + 1)) * 64
                          + (coh * 32 + a * 16 + g * 4)) = st;
            }
        }
    }
    if constexpr (OUTM == 2) {
#pragma unroll
        for (int off = 1; off < 64; off <<= 1) ssql += __shfl_xor(ssql, off);
        if (lane == 0) redd[wv] = ssql;
        __syncthreads();
        if (t == 0) atomicAdd(ssqac, redd[0] + redd[1] + redd[2] + redd[3]);
    }
}

// ---- halo zeroing ----------------------------------------------------------
__global__ __launch_bounds__(256) void k_halo(unsigned short* buf, int Hp, int Wp, int PS)
{
    int per = 2 * Wp + 2 * (Hp - 2);
    int chunks = PS >> 3;
    int total = per * chunks;
    int n = blockIdx.y;
    for (int i = blockIdx.x * 256 + threadIdx.x; i < total; i += gridDim.x * 256) {
        int pix = i / chunks, c = i - pix * chunks;
        int h, w;
        if (pix < Wp) { h = 0; w = pix; }
        else if (pix < 2 * Wp) { h = Hp - 1; w = pix - Wp; }
        else { int q = pix - 2 * Wp; h = 1 + (q >> 1); w = (q & 1) ? (Wp - 1) : 0; }
        uint4 zz = {0, 0, 0, 0};
        *(uint4*)(buf + (((size_t)n * Hp + h) * Wp + w) * PS + c * 8) = zz;
    }
}

// ---- weight prep: conv [co][ci][kh][kw] fp32 -> fragment-order bf16 --------
__global__ __launch_bounds__(256) void k_prep_conv(const float* __restrict__ w,
    unsigned short* __restrict__ o, int Cout, int Cin, int T, int CIC)
{
    int idx = blockIdx.x * 256 + threadIdx.x;
    if (idx >= Cout * Cin * T) return;
    int tap = idx % T; int r = idx / T; int ci = r % Cin; int co = r / Cin;
    int chunk = ci / CIC, cil = ci % CIC;
    int k = chunk * (T * CIC) + tap * CIC + cil;
    int s = k >> 5, g = (k >> 3) & 3, j = k & 7;
    o[((size_t)(s * 4 + g) * Cout + co) * 8 + j] = (unsigned short)bf16rne(w[idx]);
}

// ---- weight prep: convT [ci][co][4][4] -> per-phase 2x2 fragment order -----
__global__ __launch_bounds__(256) void k_prep_wT(const float* __restrict__ w,
    unsigned short* __restrict__ o)
{
    int idx = blockIdx.x * 256 + threadIdx.x;     // 65536
    int ci = idx & 63; int r = idx >> 6;
    int jw = r & 1; r >>= 1;
    int jh = r & 1; r >>= 1;
    int co = r & 63; r >>= 6;
    int pw = r & 1; int ph = (r >> 1) & 1;
    int kh = (1 - ph) + 2 * (1 - jh);
    int kw = (1 - pw) + 2 * (1 - jw);
    int k = (jh * 2 + jw) * 64 + ci;
    int s = k >> 5, g = (k >> 3) & 3, j = k & 7;
    o[(size_t)(ph * 2 + pw) * 16384 + ((size_t)(s * 4 + g) * 64 + co) * 8 + j] =
        (unsigned short)bf16rne(w[((ci * 64 + co) * 4 + kh) * 4 + kw]);
}

// ---- codebook -> per-colblock, per-K-step contiguous fragment slabs --------
// dest: [cblk(4)][s(16)][g(4)][kl(128)] x 8 bf16
__global__ __launch_bounds__(256) void k_prep_cb(const float* __restrict__ cb,
    unsigned short* __restrict__ cbFH, unsigned short* __restrict__ cbFL)
{
    int i = blockIdx.x * 256 + threadIdx.x;   // 262144
    int c = i & 511, k = i >> 9;
    float v = cb[i];
    unsigned h = bf16rne(v);
    float lo = v - __uint_as_float(h << 16);
    unsigned l = bf16rne(lo);
    int cblk = k >> 7, kl = k & 127, s = c >> 5, g = (c >> 3) & 3, j = c & 7;
    size_t off = ((((size_t)cblk * 16 + s) * 4 + g) * 128 + kl) * 8 + j;
    cbFH[off] = (unsigned short)h;
    cbFL[off] = (unsigned short)l;
}

// ---- 0.5*||c||^2 -----------------------------------------------------------
__global__ __launch_bounds__(64) void k_prep(const float* __restrict__ cb,
    float* __restrict__ cn2)
{
    int k = blockIdx.x; int t = threadIdx.x;
    float s = 0.f;
#pragma unroll
    for (int i = 0; i < 8; ++i) {
        float v = cb[k * 512 + t + i * 64];
        s = fmaf(v, v, s);
    }
#pragma unroll
    for (int off = 32; off > 0; off >>= 1) s += __shfl_xor(s, off);
    if (t == 0) cn2[k] = 0.5f * s;
}

// ---- enc conv1: Cin=1, 4x4 s2 p1, ReLU -> bf16 NHWC padded ----------------
__global__ __launch_bounds__(256) void k_conv1(const float* __restrict__ x,
    const float* __restrict__ w, const float* __restrict__ b, unsigned short* __restrict__ out)
{
    __shared__ float ws[1024];
    __shared__ float bs[64];
    int t = threadIdx.x;
#pragma unroll
    for (int i = 0; i < 4; ++i) ws[t + 256 * i] = w[t + 256 * i];
    if (t < 64) bs[t] = b[t];
    __syncthreads();
    int oh = blockIdx.x;
    int n = blockIdx.y;
    int ow = t;
    const float* xn = x + (size_t)n * 262144;
    float xv[16];
#pragma unroll
    for (int kh = 0; kh < 4; ++kh) {
        int ih = 2 * oh - 1 + kh;
        bool rok = (unsigned)ih < 512u;
        int ihc = min(max(ih, 0), 511);
#pragma unroll
        for (int kw = 0; kw < 4; ++kw) {
            int iw = 2 * ow - 1 + kw;
            bool ok = rok && ((unsigned)iw < 512u);
            int iwc = min(max(iw, 0), 511);
            float v = xn[ihc * 512 + iwc];
            xv[kh * 4 + kw] = ok ? v : 0.f;
        }
    }
    unsigned short* on = out + (((size_t)n * 258 + oh + 1) * 258 + (ow + 1)) * 64;
    unsigned uo[32];
#pragma unroll
    for (int co2 = 0; co2 < 32; ++co2) {
        float a0 = bs[2 * co2], a1 = bs[2 * co2 + 1];
#pragma unroll
        for (int q = 0; q < 16; ++q) {
            a0 = fmaf(xv[q], ws[(2 * co2) * 16 + q], a0);
            a1 = fmaf(xv[q], ws[(2 * co2 + 1) * 16 + q], a1);
        }
        uo[co2] = pack2(fmaxf(a0, 0.f), fmaxf(a1, 0.f));
    }
#pragma unroll
    for (int i = 0; i < 8; ++i) {
        uint4 st = {uo[4 * i], uo[4 * i + 1], uo[4 * i + 2], uo[4 * i + 3]};
        *(uint4*)(on + i * 8) = st;
    }
}

// ---- VQ distance GEMM: scores[32768][512] tiled 128x128, split-bf16 --------
// A = z rows (LDS, 80B row stride), B = codebook slabs (LDS). Fused per-block
// argmax(score - 0.5||c||^2) -> 4 candidates per row.
__global__ __launch_bounds__(256) void k_vqgemm(
    const unsigned short* __restrict__ zH, const unsigned short* __restrict__ zL,
    const unsigned short* __restrict__ cbFH, const unsigned short* __restrict__ cbFL,
    const float* __restrict__ cn2, float* __restrict__ candV, int* __restrict__ candI)
{
    __shared__ __align__(16) unsigned short shAH[5120];   // 128 rows x 40
    __shared__ __align__(16) unsigned short shAL[5120];
    __shared__ __align__(16) unsigned short shBH[4096];   // [g(4)][code(128)] x 8
    __shared__ __align__(16) unsigned short shBL[4096];
    __shared__ float cV[2][128];
    __shared__ int   cI[2][128];
    int t = threadIdx.x, lane = t & 63, wv = t >> 6;
    int wc = wv & 1, wr = wv >> 1;
    int m = lane & 15, g = lane >> 4;
    int cblk = blockIdx.x;
    int row0 = blockIdx.y * 128;

    f32x4_t acc[4][4];
#pragma unroll
    for (int a = 0; a < 4; ++a)
#pragma unroll
        for (int b = 0; b < 4; ++b) acc[a][b] = (f32x4_t){0.f, 0.f, 0.f, 0.f};

    const unsigned short* bsH = cbFH + (size_t)cblk * 65536;
    const unsigned short* bsL = cbFL + (size_t)cblk * 65536;

    for (int s = 0; s < 16; ++s) {
        __syncthreads();
        for (int q = t; q < 640; q += 256) {
            int r = q / 5, seg = q % 5, ss = seg & 3;
            size_t so = (size_t)(row0 + r) * 512 + s * 32 + ss * 8;
            gl_lds16(zH + so, shAH + q * 8);
            gl_lds16(zL + so, shAL + q * 8);
        }
        for (int q = t; q < 512; q += 256) {
            gl_lds16(bsH + (size_t)s * 4096 + q * 8, shBH + q * 8);
            gl_lds16(bsL + (size_t)s * 4096 + q * 8, shBL + q * 8);
        }
        __syncthreads();
        FragU Ah[4], Al[4], Bh[4], Bl[4];
#pragma unroll
        for (int mi = 0; mi < 4; ++mi) {
            int row = wr * 64 + mi * 16 + m;
            Ah[mi].u = *(const uint4*)(shAH + row * 40 + g * 8);
            Al[mi].u = *(const uint4*)(shAL + row * 40 + g * 8);
        }
#pragma unroll
        for (int ni = 0; ni < 4; ++ni) {
            int code = wc * 64 + ni * 16 + m;
            Bh[ni].u = *(const uint4*)(shBH + (g * 128 + code) * 8);
            Bl[ni].u = *(const uint4*)(shBL + (g * 128 + code) * 8);
        }
#pragma unroll
        for (int mi = 0; mi < 4; ++mi) {
#pragma unroll
            for (int ni = 0; ni < 4; ++ni) {
                acc[mi][ni] = mfma16(Ah[mi].b, Bh[ni].b, acc[mi][ni]);
                acc[mi][ni] = mfma16(Ah[mi].b, Bl[ni].b, acc[mi][ni]);
                acc[mi][ni] = mfma16(Al[mi].b, Bh[ni].b, acc[mi][ni]);
            }
        }
    }
    // ---- fused argmax over this block's 128 codes -------------------------
    float bcn[4];
#pragma unroll
    for (int ni = 0; ni < 4; ++ni) bcn[ni] = cn2[cblk * 128 + wc * 64 + ni * 16 + m];
#pragma unroll
    for (int mi = 0; mi < 4; ++mi) {
#pragma unroll
        for (int r = 0; r < 4; ++r) {
            float best = -1e30f; int bi = 0;
#pragma unroll
            for (int ni = 0; ni < 4; ++ni) {
                float v = acc[mi][ni][r] - bcn[ni];
                int ix = cblk * 128 + wc * 64 + ni * 16 + m;
                if (v > best) { best = v; bi = ix; }
            }
#pragma unroll
            for (int off = 1; off < 16; off <<= 1) {
                float ov = __shfl_xor(best, off);
                int oi = __shfl_xor(bi, off);
                if (ov > best || (ov == best && oi < bi)) { best = ov; bi = oi; }
            }
            if (m == 0) {
                int rl = wr * 64 + mi * 16 + g * 4 + r;
                cV[wc][rl] = best;
                cI[wc][rl] = bi;
            }
        }
    }
    __syncthreads();
    if (t < 128) {
        float v0 = cV[0][t]; int i0 = cI[0][t];
        float v1 = cV[1][t]; int i1 = cI[1][t];
        if (v1 > v0 || (v1 == v0 && i1 < i0)) { v0 = v1; i0 = i1; }
        candV[(size_t)cblk * 32768 + row0 + t] = v0;
        candI[(size_t)cblk * 32768 + row0 + t] = i0;
    }
}

// ---- merge 4 candidates/row, emit idx + sum of max scores ------------------
__global__ __launch_bounds__(256) void k_vqred(const float* __restrict__ candV,
    const int* __restrict__ candI, int* __restrict__ vidx, float* __restrict__ ssum)
{
    __shared__ float redd[4];
    int t = threadIdx.x;
    int row = blockIdx.x * 256 + t;
    float b = candV[row]; int bi = candI[row];
#pragma unroll
    for (int cb = 1; cb < 4; ++cb) {
        float v = candV[cb * 32768 + row];
        int i = candI[cb * 32768 + row];
        if (v > b || (v == b && i < bi)) { b = v; bi = i; }
    }
    vidx[row] = bi;
#pragma unroll
    for (int off = 1; off < 64; off <<= 1) b += __shfl_xor(b, off);
    if ((t & 63) == 0) redd[t >> 6] = b;
    __syncthreads();
    if (t == 0) atomicAdd(ssum, redd[0] + redd[1] + redd[2] + redd[3]);
}

// ---- gather z_q -> padded NHWC bf16 [8,66,66,512] --------------------------
__global__ __launch_bounds__(256) void k_gather(const int* __restrict__ idx,
    const float* __restrict__ cb, unsigned short* __restrict__ zq)
{
    int t = threadIdx.x;
    int sp = blockIdx.x * 4 + (t >> 6);
    int lane = t & 63;
    int k = idx[sp];
    int n = sp >> 12, hw = sp & 4095, h = hw >> 6, w = hw & 63;
    const float* src = cb + (size_t)k * 512 + lane * 8;
    unsigned short* dst = zq + (((size_t)n * 66 + h + 1) * 66 + (w + 1)) * 512 + lane * 8;
    float4 v0 = *(const float4*)src, v1 = *(const float4*)(src + 4);
    uint4 st = {pack2(v0.x, v0.y), pack2(v0.z, v0.w), pack2(v1.x, v1.y), pack2(v1.z, v1.w)};
    *(uint4*)dst = st;
}

// ---- final conv-transpose 64 -> 1, sigmoid ---------------------------------
__global__ __launch_bounds__(256) void k_convt_final(const unsigned short* __restrict__ xp,
    const float* __restrict__ w, const float* __restrict__ b, float* __restrict__ out)
{
    __shared__ float ws2[1024];          // [tap][ci]
    int t = threadIdx.x;
#pragma unroll
    for (int i = 0; i < 4; ++i) {
        int q = t + 256 * i;
        ws2[q] = w[((q & 63) * 16) + (q >> 6)];
    }
    __syncthreads();
    int p = blockIdx.x * 256 + t;
    int n = blockIdx.y;
    int ow = p & 511, oh = p >> 9;
    int ihA = (oh + 1) >> 1, khA = (oh + 1) & 1;
    int ihB = ihA - 1,       khB = khA + 2;
    int iwA = (ow + 1) >> 1, kwA = (ow + 1) & 1;
    int iwB = iwA - 1,       kwB = kwA + 2;
    const uint4* pp[4];
    int tt[4];
    pp[0] = (const uint4*)(xp + (((size_t)n * 258 + ihA + 1) * 258 + iwA + 1) * 64); tt[0] = khA * 4 + kwA;
    pp[1] = (const uint4*)(xp + (((size_t)n * 258 + ihA + 1) * 258 + iwB + 1) * 64); tt[1] = khA * 4 + kwB;
    pp[2] = (const uint4*)(xp + (((size_t)n * 258 + ihB + 1) * 258 + iwA + 1) * 64); tt[2] = khB * 4 + kwA;
    pp[3] = (const uint4*)(xp + (((size_t)n * 258 + ihB + 1) * 258 + iwB + 1) * 64); tt[3] = khB * 4 + kwB;
    float a = b[0];
#pragma unroll
    for (int tpix = 0; tpix < 4; ++tpix) {
        const uint4* P = pp[tpix]; int tp = tt[tpix];
#pragma unroll
        for (int c8 = 0; c8 < 8; ++c8) {
            uint4 v = P[c8];
            const float4 w0 = *(const float4*)&ws2[tp * 64 + c8 * 8];
            const float4 w1 = *(const float4*)&ws2[tp * 64 + c8 * 8 + 4];
            a = fmaf(bl(v.x), w0.x, a); a = fmaf(bh(v.x), w0.y, a);
            a = fmaf(bl(v.y), w0.z, a); a = fmaf(bh(v.y), w0.w, a);
            a = fmaf(bl(v.z), w1.x, a); a = fmaf(bh(v.z), w1.y, a);
            a = fmaf(bl(v.w), w1.z, a); a = fmaf(bh(v.w), w1.w, a);
        }
    }
    out[(size_t)n * 262144 + p] = 1.0f / (1.0f + __expf(-a));
}

// ---- finalize loss: 1.25*(ssq - 2*scoresum)/N ------------------------------
__global__ void k_loss_final(const float* __restrict__ scal, float* __restrict__ out)
{
    if (threadIdx.x == 0 && blockIdx.x == 0)
        out[0] = 1.25f * (scal[0] - 2.f * scal[1]) * (1.0f / 16777216.0f);
}

// ---------------------------------------------------------------------------
extern "C" void kernel_launch(void* const* d_in, const int* in_sizes, int n_in,
                              void* d_out, int out_size, void* d_ws, size_t ws_size,
                              hipStream_t stream)
{
    const float* x      = (const float*)d_in[0];
    const float* enc_w1 = (const float*)d_in[1];
    const float* enc_b1 = (const float*)d_in[2];
    const float* enc_w2 = (const float*)d_in[3];
    const float* enc_b2 = (const float*)d_in[4];
    const float* enc_w3 = (const float*)d_in[5];
    const float* enc_b3 = (const float*)d_in[6];
    const float* enc_w4 = (const float*)d_in[7];
    const float* enc_b4 = (const float*)d_in[8];
    const float* cb     = (const float*)d_in[9];
    const float* dec_w1 = (const float*)d_in[10];
    const float* dec_b1 = (const float*)d_in[11];
    const float* tw1    = (const float*)d_in[12];
    const float* tb1    = (const float*)d_in[13];
    const float* tw2    = (const float*)d_in[14];
    const float* tb2    = (const float*)d_in[15];
    const float* tw3    = (const float*)d_in[16];
    const float* tb3    = (const float*)d_in[17];
    float* out = (float*)d_out;

    unsigned short* a1 = (unsigned short*)d_ws;        // 8*258*258*64
    unsigned short* a2 = a1 + 34076672;                // 8*130*130*64
    unsigned short* a3 = a2 + 8652800;                 // 8*66*66*64
    unsigned short* zH = a3 + 2230272;                 // 32768*512
    unsigned short* zL = zH + 16777216;                // 32768*512
    unsigned short* zq = zL + 16777216;                // 8*66*66*512
    unsigned short* d1 = zq + 17842176;                // 8*66*66*64
    unsigned short* wA2 = d1 + 2230272;                // 65536
    unsigned short* wA3 = wA2 + 65536;
    unsigned short* wB1 = wA3 + 65536;                 // 294912
    unsigned short* wB2 = wB1 + 294912;                // 294912
    unsigned short* wC1 = wB2 + 294912;                // 65536
    unsigned short* wC2 = wC1 + 65536;                 // 65536
    unsigned short* cbFH = wC2 + 65536;                // 262144
    unsigned short* cbFL = cbFH + 262144;              // 262144
    float* cn2 = (float*)(cbFL + 262144);              // 512
    int*   vidx = (int*)(cn2 + 512);                   // 32768
    float* candV = (float*)(vidx + 32768);             // 131072
    int*   candI = (int*)(candV + 131072);             // 131072
    float* scal = (float*)(candI + 131072);            // 2: [ssq, scoresum]

    hipMemsetAsync(scal, 0, 8, stream);

    // halos + preps
    k_halo<<<dim3(33, 8), 256, 0, stream>>>(a1, 258, 258, 64);
    k_halo<<<dim3(17, 8), 256, 0, stream>>>(a2, 130, 130, 64);
    k_halo<<<dim3(9, 8), 256, 0, stream>>>(a3, 66, 66, 64);
    k_halo<<<dim3(65, 8), 256, 0, stream>>>(zq, 66, 66, 512);
    k_halo<<<dim3(9, 8), 256, 0, stream>>>(d1, 66, 66, 64);
    k_prep<<<512, 64, 0, stream>>>(cb, cn2);
    k_prep_cb<<<1024, 256, 0, stream>>>(cb, cbFH, cbFL);
    k_prep_conv<<<256, 256, 0, stream>>>(enc_w2, wA2, 64, 64, 16, 64);
    k_prep_conv<<<256, 256, 0, stream>>>(enc_w3, wA3, 64, 64, 16, 64);
    k_prep_conv<<<1152, 256, 0, stream>>>(enc_w4, wB1, 512, 64, 9, 64);
    k_prep_conv<<<1152, 256, 0, stream>>>(dec_w1, wB2, 64, 512, 9, 128);
    k_prep_wT<<<256, 256, 0, stream>>>(tw1, wC1);
    k_prep_wT<<<256, 256, 0, stream>>>(tw2, wC2);

    // pipeline
    k_conv1<<<dim3(256, 8), 256, 0, stream>>>(x, enc_w1, enc_b1, a1);
    conv_mfma<4, 4, 2, 64, 32, 1, false, 0><<<dim3(4, 128, 8), 256, 0, stream>>>(
        a1, wA2, enc_b2, a2, 258, 258, 64, 1, 64, 1, 130, 130, 1, nullptr, nullptr);
    conv_mfma<4, 4, 2, 64, 32, 1, false, 0><<<dim3(2, 64, 8), 256, 0, stream>>>(
        a2, wA3, enc_b3, a3, 130, 130, 64, 1, 64, 1, 66, 66, 1, nullptr, nullptr);
    conv_mfma<3, 3, 1, 64, 64, 2, false, 2><<<dim3(1, 64, 64), 256, 0, stream>>>(
        a3, wB1, enc_b4, zH, 66, 66, 64, 1, 512, 8, 0, 0, 0, zL, scal);
    k_vqgemm<<<dim3(4, 256), 256, 0, stream>>>(zH, zL, cbFH, cbFL, cn2, candV, candI);
    k_vqred<<<128, 256, 0, stream>>>(candV, candI, vidx, scal + 1);
    k_gather<<<8192, 256, 0, stream>>>(vidx, cb, zq);
    conv_mfma<3, 3, 1, 128, 64, 2, false, 0><<<dim3(1, 64, 8), 256, 0, stream>>>(
        zq, wB2, dec_b1, d1, 66, 66, 512, 4, 64, 1, 66, 66, 1, nullptr, nullptr);
    conv_mfma<2, 2, 1, 64, 64, 2, true, 0><<<dim3(4, 64, 8), 256, 0, stream>>>(
        d1, wC1, tb1, a2, 66, 66, 64, 1, 64, 1, 130, 130, 1, nullptr, nullptr);
    conv_mfma<2, 2, 1, 64, 64, 2, true, 0><<<dim3(8, 128, 8), 256, 0, stream>>>(
        a2, wC2, tb2, a1, 130, 130, 64, 1, 64, 1, 258, 258, 1, nullptr, nullptr);
    k_convt_final<<<dim3(1024, 8), 256, 0, stream>>>(a1, tw3, tb3, out);
    k_loss_final<<<1, 64, 0, stream>>>(scal, out + 2097152);
}

// Round 5
// 543.962 us; speedup vs baseline: 3.9526x; 1.0963x over previous
//
#include <hip/hip_runtime.h>
#include <math.h>

// ---------------------------------------------------------------------------
// VQ-VAE forward, bf16-MFMA. Round 5: LDS-staged dot2-fp16 final conv-T.
// ---------------------------------------------------------------------------

typedef __bf16 bf16x8_t __attribute__((ext_vector_type(8)));
typedef float f32x4_t __attribute__((ext_vector_type(4)));
typedef _Float16 h2_t __attribute__((ext_vector_type(2)));

union FragU { uint4 u; bf16x8_t b; };

__device__ inline f32x4_t mfma16(bf16x8_t a, bf16x8_t b, f32x4_t c) {
    return __builtin_amdgcn_mfma_f32_16x16x32_bf16(a, b, c, 0, 0, 0);
}

__device__ inline void gl_lds16(const void* g, void* l) {
    __builtin_amdgcn_global_load_lds((const __attribute__((address_space(1))) void*)g,
                                     (__attribute__((address_space(3))) void*)l, 16, 0, 0);
}

__device__ inline unsigned bf16rne(float f) {
    unsigned u = __float_as_uint(f);
    u += 0x7FFFu + ((u >> 16) & 1u);
    return u >> 16;
}
__device__ inline unsigned pack2(float lo, float hi) {
    return bf16rne(lo) | (bf16rne(hi) << 16);
}
__device__ inline unsigned pack2h(float lo, float hi) {
    union { h2_t h; unsigned u; } r;
    r.h[0] = (_Float16)lo; r.h[1] = (_Float16)hi;
    return r.u;
}
__device__ inline float bl(unsigned u) { return __uint_as_float(u << 16); }
__device__ inline float bh(unsigned u) { return __uint_as_float(u & 0xffff0000u); }
__device__ inline void split2(float x, float y, unsigned& h, unsigned& l) {
    unsigned hx = bf16rne(x), hy = bf16rne(y);
    float rx = x - __uint_as_float(hx << 16);
    float ry = y - __uint_as_float(hy << 16);
    h = hx | (hy << 16);
    l = bf16rne(rx) | (bf16rne(ry) << 16);
}

#if defined(__has_builtin)
#if __has_builtin(__builtin_amdgcn_fdot2)
#define HAS_FDOT2 1
#endif
#endif

__device__ inline float dot2h(unsigned x, unsigned w, float a) {
#ifdef HAS_FDOT2
    union { unsigned u; h2_t h; } ax, bw;
    ax.u = x; bw.u = w;
    return __builtin_amdgcn_fdot2(ax.h, bw.h, a, false);
#else
    union { unsigned u; _Float16 h[2]; } ax, bw;
    ax.u = x; bw.u = w;
    a = fmaf((float)ax.h[0], (float)bw.h[0], a);
    return fmaf((float)ax.h[1], (float)bw.h[1], a);
#endif
}
__device__ inline float dot8(uint4 x, uint4 w, float a) {
    a = dot2h(x.x, w.x, a); a = dot2h(x.y, w.y, a);
    a = dot2h(x.z, w.z, a); a = dot2h(x.w, w.w, a);
    return a;
}

// ---- generic implicit-GEMM conv -------------------------------------------
// OUTM: 0 = bf16 NHWC halo store, 2 = split zH/zL + global ssq atomic,
//       3 = fp16 NHWC halo store.
template<int NR, int KW_, int SW, int CIC, int SPT, int NT, bool PHASED, int OUTM>
__global__ __launch_bounds__(256) void conv_mfma(
    const unsigned short* __restrict__ in, const unsigned short* __restrict__ wp,
    const float* __restrict__ bias, void* __restrict__ outp,
    int Hp, int Wp, int PS, int nchunks, int Cout, int ncog,
    int Hpo, int Wpo, int relu,
    unsigned short* __restrict__ outp2, float* __restrict__ ssqac)
{
    constexpr int W_ST = SW * (SPT - 1) + KW_;
    constexpr int SLOTS_PP = CIC / 8;
    constexpr int ROW_SLOTS = W_ST * SLOTS_PP;
    constexpr int SEGS = (ROW_SLOTS + 63) / 64;
    constexpr int KT = NR * KW_;
    constexpr int CSTEPS = CIC / 32;
    __shared__ __align__(16) unsigned short sh[NR * W_ST * CIC];
    __shared__ float redd[4];

    int t = threadIdx.x, lane = t & 63, wv = t >> 6;
    int bx = blockIdx.x;
    int ph = 0, pw = 0, owt = bx;
    if (PHASED) { int phs = bx & 3; ph = phs >> 1; pw = phs & 1; owt = bx >> 2; }
    int ohg = blockIdx.y;
    int bz = blockIdx.z; int nb = bz / ncog; int cog = bz % ncog;
    int ow0 = owt * SPT;
    int row0 = SW * ohg + (PHASED ? ph : 0);
    int col0 = SW * ow0 + (PHASED ? pw : 0);
    int coh = wv & 1;
    int sph = wv >> 1;
    int m = lane & 15, g = lane >> 4;

    if (PHASED) wp += (size_t)(ph * 2 + pw) * Cout * KT * CIC;

    f32x4_t acc[2][NT];
#pragma unroll
    for (int a = 0; a < 2; ++a)
#pragma unroll
        for (int u2 = 0; u2 < NT; ++u2) acc[a][u2] = (f32x4_t){0.f, 0.f, 0.f, 0.f};

    for (int ch = 0; ch < nchunks; ++ch) {
        if (ch) __syncthreads();
        for (int u_ = wv; u_ < NR * SEGS; u_ += 4) {
            int r = u_ / SEGS, seg = u_ - r * SEGS;
            int slot = seg * 64 + lane;
            int p = slot / SLOTS_PP;
            int uu = slot & (SLOTS_PP - 1);
            if (p < W_ST) {
                int su = (uu - (p & 7)) & (SLOTS_PP - 1);
                const unsigned short* gsrc = in +
                    (((size_t)nb * Hp + (row0 + r)) * Wp + (col0 + p)) * PS + ch * CIC + su * 8;
                unsigned short* ldst = sh + ((size_t)(r * ROW_SLOTS + seg * 64 + lane)) * 8;
                gl_lds16(gsrc, ldst);
            }
        }
        __syncthreads();
        int sbase = ch * (KT * CSTEPS);
#pragma unroll
        for (int tap = 0; tap < KT; ++tap) {
            const int r_l = tap / KW_, kwp = tap % KW_;
#pragma unroll
            for (int cs = 0; cs < CSTEPS; ++cs) {
                int s = sbase + tap * CSTEPS + cs;
                const uint4* wr = (const uint4*)wp + (size_t)(s * 4 + g) * Cout + cog * 64 + coh * 32 + m;
                FragU a0, a1;
                a0.u = wr[0];
                a1.u = wr[16];
#pragma unroll
                for (int u2 = 0; u2 < NT; ++u2) {
                    int sp_l = sph * (SPT / 2) + u2 * 16 + m;
                    int p = SW * sp_l + kwp;
                    int off = (cs * 32 + g * 8 + ((p & 7) << 3)) & (CIC - 1);
                    FragU bb;
                    bb.u = *(const uint4*)(sh + (size_t)(r_l * W_ST + p) * CIC + off);
                    acc[0][u2] = mfma16(a0.b, bb.b, acc[0][u2]);
                    acc[1][u2] = mfma16(a1.b, bb.b, acc[1][u2]);
                }
            }
        }
    }
    float ssql = 0.f;
#pragma unroll
    for (int a = 0; a < 2; ++a) {
        int co = cog * 64 + coh * 32 + a * 16 + g * 4;
        float4 bv = *(const float4*)(bias + co);
#pragma unroll
        for (int u2 = 0; u2 < NT; ++u2) {
            int ow = ow0 + sph * (SPT / 2) + u2 * 16 + m;
            float v0 = acc[a][u2][0] + bv.x;
            float v1 = acc[a][u2][1] + bv.y;
            float v2 = acc[a][u2][2] + bv.z;
            float v3 = acc[a][u2][3] + bv.w;
            if (relu) {
                v0 = fmaxf(v0, 0.f); v1 = fmaxf(v1, 0.f);
                v2 = fmaxf(v2, 0.f); v3 = fmaxf(v3, 0.f);
            }
            if constexpr (OUTM == 2) {
                unsigned short* zH = (unsigned short*)outp;
                size_t spg = ((size_t)nb * 64 + ohg) * 64 + ow;
                unsigned h0, l0, h1, l1;
                split2(v0, v1, h0, l0);
                split2(v2, v3, h1, l1);
                uint2 sth = {h0, h1}, stl = {l0, l1};
                *(uint2*)(zH + spg * 512 + co) = sth;
                *(uint2*)(outp2 + spg * 512 + co) = stl;
                ssql += v0 * v0 + v1 * v1 + v2 * v2 + v3 * v3;
            } else {
                unsigned short* ob = (unsigned short*)outp;
                int oho = PHASED ? 2 * ohg + ph : ohg;
                int owo = PHASED ? 2 * ow + pw : ow;
                uint2 st;
                if constexpr (OUTM == 3) st = (uint2){pack2h(v0, v1), pack2h(v2, v3)};
                else                     st = (uint2){pack2(v0, v1), pack2(v2, v3)};
                *(uint2*)(ob + (((size_t)nb * Hpo + oho + 1) * Wpo + (owo + 1)) * 64
                          + (coh * 32 + a * 16 + g * 4)) = st;
            }
        }
    }
    if constexpr (OUTM == 2) {
#pragma unroll
        for (int off = 1; off < 64; off <<= 1) ssql += __shfl_xor(ssql, off);
        if (lane == 0) redd[wv] = ssql;
        __syncthreads();
        if (t == 0) atomicAdd(ssqac, redd[0] + redd[1] + redd[2] + redd[3]);
    }
}

// ---- halo zeroing ----------------------------------------------------------
__global__ __launch_bounds__(256) void k_halo(unsigned short* buf, int Hp, int Wp, int PS)
{
    int per = 2 * Wp + 2 * (Hp - 2);
    int chunks = PS >> 3;
    int total = per * chunks;
    int n = blockIdx.y;
    for (int i = blockIdx.x * 256 + threadIdx.x; i < total; i += gridDim.x * 256) {
        int pix = i / chunks, c = i - pix * chunks;
        int h, w;
        if (pix < Wp) { h = 0; w = pix; }
        else if (pix < 2 * Wp) { h = Hp - 1; w = pix - Wp; }
        else { int q = pix - 2 * Wp; h = 1 + (q >> 1); w = (q & 1) ? (Wp - 1) : 0; }
        uint4 zz = {0, 0, 0, 0};
        *(uint4*)(buf + (((size_t)n * Hp + h) * Wp + w) * PS + c * 8) = zz;
    }
}

// ---- weight prep: conv [co][ci][kh][kw] fp32 -> fragment-order bf16 --------
__global__ __launch_bounds__(256) void k_prep_conv(const float* __restrict__ w,
    unsigned short* __restrict__ o, int Cout, int Cin, int T, int CIC)
{
    int idx = blockIdx.x * 256 + threadIdx.x;
    if (idx >= Cout * Cin * T) return;
    int tap = idx % T; int r = idx / T; int ci = r % Cin; int co = r / Cin;
    int chunk = ci / CIC, cil = ci % CIC;
    int k = chunk * (T * CIC) + tap * CIC + cil;
    int s = k >> 5, g = (k >> 3) & 3, j = k & 7;
    o[((size_t)(s * 4 + g) * Cout + co) * 8 + j] = (unsigned short)bf16rne(w[idx]);
}

// ---- weight prep: convT [ci][co][4][4] -> per-phase 2x2 fragment order -----
__global__ __launch_bounds__(256) void k_prep_wT(const float* __restrict__ w,
    unsigned short* __restrict__ o)
{
    int idx = blockIdx.x * 256 + threadIdx.x;     // 65536
    int ci = idx & 63; int r = idx >> 6;
    int jw = r & 1; r >>= 1;
    int jh = r & 1; r >>= 1;
    int co = r & 63; r >>= 6;
    int pw = r & 1; int ph = (r >> 1) & 1;
    int kh = (1 - ph) + 2 * (1 - jh);
    int kw = (1 - pw) + 2 * (1 - jw);
    int k = (jh * 2 + jw) * 64 + ci;
    int s = k >> 5, g = (k >> 3) & 3, j = k & 7;
    o[(size_t)(ph * 2 + pw) * 16384 + ((size_t)(s * 4 + g) * 64 + co) * 8 + j] =
        (unsigned short)bf16rne(w[((ci * 64 + co) * 4 + kh) * 4 + kw]);
}

// ---- codebook -> per-colblock, per-K-step contiguous fragment slabs --------
__global__ __launch_bounds__(256) void k_prep_cb(const float* __restrict__ cb,
    unsigned short* __restrict__ cbFH, unsigned short* __restrict__ cbFL)
{
    int i = blockIdx.x * 256 + threadIdx.x;   // 262144
    int c = i & 511, k = i >> 9;
    float v = cb[i];
    unsigned h = bf16rne(v);
    float lo = v - __uint_as_float(h << 16);
    unsigned l = bf16rne(lo);
    int cblk = k >> 7, kl = k & 127, s = c >> 5, g = (c >> 3) & 3, j = c & 7;
    size_t off = ((((size_t)cblk * 16 + s) * 4 + g) * 128 + kl) * 8 + j;
    cbFH[off] = (unsigned short)h;
    cbFL[off] = (unsigned short)l;
}

// ---- 0.5*||c||^2 -----------------------------------------------------------
__global__ __launch_bounds__(64) void k_prep(const float* __restrict__ cb,
    float* __restrict__ cn2)
{
    int k = blockIdx.x; int t = threadIdx.x;
    float s = 0.f;
#pragma unroll
    for (int i = 0; i < 8; ++i) {
        float v = cb[k * 512 + t + i * 64];
        s = fmaf(v, v, s);
    }
#pragma unroll
    for (int off = 32; off > 0; off >>= 1) s += __shfl_xor(s, off);
    if (t == 0) cn2[k] = 0.5f * s;
}

// ---- enc conv1: Cin=1, 4x4 s2 p1, ReLU -> bf16 NHWC padded ----------------
__global__ __launch_bounds__(256) void k_conv1(const float* __restrict__ x,
    const float* __restrict__ w, const float* __restrict__ b, unsigned short* __restrict__ out)
{
    __shared__ float ws[1024];
    __shared__ float bs[64];
    int t = threadIdx.x;
#pragma unroll
    for (int i = 0; i < 4; ++i) ws[t + 256 * i] = w[t + 256 * i];
    if (t < 64) bs[t] = b[t];
    __syncthreads();
    int oh = blockIdx.x;
    int n = blockIdx.y;
    int ow = t;
    const float* xn = x + (size_t)n * 262144;
    float xv[16];
#pragma unroll
    for (int kh = 0; kh < 4; ++kh) {
        int ih = 2 * oh - 1 + kh;
        bool rok = (unsigned)ih < 512u;
        int ihc = min(max(ih, 0), 511);
#pragma unroll
        for (int kw = 0; kw < 4; ++kw) {
            int iw = 2 * ow - 1 + kw;
            bool ok = rok && ((unsigned)iw < 512u);
            int iwc = min(max(iw, 0), 511);
            float v = xn[ihc * 512 + iwc];
            xv[kh * 4 + kw] = ok ? v : 0.f;
        }
    }
    unsigned short* on = out + (((size_t)n * 258 + oh + 1) * 258 + (ow + 1)) * 64;
    unsigned uo[32];
#pragma unroll
    for (int co2 = 0; co2 < 32; ++co2) {
        float a0 = bs[2 * co2], a1 = bs[2 * co2 + 1];
#pragma unroll
        for (int q = 0; q < 16; ++q) {
            a0 = fmaf(xv[q], ws[(2 * co2) * 16 + q], a0);
            a1 = fmaf(xv[q], ws[(2 * co2 + 1) * 16 + q], a1);
        }
        uo[co2] = pack2(fmaxf(a0, 0.f), fmaxf(a1, 0.f));
    }
#pragma unroll
    for (int i = 0; i < 8; ++i) {
        uint4 st = {uo[4 * i], uo[4 * i + 1], uo[4 * i + 2], uo[4 * i + 3]};
        *(uint4*)(on + i * 8) = st;
    }
}

// ---- VQ distance GEMM: scores[32768][512] tiled 128x128, split-bf16 --------
__global__ __launch_bounds__(256) void k_vqgemm(
    const unsigned short* __restrict__ zH, const unsigned short* __restrict__ zL,
    const unsigned short* __restrict__ cbFH, const unsigned short* __restrict__ cbFL,
    const float* __restrict__ cn2, float* __restrict__ candV, int* __restrict__ candI)
{
    __shared__ __align__(16) unsigned short shAH[5120];   // 128 rows x 40
    __shared__ __align__(16) unsigned short shAL[5120];
    __shared__ __align__(16) unsigned short shBH[4096];   // [g(4)][code(128)] x 8
    __shared__ __align__(16) unsigned short shBL[4096];
    __shared__ float cV[2][128];
    __shared__ int   cI[2][128];
    int t = threadIdx.x, lane = t & 63, wv = t >> 6;
    int wc = wv & 1, wr = wv >> 1;
    int m = lane & 15, g = lane >> 4;
    int cblk = blockIdx.x;
    int row0 = blockIdx.y * 128;

    f32x4_t acc[4][4];
#pragma unroll
    for (int a = 0; a < 4; ++a)
#pragma unroll
        for (int b = 0; b < 4; ++b) acc[a][b] = (f32x4_t){0.f, 0.f, 0.f, 0.f};

    const unsigned short* bsH = cbFH + (size_t)cblk * 65536;
    const unsigned short* bsL = cbFL + (size_t)cblk * 65536;

    for (int s = 0; s < 16; ++s) {
        __syncthreads();
        for (int q = t; q < 640; q += 256) {
            int r = q / 5, seg = q % 5, ss = seg & 3;
            size_t so = (size_t)(row0 + r) * 512 + s * 32 + ss * 8;
            gl_lds16(zH + so, shAH + q * 8);
            gl_lds16(zL + so, shAL + q * 8);
        }
        for (int q = t; q < 512; q += 256) {
            gl_lds16(bsH + (size_t)s * 4096 + q * 8, shBH + q * 8);
            gl_lds16(bsL + (size_t)s * 4096 + q * 8, shBL + q * 8);
        }
        __syncthreads();
        FragU Ah[4], Al[4], Bh[4], Bl[4];
#pragma unroll
        for (int mi = 0; mi < 4; ++mi) {
            int row = wr * 64 + mi * 16 + m;
            Ah[mi].u = *(const uint4*)(shAH + row * 40 + g * 8);
            Al[mi].u = *(const uint4*)(shAL + row * 40 + g * 8);
        }
#pragma unroll
        for (int ni = 0; ni < 4; ++ni) {
            int code = wc * 64 + ni * 16 + m;
            Bh[ni].u = *(const uint4*)(shBH + (g * 128 + code) * 8);
            Bl[ni].u = *(const uint4*)(shBL + (g * 128 + code) * 8);
        }
#pragma unroll
        for (int mi = 0; mi < 4; ++mi) {
#pragma unroll
            for (int ni = 0; ni < 4; ++ni) {
                acc[mi][ni] = mfma16(Ah[mi].b, Bh[ni].b, acc[mi][ni]);
                acc[mi][ni] = mfma16(Ah[mi].b, Bl[ni].b, acc[mi][ni]);
                acc[mi][ni] = mfma16(Al[mi].b, Bh[ni].b, acc[mi][ni]);
            }
        }
    }
    float bcn[4];
#pragma unroll
    for (int ni = 0; ni < 4; ++ni) bcn[ni] = cn2[cblk * 128 + wc * 64 + ni * 16 + m];
#pragma unroll
    for (int mi = 0; mi < 4; ++mi) {
#pragma unroll
        for (int r = 0; r < 4; ++r) {
            float best = -1e30f; int bi = 0;
#pragma unroll
            for (int ni = 0; ni < 4; ++ni) {
                float v = acc[mi][ni][r] - bcn[ni];
                int ix = cblk * 128 + wc * 64 + ni * 16 + m;
                if (v > best) { best = v; bi = ix; }
            }
#pragma unroll
            for (int off = 1; off < 16; off <<= 1) {
                float ov = __shfl_xor(best, off);
                int oi = __shfl_xor(bi, off);
                if (ov > best || (ov == best && oi < bi)) { best = ov; bi = oi; }
            }
            if (m == 0) {
                int rl = wr * 64 + mi * 16 + g * 4 + r;
                cV[wc][rl] = best;
                cI[wc][rl] = bi;
            }
        }
    }
    __syncthreads();
    if (t < 128) {
        float v0 = cV[0][t]; int i0 = cI[0][t];
        float v1 = cV[1][t]; int i1 = cI[1][t];
        if (v1 > v0 || (v1 == v0 && i1 < i0)) { v0 = v1; i0 = i1; }
        candV[(size_t)cblk * 32768 + row0 + t] = v0;
        candI[(size_t)cblk * 32768 + row0 + t] = i0;
    }
}

// ---- merge 4 candidates/row, emit idx + sum of max scores ------------------
__global__ __launch_bounds__(256) void k_vqred(const float* __restrict__ candV,
    const int* __restrict__ candI, int* __restrict__ vidx, float* __restrict__ ssum)
{
    __shared__ float redd[4];
    int t = threadIdx.x;
    int row = blockIdx.x * 256 + t;
    float b = candV[row]; int bi = candI[row];
#pragma unroll
    for (int cb = 1; cb < 4; ++cb) {
        float v = candV[cb * 32768 + row];
        int i = candI[cb * 32768 + row];
        if (v > b || (v == b && i < bi)) { b = v; bi = i; }
    }
    vidx[row] = bi;
#pragma unroll
    for (int off = 1; off < 64; off <<= 1) b += __shfl_xor(b, off);
    if ((t & 63) == 0) redd[t >> 6] = b;
    __syncthreads();
    if (t == 0) atomicAdd(ssum, redd[0] + redd[1] + redd[2] + redd[3]);
}

// ---- gather z_q -> padded NHWC bf16 [8,66,66,512] --------------------------
__global__ __launch_bounds__(256) void k_gather(const int* __restrict__ idx,
    const float* __restrict__ cb, unsigned short* __restrict__ zq)
{
    int t = threadIdx.x;
    int sp = blockIdx.x * 4 + (t >> 6);
    int lane = t & 63;
    int k = idx[sp];
    int n = sp >> 12, hw = sp & 4095, h = hw >> 6, w = hw & 63;
    const float* src = cb + (size_t)k * 512 + lane * 8;
    unsigned short* dst = zq + (((size_t)n * 66 + h + 1) * 66 + (w + 1)) * 512 + lane * 8;
    float4 v0 = *(const float4*)src, v1 = *(const float4*)(src + 4);
    uint4 st = {pack2(v0.x, v0.y), pack2(v0.z, v0.w), pack2(v1.x, v1.y), pack2(v1.z, v1.w)};
    *(uint4*)dst = st;
}

// ---- final conv-transpose 64 -> 1, sigmoid (LDS-staged, fp16 dot2) ---------
// Block: 4 output rows {4q-1..4q+2} x 256 cols. Needs padded input rows
// {2q, 2q+1, 2q+2} x 130 cols, staged to LDS with 16B source-side rotation.
__global__ __launch_bounds__(256) void k_convt_final2(const unsigned short* __restrict__ xp,
    const float* __restrict__ w, const float* __restrict__ b, float* __restrict__ out)
{
    __shared__ __align__(16) unsigned short shx[3 * 1040 * 8];  // fp16 bits
    __shared__ __align__(16) unsigned wp[16][32];               // fp16 pairs [tap][c2]
    int t = threadIdx.x, lane = t & 63, wv = t >> 6;
    int bx = blockIdx.x, q = blockIdx.y, n = blockIdx.z;
    int colbase = bx * 128;
#pragma unroll
    for (int i = 0; i < 2; ++i) {
        int qq = t + i * 256;
        int tap = qq >> 5, c2 = qq & 31;
        wp[tap][c2] = pack2h(w[(2 * c2) * 16 + tap], w[(2 * c2 + 1) * 16 + tap]);
    }
    const unsigned short* an = xp + (size_t)n * 258 * 258 * 64;
    // stage 3 rows x 130 px x 64 ch (slots of 8 fp16 = 16B)
    for (int u_ = wv; u_ < 51; u_ += 4) {
        int r = u_ / 17, seg = u_ % 17;
        int slot = seg * 64 + lane;
        if (slot < 1040) {
            int p = slot >> 3, uu = slot & 7;
            int su = (uu - p) & 7;
            int row = min(2 * q + r, 257);
            const unsigned short* gsrc = an + ((size_t)row * 258 + colbase + p) * 64 + su * 8;
            gl_lds16(gsrc, shx + ((size_t)(r * 1040 + slot)) * 8);
        }
    }
    __syncthreads();
    int ow = bx * 256 + t;
    int kwA = (ow + 1) & 1;
    int cA = ((ow + 1) >> 1) + 1 - colbase;
    int cB = cA - 1;
    float b0 = b[0];
    float acc0 = b0, acc1 = b0, acc2 = b0, acc3 = b0;
#pragma unroll
    for (int c8 = 0; c8 < 8; ++c8) {
        uint4 xr[3][2];
#pragma unroll
        for (int r = 0; r < 3; ++r) {
            xr[r][0] = *(const uint4*)(shx + (size_t)(r * 1040 + cB * 8 + ((c8 + cB) & 7)) * 8);
            xr[r][1] = *(const uint4*)(shx + (size_t)(r * 1040 + cA * 8 + ((c8 + cA) & 7)) * 8);
        }
        uint4 wA[4], wB[4];
#pragma unroll
        for (int kh = 0; kh < 4; ++kh) {
            wA[kh] = *(const uint4*)&wp[kh * 4 + kwA][c8 * 4];
            wB[kh] = *(const uint4*)&wp[kh * 4 + kwA + 2][c8 * 4];
        }
        acc0 = dot8(xr[1][1], wA[0], acc0); acc0 = dot8(xr[1][0], wB[0], acc0);
        acc0 = dot8(xr[0][1], wA[2], acc0); acc0 = dot8(xr[0][0], wB[2], acc0);
        acc1 = dot8(xr[1][1], wA[1], acc1); acc1 = dot8(xr[1][0], wB[1], acc1);
        acc1 = dot8(xr[0][1], wA[3], acc1); acc1 = dot8(xr[0][0], wB[3], acc1);
        acc2 = dot8(xr[2][1], wA[0], acc2); acc2 = dot8(xr[2][0], wB[0], acc2);
        acc2 = dot8(xr[1][1], wA[2], acc2); acc2 = dot8(xr[1][0], wB[2], acc2);
        acc3 = dot8(xr[2][1], wA[1], acc3); acc3 = dot8(xr[2][0], wB[1], acc3);
        acc3 = dot8(xr[1][1], wA[3], acc3); acc3 = dot8(xr[1][0], wB[3], acc3);
    }
    float accs[4] = {acc0, acc1, acc2, acc3};
    float* on = out + (size_t)n * 262144;
#pragma unroll
    for (int ro = 0; ro < 4; ++ro) {
        int oh = 4 * q - 1 + ro;
        if ((unsigned)oh < 512u)
            on[(size_t)oh * 512 + ow] = 1.0f / (1.0f + __expf(-accs[ro]));
    }
}

// ---- finalize loss: 1.25*(ssq - 2*scoresum)/N ------------------------------
__global__ void k_loss_final(const float* __restrict__ scal, float* __restrict__ out)
{
    if (threadIdx.x == 0 && blockIdx.x == 0)
        out[0] = 1.25f * (scal[0] - 2.f * scal[1]) * (1.0f / 16777216.0f);
}

// ---------------------------------------------------------------------------
extern "C" void kernel_launch(void* const* d_in, const int* in_sizes, int n_in,
                              void* d_out, int out_size, void* d_ws, size_t ws_size,
                              hipStream_t stream)
{
    const float* x      = (const float*)d_in[0];
    const float* enc_w1 = (const float*)d_in[1];
    const float* enc_b1 = (const float*)d_in[2];
    const float* enc_w2 = (const float*)d_in[3];
    const float* enc_b2 = (const float*)d_in[4];
    const float* enc_w3 = (const float*)d_in[5];
    const float* enc_b3 = (const float*)d_in[6];
    const float* enc_w4 = (const float*)d_in[7];
    const float* enc_b4 = (const float*)d_in[8];
    const float* cb     = (const float*)d_in[9];
    const float* dec_w1 = (const float*)d_in[10];
    const float* dec_b1 = (const float*)d_in[11];
    const float* tw1    = (const float*)d_in[12];
    const float* tb1    = (const float*)d_in[13];
    const float* tw2    = (const float*)d_in[14];
    const float* tb2    = (const float*)d_in[15];
    const float* tw3    = (const float*)d_in[16];
    const float* tb3    = (const float*)d_in[17];
    float* out = (float*)d_out;

    unsigned short* a1 = (unsigned short*)d_ws;        // 8*258*258*64
    unsigned short* a2 = a1 + 34076672;                // 8*130*130*64
    unsigned short* a3 = a2 + 8652800;                 // 8*66*66*64
    unsigned short* zH = a3 + 2230272;                 // 32768*512
    unsigned short* zL = zH + 16777216;                // 32768*512
    unsigned short* zq = zL + 16777216;                // 8*66*66*512
    unsigned short* d1 = zq + 17842176;                // 8*66*66*64
    unsigned short* wA2 = d1 + 2230272;                // 65536
    unsigned short* wA3 = wA2 + 65536;
    unsigned short* wB1 = wA3 + 65536;                 // 294912
    unsigned short* wB2 = wB1 + 294912;                // 294912
    unsigned short* wC1 = wB2 + 294912;                // 65536
    unsigned short* wC2 = wC1 + 65536;                 // 65536
    unsigned short* cbFH = wC2 + 65536;                // 262144
    unsigned short* cbFL = cbFH + 262144;              // 262144
    float* cn2 = (float*)(cbFL + 262144);              // 512
    int*   vidx = (int*)(cn2 + 512);                   // 32768
    float* candV = (float*)(vidx + 32768);             // 131072
    int*   candI = (int*)(candV + 131072);             // 131072
    float* scal = (float*)(candI + 131072);            // 2: [ssq, scoresum]

    hipMemsetAsync(scal, 0, 8, stream);

    // halos + preps
    k_halo<<<dim3(33, 8), 256, 0, stream>>>(a1, 258, 258, 64);
    k_halo<<<dim3(17, 8), 256, 0, stream>>>(a2, 130, 130, 64);
    k_halo<<<dim3(9, 8), 256, 0, stream>>>(a3, 66, 66, 64);
    k_halo<<<dim3(65, 8), 256, 0, stream>>>(zq, 66, 66, 512);
    k_halo<<<dim3(9, 8), 256, 0, stream>>>(d1, 66, 66, 64);
    k_prep<<<512, 64, 0, stream>>>(cb, cn2);
    k_prep_cb<<<1024, 256, 0, stream>>>(cb, cbFH, cbFL);
    k_prep_conv<<<256, 256, 0, stream>>>(enc_w2, wA2, 64, 64, 16, 64);
    k_prep_conv<<<256, 256, 0, stream>>>(enc_w3, wA3, 64, 64, 16, 64);
    k_prep_conv<<<1152, 256, 0, stream>>>(enc_w4, wB1, 512, 64, 9, 64);
    k_prep_conv<<<1152, 256, 0, stream>>>(dec_w1, wB2, 64, 512, 9, 128);
    k_prep_wT<<<256, 256, 0, stream>>>(tw1, wC1);
    k_prep_wT<<<256, 256, 0, stream>>>(tw2, wC2);

    // pipeline
    k_conv1<<<dim3(256, 8), 256, 0, stream>>>(x, enc_w1, enc_b1, a1);
    conv_mfma<4, 4, 2, 64, 32, 1, false, 0><<<dim3(4, 128, 8), 256, 0, stream>>>(
        a1, wA2, enc_b2, a2, 258, 258, 64, 1, 64, 1, 130, 130, 1, nullptr, nullptr);
    conv_mfma<4, 4, 2, 64, 32, 1, false, 0><<<dim3(2, 64, 8), 256, 0, stream>>>(
        a2, wA3, enc_b3, a3, 130, 130, 64, 1, 64, 1, 66, 66, 1, nullptr, nullptr);
    conv_mfma<3, 3, 1, 64, 64, 2, false, 2><<<dim3(1, 64, 64), 256, 0, stream>>>(
        a3, wB1, enc_b4, zH, 66, 66, 64, 1, 512, 8, 0, 0, 0, zL, scal);
    k_vqgemm<<<dim3(4, 256), 256, 0, stream>>>(zH, zL, cbFH, cbFL, cn2, candV, candI);
    k_vqred<<<128, 256, 0, stream>>>(candV, candI, vidx, scal + 1);
    k_gather<<<8192, 256, 0, stream>>>(vidx, cb, zq);
    conv_mfma<3, 3, 1, 128, 64, 2, false, 0><<<dim3(1, 64, 8), 256, 0, stream>>>(
        zq, wB2, dec_b1, d1, 66, 66, 512, 4, 64, 1, 66, 66, 1, nullptr, nullptr);
    conv_mfma<2, 2, 1, 64, 64, 2, true, 0><<<dim3(4, 64, 8), 256, 0, stream>>>(
        d1, wC1, tb1, a2, 66, 66, 64, 1, 64, 1, 130, 130, 1, nullptr, nullptr);
    conv_mfma<2, 2, 1, 64, 64, 2, true, 3><<<dim3(8, 128, 8), 256, 0, stream>>>(
        a2, wC2, tb2, a1, 130, 130, 64, 1, 64, 1, 258, 258, 1, nullptr, nullptr);
    k_convt_final2<<<dim3(2, 129, 8), 256, 0, stream>>>(a1, tw3, tb3, out);
    k_loss_final<<<1, 64, 0, stream>>>(scal, out + 2097152);
}

// Round 6
// 538.110 us; speedup vs baseline: 3.9956x; 1.0109x over previous
//
#include <hip/hip_runtime.h>
#include <math.h>

// ---------------------------------------------------------------------------
// VQ-VAE forward, bf16-MFMA. Round 6: k_vqgemm with B-from-L2 + XCD swizzle.
// ---------------------------------------------------------------------------

typedef __bf16 bf16x8_t __attribute__((ext_vector_type(8)));
typedef float f32x4_t __attribute__((ext_vector_type(4)));
typedef _Float16 h2_t __attribute__((ext_vector_type(2)));

union FragU { uint4 u; bf16x8_t b; };

__device__ inline f32x4_t mfma16(bf16x8_t a, bf16x8_t b, f32x4_t c) {
    return __builtin_amdgcn_mfma_f32_16x16x32_bf16(a, b, c, 0, 0, 0);
}

__device__ inline void gl_lds16(const void* g, void* l) {
    __builtin_amdgcn_global_load_lds((const __attribute__((address_space(1))) void*)g,
                                     (__attribute__((address_space(3))) void*)l, 16, 0, 0);
}

__device__ inline unsigned bf16rne(float f) {
    unsigned u = __float_as_uint(f);
    u += 0x7FFFu + ((u >> 16) & 1u);
    return u >> 16;
}
__device__ inline unsigned pack2(float lo, float hi) {
    return bf16rne(lo) | (bf16rne(hi) << 16);
}
__device__ inline unsigned pack2h(float lo, float hi) {
    union { h2_t h; unsigned u; } r;
    r.h[0] = (_Float16)lo; r.h[1] = (_Float16)hi;
    return r.u;
}
__device__ inline float bl(unsigned u) { return __uint_as_float(u << 16); }
__device__ inline float bh(unsigned u) { return __uint_as_float(u & 0xffff0000u); }
__device__ inline void split2(float x, float y, unsigned& h, unsigned& l) {
    unsigned hx = bf16rne(x), hy = bf16rne(y);
    float rx = x - __uint_as_float(hx << 16);
    float ry = y - __uint_as_float(hy << 16);
    h = hx | (hy << 16);
    l = bf16rne(rx) | (bf16rne(ry) << 16);
}

#if defined(__has_builtin)
#if __has_builtin(__builtin_amdgcn_fdot2)
#define HAS_FDOT2 1
#endif
#endif

__device__ inline float dot2h(unsigned x, unsigned w, float a) {
#ifdef HAS_FDOT2
    union { unsigned u; h2_t h; } ax, bw;
    ax.u = x; bw.u = w;
    return __builtin_amdgcn_fdot2(ax.h, bw.h, a, false);
#else
    union { unsigned u; _Float16 h[2]; } ax, bw;
    ax.u = x; bw.u = w;
    a = fmaf((float)ax.h[0], (float)bw.h[0], a);
    return fmaf((float)ax.h[1], (float)bw.h[1], a);
#endif
}
__device__ inline float dot8(uint4 x, uint4 w, float a) {
    a = dot2h(x.x, w.x, a); a = dot2h(x.y, w.y, a);
    a = dot2h(x.z, w.z, a); a = dot2h(x.w, w.w, a);
    return a;
}

// ---- generic implicit-GEMM conv -------------------------------------------
// OUTM: 0 = bf16 NHWC halo store, 2 = split zH/zL + global ssq atomic,
//       3 = fp16 NHWC halo store.
template<int NR, int KW_, int SW, int CIC, int SPT, int NT, bool PHASED, int OUTM>
__global__ __launch_bounds__(256) void conv_mfma(
    const unsigned short* __restrict__ in, const unsigned short* __restrict__ wp,
    const float* __restrict__ bias, void* __restrict__ outp,
    int Hp, int Wp, int PS, int nchunks, int Cout, int ncog,
    int Hpo, int Wpo, int relu,
    unsigned short* __restrict__ outp2, float* __restrict__ ssqac)
{
    constexpr int W_ST = SW * (SPT - 1) + KW_;
    constexpr int SLOTS_PP = CIC / 8;
    constexpr int ROW_SLOTS = W_ST * SLOTS_PP;
    constexpr int SEGS = (ROW_SLOTS + 63) / 64;
    constexpr int KT = NR * KW_;
    constexpr int CSTEPS = CIC / 32;
    __shared__ __align__(16) unsigned short sh[NR * W_ST * CIC];
    __shared__ float redd[4];

    int t = threadIdx.x, lane = t & 63, wv = t >> 6;
    int bx = blockIdx.x;
    int ph = 0, pw = 0, owt = bx;
    if (PHASED) { int phs = bx & 3; ph = phs >> 1; pw = phs & 1; owt = bx >> 2; }
    int ohg = blockIdx.y;
    int bz = blockIdx.z; int nb = bz / ncog; int cog = bz % ncog;
    int ow0 = owt * SPT;
    int row0 = SW * ohg + (PHASED ? ph : 0);
    int col0 = SW * ow0 + (PHASED ? pw : 0);
    int coh = wv & 1;
    int sph = wv >> 1;
    int m = lane & 15, g = lane >> 4;

    if (PHASED) wp += (size_t)(ph * 2 + pw) * Cout * KT * CIC;

    f32x4_t acc[2][NT];
#pragma unroll
    for (int a = 0; a < 2; ++a)
#pragma unroll
        for (int u2 = 0; u2 < NT; ++u2) acc[a][u2] = (f32x4_t){0.f, 0.f, 0.f, 0.f};

    for (int ch = 0; ch < nchunks; ++ch) {
        if (ch) __syncthreads();
        for (int u_ = wv; u_ < NR * SEGS; u_ += 4) {
            int r = u_ / SEGS, seg = u_ - r * SEGS;
            int slot = seg * 64 + lane;
            int p = slot / SLOTS_PP;
            int uu = slot & (SLOTS_PP - 1);
            if (p < W_ST) {
                int su = (uu - (p & 7)) & (SLOTS_PP - 1);
                const unsigned short* gsrc = in +
                    (((size_t)nb * Hp + (row0 + r)) * Wp + (col0 + p)) * PS + ch * CIC + su * 8;
                unsigned short* ldst = sh + ((size_t)(r * ROW_SLOTS + seg * 64 + lane)) * 8;
                gl_lds16(gsrc, ldst);
            }
        }
        __syncthreads();
        int sbase = ch * (KT * CSTEPS);
#pragma unroll
        for (int tap = 0; tap < KT; ++tap) {
            const int r_l = tap / KW_, kwp = tap % KW_;
#pragma unroll
            for (int cs = 0; cs < CSTEPS; ++cs) {
                int s = sbase + tap * CSTEPS + cs;
                const uint4* wr = (const uint4*)wp + (size_t)(s * 4 + g) * Cout + cog * 64 + coh * 32 + m;
                FragU a0, a1;
                a0.u = wr[0];
                a1.u = wr[16];
#pragma unroll
                for (int u2 = 0; u2 < NT; ++u2) {
                    int sp_l = sph * (SPT / 2) + u2 * 16 + m;
                    int p = SW * sp_l + kwp;
                    int off = (cs * 32 + g * 8 + ((p & 7) << 3)) & (CIC - 1);
                    FragU bb;
                    bb.u = *(const uint4*)(sh + (size_t)(r_l * W_ST + p) * CIC + off);
                    acc[0][u2] = mfma16(a0.b, bb.b, acc[0][u2]);
                    acc[1][u2] = mfma16(a1.b, bb.b, acc[1][u2]);
                }
            }
        }
    }
    float ssql = 0.f;
#pragma unroll
    for (int a = 0; a < 2; ++a) {
        int co = cog * 64 + coh * 32 + a * 16 + g * 4;
        float4 bv = *(const float4*)(bias + co);
#pragma unroll
        for (int u2 = 0; u2 < NT; ++u2) {
            int ow = ow0 + sph * (SPT / 2) + u2 * 16 + m;
            float v0 = acc[a][u2][0] + bv.x;
            float v1 = acc[a][u2][1] + bv.y;
            float v2 = acc[a][u2][2] + bv.z;
            float v3 = acc[a][u2][3] + bv.w;
            if (relu) {
                v0 = fmaxf(v0, 0.f); v1 = fmaxf(v1, 0.f);
                v2 = fmaxf(v2, 0.f); v3 = fmaxf(v3, 0.f);
            }
            if constexpr (OUTM == 2) {
                unsigned short* zH = (unsigned short*)outp;
                size_t spg = ((size_t)nb * 64 + ohg) * 64 + ow;
                unsigned h0, l0, h1, l1;
                split2(v0, v1, h0, l0);
                split2(v2, v3, h1, l1);
                uint2 sth = {h0, h1}, stl = {l0, l1};
                *(uint2*)(zH + spg * 512 + co) = sth;
                *(uint2*)(outp2 + spg * 512 + co) = stl;
                ssql += v0 * v0 + v1 * v1 + v2 * v2 + v3 * v3;
            } else {
                unsigned short* ob = (unsigned short*)outp;
                int oho = PHASED ? 2 * ohg + ph : ohg;
                int owo = PHASED ? 2 * ow + pw : ow;
                uint2 st;
                if constexpr (OUTM == 3) st = (uint2){pack2h(v0, v1), pack2h(v2, v3)};
                else                     st = (uint2){pack2(v0, v1), pack2(v2, v3)};
                *(uint2*)(ob + (((size_t)nb * Hpo + oho + 1) * Wpo + (owo + 1)) * 64
                          + (coh * 32 + a * 16 + g * 4)) = st;
            }
        }
    }
    if constexpr (OUTM == 2) {
#pragma unroll
        for (int off = 1; off < 64; off <<= 1) ssql += __shfl_xor(ssql, off);
        if (lane == 0) redd[wv] = ssql;
        __syncthreads();
        if (t == 0) atomicAdd(ssqac, redd[0] + redd[1] + redd[2] + redd[3]);
    }
}

// ---- halo zeroing ----------------------------------------------------------
__global__ __launch_bounds__(256) void k_halo(unsigned short* buf, int Hp, int Wp, int PS)
{
    int per = 2 * Wp + 2 * (Hp - 2);
    int chunks = PS >> 3;
    int total = per * chunks;
    int n = blockIdx.y;
    for (int i = blockIdx.x * 256 + threadIdx.x; i < total; i += gridDim.x * 256) {
        int pix = i / chunks, c = i - pix * chunks;
        int h, w;
        if (pix < Wp) { h = 0; w = pix; }
        else if (pix < 2 * Wp) { h = Hp - 1; w = pix - Wp; }
        else { int q = pix - 2 * Wp; h = 1 + (q >> 1); w = (q & 1) ? (Wp - 1) : 0; }
        uint4 zz = {0, 0, 0, 0};
        *(uint4*)(buf + (((size_t)n * Hp + h) * Wp + w) * PS + c * 8) = zz;
    }
}

// ---- weight prep: conv [co][ci][kh][kw] fp32 -> fragment-order bf16 --------
__global__ __launch_bounds__(256) void k_prep_conv(const float* __restrict__ w,
    unsigned short* __restrict__ o, int Cout, int Cin, int T, int CIC)
{
    int idx = blockIdx.x * 256 + threadIdx.x;
    if (idx >= Cout * Cin * T) return;
    int tap = idx % T; int r = idx / T; int ci = r % Cin; int co = r / Cin;
    int chunk = ci / CIC, cil = ci % CIC;
    int k = chunk * (T * CIC) + tap * CIC + cil;
    int s = k >> 5, g = (k >> 3) & 3, j = k & 7;
    o[((size_t)(s * 4 + g) * Cout + co) * 8 + j] = (unsigned short)bf16rne(w[idx]);
}

// ---- weight prep: convT [ci][co][4][4] -> per-phase 2x2 fragment order -----
__global__ __launch_bounds__(256) void k_prep_wT(const float* __restrict__ w,
    unsigned short* __restrict__ o)
{
    int idx = blockIdx.x * 256 + threadIdx.x;     // 65536
    int ci = idx & 63; int r = idx >> 6;
    int jw = r & 1; r >>= 1;
    int jh = r & 1; r >>= 1;
    int co = r & 63; r >>= 6;
    int pw = r & 1; int ph = (r >> 1) & 1;
    int kh = (1 - ph) + 2 * (1 - jh);
    int kw = (1 - pw) + 2 * (1 - jw);
    int k = (jh * 2 + jw) * 64 + ci;
    int s = k >> 5, g = (k >> 3) & 3, j = k & 7;
    o[(size_t)(ph * 2 + pw) * 16384 + ((size_t)(s * 4 + g) * 64 + co) * 8 + j] =
        (unsigned short)bf16rne(w[((ci * 64 + co) * 4 + kh) * 4 + kw]);
}

// ---- codebook -> per-colblock, per-K-step contiguous fragment slabs --------
__global__ __launch_bounds__(256) void k_prep_cb(const float* __restrict__ cb,
    unsigned short* __restrict__ cbFH, unsigned short* __restrict__ cbFL)
{
    int i = blockIdx.x * 256 + threadIdx.x;   // 262144
    int c = i & 511, k = i >> 9;
    float v = cb[i];
    unsigned h = bf16rne(v);
    float lo = v - __uint_as_float(h << 16);
    unsigned l = bf16rne(lo);
    int cblk = k >> 7, kl = k & 127, s = c >> 5, g = (c >> 3) & 3, j = c & 7;
    size_t off = ((((size_t)cblk * 16 + s) * 4 + g) * 128 + kl) * 8 + j;
    cbFH[off] = (unsigned short)h;
    cbFL[off] = (unsigned short)l;
}

// ---- 0.5*||c||^2 -----------------------------------------------------------
__global__ __launch_bounds__(64) void k_prep(const float* __restrict__ cb,
    float* __restrict__ cn2)
{
    int k = blockIdx.x; int t = threadIdx.x;
    float s = 0.f;
#pragma unroll
    for (int i = 0; i < 8; ++i) {
        float v = cb[k * 512 + t + i * 64];
        s = fmaf(v, v, s);
    }
#pragma unroll
    for (int off = 32; off > 0; off >>= 1) s += __shfl_xor(s, off);
    if (t == 0) cn2[k] = 0.5f * s;
}

// ---- enc conv1: Cin=1, 4x4 s2 p1, ReLU -> bf16 NHWC padded ----------------
__global__ __launch_bounds__(256) void k_conv1(const float* __restrict__ x,
    const float* __restrict__ w, const float* __restrict__ b, unsigned short* __restrict__ out)
{
    __shared__ float ws[1024];
    __shared__ float bs[64];
    int t = threadIdx.x;
#pragma unroll
    for (int i = 0; i < 4; ++i) ws[t + 256 * i] = w[t + 256 * i];
    if (t < 64) bs[t] = b[t];
    __syncthreads();
    int oh = blockIdx.x;
    int n = blockIdx.y;
    int ow = t;
    const float* xn = x + (size_t)n * 262144;
    float xv[16];
#pragma unroll
    for (int kh = 0; kh < 4; ++kh) {
        int ih = 2 * oh - 1 + kh;
        bool rok = (unsigned)ih < 512u;
        int ihc = min(max(ih, 0), 511);
#pragma unroll
        for (int kw = 0; kw < 4; ++kw) {
            int iw = 2 * ow - 1 + kw;
            bool ok = rok && ((unsigned)iw < 512u);
            int iwc = min(max(iw, 0), 511);
            float v = xn[ihc * 512 + iwc];
            xv[kh * 4 + kw] = ok ? v : 0.f;
        }
    }
    unsigned short* on = out + (((size_t)n * 258 + oh + 1) * 258 + (ow + 1)) * 64;
    unsigned uo[32];
#pragma unroll
    for (int co2 = 0; co2 < 32; ++co2) {
        float a0 = bs[2 * co2], a1 = bs[2 * co2 + 1];
#pragma unroll
        for (int q = 0; q < 16; ++q) {
            a0 = fmaf(xv[q], ws[(2 * co2) * 16 + q], a0);
            a1 = fmaf(xv[q], ws[(2 * co2 + 1) * 16 + q], a1);
        }
        uo[co2] = pack2(fmaxf(a0, 0.f), fmaxf(a1, 0.f));
    }
#pragma unroll
    for (int i = 0; i < 8; ++i) {
        uint4 st = {uo[4 * i], uo[4 * i + 1], uo[4 * i + 2], uo[4 * i + 3]};
        *(uint4*)(on + i * 8) = st;
    }
}

// ---- VQ distance GEMM: 128x128 tiles, split-bf16, B from L2, XCD swizzle ---
// Linear grid 1024: xcd = L&7 groups the 4 column blocks of one row tile on
// one XCD (z tile L2-shared). A staged to LDS; B read direct (coalesced,
// L2-resident fragment slabs). Fused per-block argmax -> 4 candidates/row.
__global__ __launch_bounds__(256) void k_vqgemm(
    const unsigned short* __restrict__ zH, const unsigned short* __restrict__ zL,
    const unsigned short* __restrict__ cbFH, const unsigned short* __restrict__ cbFL,
    const float* __restrict__ cn2, float* __restrict__ candV, int* __restrict__ candI)
{
    __shared__ __align__(16) unsigned short shAH[5120];   // 128 rows x 40
    __shared__ __align__(16) unsigned short shAL[5120];
    __shared__ float cV[2][128];
    __shared__ int   cI[2][128];
    int t = threadIdx.x, lane = t & 63, wv = t >> 6;
    int wc = wv & 1, wr = wv >> 1;
    int m = lane & 15, g = lane >> 4;
    int L = blockIdx.x;
    int xcd = L & 7, kk = L >> 3;
    int cblk = kk & 3;
    int row0 = ((kk >> 2) + xcd * 32) * 128;

    f32x4_t acc[4][4];
#pragma unroll
    for (int a = 0; a < 4; ++a)
#pragma unroll
        for (int b = 0; b < 4; ++b) acc[a][b] = (f32x4_t){0.f, 0.f, 0.f, 0.f};

    const uint4* bH = (const uint4*)cbFH + (size_t)cblk * 8192;
    const uint4* bL = (const uint4*)cbFL + (size_t)cblk * 8192;

    for (int s = 0; s < 16; ++s) {
        __syncthreads();
        for (int q = t; q < 640; q += 256) {
            int r = q / 5, seg = q % 5, ss = seg & 3;
            size_t so = (size_t)(row0 + r) * 512 + s * 32 + ss * 8;
            gl_lds16(zH + so, shAH + q * 8);
            gl_lds16(zL + so, shAL + q * 8);
        }
        // B fragments direct from global (L2) — overlaps the staging drain
        FragU Bh[4], Bl[4];
#pragma unroll
        for (int ni = 0; ni < 4; ++ni) {
            int i4 = (s * 4 + g) * 128 + wc * 64 + ni * 16 + m;
            Bh[ni].u = bH[i4];
            Bl[ni].u = bL[i4];
        }
        __syncthreads();
        FragU Ah[4], Al[4];
#pragma unroll
        for (int mi = 0; mi < 4; ++mi) {
            int row = wr * 64 + mi * 16 + m;
            Ah[mi].u = *(const uint4*)(shAH + row * 40 + g * 8);
            Al[mi].u = *(const uint4*)(shAL + row * 40 + g * 8);
        }
#pragma unroll
        for (int mi = 0; mi < 4; ++mi) {
#pragma unroll
            for (int ni = 0; ni < 4; ++ni) {
                acc[mi][ni] = mfma16(Ah[mi].b, Bh[ni].b, acc[mi][ni]);
                acc[mi][ni] = mfma16(Ah[mi].b, Bl[ni].b, acc[mi][ni]);
                acc[mi][ni] = mfma16(Al[mi].b, Bh[ni].b, acc[mi][ni]);
            }
        }
    }
    float bcn[4];
#pragma unroll
    for (int ni = 0; ni < 4; ++ni) bcn[ni] = cn2[cblk * 128 + wc * 64 + ni * 16 + m];
#pragma unroll
    for (int mi = 0; mi < 4; ++mi) {
#pragma unroll
        for (int r = 0; r < 4; ++r) {
            float best = -1e30f; int bi = 0;
#pragma unroll
            for (int ni = 0; ni < 4; ++ni) {
                float v = acc[mi][ni][r] - bcn[ni];
                int ix = cblk * 128 + wc * 64 + ni * 16 + m;
                if (v > best) { best = v; bi = ix; }
            }
#pragma unroll
            for (int off = 1; off < 16; off <<= 1) {
                float ov = __shfl_xor(best, off);
                int oi = __shfl_xor(bi, off);
                if (ov > best || (ov == best && oi < bi)) { best = ov; bi = oi; }
            }
            if (m == 0) {
                int rl = wr * 64 + mi * 16 + g * 4 + r;
                cV[wc][rl] = best;
                cI[wc][rl] = bi;
            }
        }
    }
    __syncthreads();
    if (t < 128) {
        float v0 = cV[0][t]; int i0 = cI[0][t];
        float v1 = cV[1][t]; int i1 = cI[1][t];
        if (v1 > v0 || (v1 == v0 && i1 < i0)) { v0 = v1; i0 = i1; }
        candV[(size_t)cblk * 32768 + row0 + t] = v0;
        candI[(size_t)cblk * 32768 + row0 + t] = i0;
    }
}

// ---- merge 4 candidates/row, emit idx + sum of max scores ------------------
__global__ __launch_bounds__(256) void k_vqred(const float* __restrict__ candV,
    const int* __restrict__ candI, int* __restrict__ vidx, float* __restrict__ ssum)
{
    __shared__ float redd[4];
    int t = threadIdx.x;
    int row = blockIdx.x * 256 + t;
    float b = candV[row]; int bi = candI[row];
#pragma unroll
    for (int cb = 1; cb < 4; ++cb) {
        float v = candV[cb * 32768 + row];
        int i = candI[cb * 32768 + row];
        if (v > b || (v == b && i < bi)) { b = v; bi = i; }
    }
    vidx[row] = bi;
#pragma unroll
    for (int off = 1; off < 64; off <<= 1) b += __shfl_xor(b, off);
    if ((t & 63) == 0) redd[t >> 6] = b;
    __syncthreads();
    if (t == 0) atomicAdd(ssum, redd[0] + redd[1] + redd[2] + redd[3]);
}

// ---- gather z_q -> padded NHWC bf16 [8,66,66,512] --------------------------
__global__ __launch_bounds__(256) void k_gather(const int* __restrict__ idx,
    const float* __restrict__ cb, unsigned short* __restrict__ zq)
{
    int t = threadIdx.x;
    int sp = blockIdx.x * 4 + (t >> 6);
    int lane = t & 63;
    int k = idx[sp];
    int n = sp >> 12, hw = sp & 4095, h = hw >> 6, w = hw & 63;
    const float* src = cb + (size_t)k * 512 + lane * 8;
    unsigned short* dst = zq + (((size_t)n * 66 + h + 1) * 66 + (w + 1)) * 512 + lane * 8;
    float4 v0 = *(const float4*)src, v1 = *(const float4*)(src + 4);
    uint4 st = {pack2(v0.x, v0.y), pack2(v0.z, v0.w), pack2(v1.x, v1.y), pack2(v1.z, v1.w)};
    *(uint4*)dst = st;
}

// ---- final conv-transpose 64 -> 1, sigmoid (LDS-staged, fp16 dot2) ---------
__global__ __launch_bounds__(256) void k_convt_final2(const unsigned short* __restrict__ xp,
    const float* __restrict__ w, const float* __restrict__ b, float* __restrict__ out)
{
    __shared__ __align__(16) unsigned short shx[3 * 1040 * 8];  // fp16 bits
    __shared__ __align__(16) unsigned wp[16][32];               // fp16 pairs [tap][c2]
    int t = threadIdx.x, lane = t & 63, wv = t >> 6;
    int bx = blockIdx.x, q = blockIdx.y, n = blockIdx.z;
    int colbase = bx * 128;
#pragma unroll
    for (int i = 0; i < 2; ++i) {
        int qq = t + i * 256;
        int tap = qq >> 5, c2 = qq & 31;
        wp[tap][c2] = pack2h(w[(2 * c2) * 16 + tap], w[(2 * c2 + 1) * 16 + tap]);
    }
    const unsigned short* an = xp + (size_t)n * 258 * 258 * 64;
    for (int u_ = wv; u_ < 51; u_ += 4) {
        int r = u_ / 17, seg = u_ % 17;
        int slot = seg * 64 + lane;
        if (slot < 1040) {
            int p = slot >> 3, uu = slot & 7;
            int su = (uu - p) & 7;
            int row = min(2 * q + r, 257);
            const unsigned short* gsrc = an + ((size_t)row * 258 + colbase + p) * 64 + su * 8;
            gl_lds16(gsrc, shx + ((size_t)(r * 1040 + slot)) * 8);
        }
    }
    __syncthreads();
    int ow = bx * 256 + t;
    int kwA = (ow + 1) & 1;
    int cA = ((ow + 1) >> 1) + 1 - colbase;
    int cB = cA - 1;
    float b0 = b[0];
    float acc0 = b0, acc1 = b0, acc2 = b0, acc3 = b0;
#pragma unroll
    for (int c8 = 0; c8 < 8; ++c8) {
        uint4 xr[3][2];
#pragma unroll
        for (int r = 0; r < 3; ++r) {
            xr[r][0] = *(const uint4*)(shx + (size_t)(r * 1040 + cB * 8 + ((c8 + cB) & 7)) * 8);
            xr[r][1] = *(const uint4*)(shx + (size_t)(r * 1040 + cA * 8 + ((c8 + cA) & 7)) * 8);
        }
        uint4 wA[4], wB[4];
#pragma unroll
        for (int kh = 0; kh < 4; ++kh) {
            wA[kh] = *(const uint4*)&wp[kh * 4 + kwA][c8 * 4];
            wB[kh] = *(const uint4*)&wp[kh * 4 + kwA + 2][c8 * 4];
        }
        acc0 = dot8(xr[1][1], wA[0], acc0); acc0 = dot8(xr[1][0], wB[0], acc0);
        acc0 = dot8(xr[0][1], wA[2], acc0); acc0 = dot8(xr[0][0], wB[2], acc0);
        acc1 = dot8(xr[1][1], wA[1], acc1); acc1 = dot8(xr[1][0], wB[1], acc1);
        acc1 = dot8(xr[0][1], wA[3], acc1); acc1 = dot8(xr[0][0], wB[3], acc1);
        acc2 = dot8(xr[2][1], wA[0], acc2); acc2 = dot8(xr[2][0], wB[0], acc2);
        acc2 = dot8(xr[1][1], wA[2], acc2); acc2 = dot8(xr[1][0], wB[2], acc2);
        acc3 = dot8(xr[2][1], wA[1], acc3); acc3 = dot8(xr[2][0], wB[1], acc3);
        acc3 = dot8(xr[1][1], wA[3], acc3); acc3 = dot8(xr[1][0], wB[3], acc3);
    }
    float accs[4] = {acc0, acc1, acc2, acc3};
    float* on = out + (size_t)n * 262144;
#pragma unroll
    for (int ro = 0; ro < 4; ++ro) {
        int oh = 4 * q - 1 + ro;
        if ((unsigned)oh < 512u)
            on[(size_t)oh * 512 + ow] = 1.0f / (1.0f + __expf(-accs[ro]));
    }
}

// ---- finalize loss: 1.25*(ssq - 2*scoresum)/N ------------------------------
__global__ void k_loss_final(const float* __restrict__ scal, float* __restrict__ out)
{
    if (threadIdx.x == 0 && blockIdx.x == 0)
        out[0] = 1.25f * (scal[0] - 2.f * scal[1]) * (1.0f / 16777216.0f);
}

// ---------------------------------------------------------------------------
extern "C" void kernel_launch(void* const* d_in, const int* in_sizes, int n_in,
                              void* d_out, int out_size, void* d_ws, size_t ws_size,
                              hipStream_t stream)
{
    const float* x      = (const float*)d_in[0];
    const float* enc_w1 = (const float*)d_in[1];
    const float* enc_b1 = (const float*)d_in[2];
    const float* enc_w2 = (const float*)d_in[3];
    const float* enc_b2 = (const float*)d_in[4];
    const float* enc_w3 = (const float*)d_in[5];
    const float* enc_b3 = (const float*)d_in[6];
    const float* enc_w4 = (const float*)d_in[7];
    const float* enc_b4 = (const float*)d_in[8];
    const float* cb     = (const float*)d_in[9];
    const float* dec_w1 = (const float*)d_in[10];
    const float* dec_b1 = (const float*)d_in[11];
    const float* tw1    = (const float*)d_in[12];
    const float* tb1    = (const float*)d_in[13];
    const float* tw2    = (const float*)d_in[14];
    const float* tb2    = (const float*)d_in[15];
    const float* tw3    = (const float*)d_in[16];
    const float* tb3    = (const float*)d_in[17];
    float* out = (float*)d_out;

    unsigned short* a1 = (unsigned short*)d_ws;        // 8*258*258*64
    unsigned short* a2 = a1 + 34076672;                // 8*130*130*64
    unsigned short* a3 = a2 + 8652800;                 // 8*66*66*64
    unsigned short* zH = a3 + 2230272;                 // 32768*512
    unsigned short* zL = zH + 16777216;                // 32768*512
    unsigned short* zq = zL + 16777216;                // 8*66*66*512
    unsigned short* d1 = zq + 17842176;                // 8*66*66*64
    unsigned short* wA2 = d1 + 2230272;                // 65536
    unsigned short* wA3 = wA2 + 65536;
    unsigned short* wB1 = wA3 + 65536;                 // 294912
    unsigned short* wB2 = wB1 + 294912;                // 294912
    unsigned short* wC1 = wB2 + 294912;                // 65536
    unsigned short* wC2 = wC1 + 65536;                 // 65536
    unsigned short* cbFH = wC2 + 65536;                // 262144
    unsigned short* cbFL = cbFH + 262144;              // 262144
    float* cn2 = (float*)(cbFL + 262144);              // 512
    int*   vidx = (int*)(cn2 + 512);                   // 32768
    float* candV = (float*)(vidx + 32768);             // 131072
    int*   candI = (int*)(candV + 131072);             // 131072
    float* scal = (float*)(candI + 131072);            // 2: [ssq, scoresum]

    hipMemsetAsync(scal, 0, 8, stream);

    // halos + preps
    k_halo<<<dim3(33, 8), 256, 0, stream>>>(a1, 258, 258, 64);
    k_halo<<<dim3(17, 8), 256, 0, stream>>>(a2, 130, 130, 64);
    k_halo<<<dim3(9, 8), 256, 0, stream>>>(a3, 66, 66, 64);
    k_halo<<<dim3(65, 8), 256, 0, stream>>>(zq, 66, 66, 512);
    k_halo<<<dim3(9, 8), 256, 0, stream>>>(d1, 66, 66, 64);
    k_prep<<<512, 64, 0, stream>>>(cb, cn2);
    k_prep_cb<<<1024, 256, 0, stream>>>(cb, cbFH, cbFL);
    k_prep_conv<<<256, 256, 0, stream>>>(enc_w2, wA2, 64, 64, 16, 64);
    k_prep_conv<<<256, 256, 0, stream>>>(enc_w3, wA3, 64, 64, 16, 64);
    k_prep_conv<<<1152, 256, 0, stream>>>(enc_w4, wB1, 512, 64, 9, 64);
    k_prep_conv<<<1152, 256, 0, stream>>>(dec_w1, wB2, 64, 512, 9, 128);
    k_prep_wT<<<256, 256, 0, stream>>>(tw1, wC1);
    k_prep_wT<<<256, 256, 0, stream>>>(tw2, wC2);

    // pipeline
    k_conv1<<<dim3(256, 8), 256, 0, stream>>>(x, enc_w1, enc_b1, a1);
    conv_mfma<4, 4, 2, 64, 32, 1, false, 0><<<dim3(4, 128, 8), 256, 0, stream>>>(
        a1, wA2, enc_b2, a2, 258, 258, 64, 1, 64, 1, 130, 130, 1, nullptr, nullptr);
    conv_mfma<4, 4, 2, 64, 32, 1, false, 0><<<dim3(2, 64, 8), 256, 0, stream>>>(
        a2, wA3, enc_b3, a3, 130, 130, 64, 1, 64, 1, 66, 66, 1, nullptr, nullptr);
    conv_mfma<3, 3, 1, 64, 64, 2, false, 2><<<dim3(1, 64, 64), 256, 0, stream>>>(
        a3, wB1, enc_b4, zH, 66, 66, 64, 1, 512, 8, 0, 0, 0, zL, scal);
    k_vqgemm<<<1024, 256, 0, stream>>>(zH, zL, cbFH, cbFL, cn2, candV, candI);
    k_vqred<<<128, 256, 0, stream>>>(candV, candI, vidx, scal + 1);
    k_gather<<<8192, 256, 0, stream>>>(vidx, cb, zq);
    conv_mfma<3, 3, 1, 128, 64, 2, false, 0><<<dim3(1, 64, 8), 256, 0, stream>>>(
        zq, wB2, dec_b1, d1, 66, 66, 512, 4, 64, 1, 66, 66, 1, nullptr, nullptr);
    conv_mfma<2, 2, 1, 64, 64, 2, true, 0><<<dim3(4, 64, 8), 256, 0, stream>>>(
        d1, wC1, tb1, a2, 66, 66, 64, 1, 64, 1, 130, 130, 1, nullptr, nullptr);
    conv_mfma<2, 2, 1, 64, 64, 2, true, 3><<<dim3(8, 128, 8), 256, 0, stream>>>(
        a2, wC2, tb2, a1, 130, 130, 64, 1, 64, 1, 258, 258, 1, nullptr, nullptr);
    k_convt_final2<<<dim3(2, 129, 8), 256, 0, stream>>>(a1, tw3, tb3, out);
    k_loss_final<<<1, 64, 0, stream>>>(scal, out + 2097152);
}

// Round 7
// 513.443 us; speedup vs baseline: 4.1876x; 1.0480x over previous
//
#include <hip/hip_runtime.h>
#include <math.h>

// ---------------------------------------------------------------------------
// VQ-VAE forward, bf16-MFMA. Round 7: dedicated 128x128-tile enc4 GEMM-conv.
// ---------------------------------------------------------------------------

typedef __bf16 bf16x8_t __attribute__((ext_vector_type(8)));
typedef float f32x4_t __attribute__((ext_vector_type(4)));
typedef _Float16 h2_t __attribute__((ext_vector_type(2)));

union FragU { uint4 u; bf16x8_t b; };

__device__ inline f32x4_t mfma16(bf16x8_t a, bf16x8_t b, f32x4_t c) {
    return __builtin_amdgcn_mfma_f32_16x16x32_bf16(a, b, c, 0, 0, 0);
}

__device__ inline void gl_lds16(const void* g, void* l) {
    __builtin_amdgcn_global_load_lds((const __attribute__((address_space(1))) void*)g,
                                     (__attribute__((address_space(3))) void*)l, 16, 0, 0);
}

__device__ inline unsigned bf16rne(float f) {
    unsigned u = __float_as_uint(f);
    u += 0x7FFFu + ((u >> 16) & 1u);
    return u >> 16;
}
__device__ inline unsigned pack2(float lo, float hi) {
    return bf16rne(lo) | (bf16rne(hi) << 16);
}
__device__ inline unsigned pack2h(float lo, float hi) {
    union { h2_t h; unsigned u; } r;
    r.h[0] = (_Float16)lo; r.h[1] = (_Float16)hi;
    return r.u;
}
__device__ inline float bl(unsigned u) { return __uint_as_float(u << 16); }
__device__ inline float bh(unsigned u) { return __uint_as_float(u & 0xffff0000u); }
__device__ inline void split2(float x, float y, unsigned& h, unsigned& l) {
    unsigned hx = bf16rne(x), hy = bf16rne(y);
    float rx = x - __uint_as_float(hx << 16);
    float ry = y - __uint_as_float(hy << 16);
    h = hx | (hy << 16);
    l = bf16rne(rx) | (bf16rne(ry) << 16);
}

#if defined(__has_builtin)
#if __has_builtin(__builtin_amdgcn_fdot2)
#define HAS_FDOT2 1
#endif
#endif

__device__ inline float dot2h(unsigned x, unsigned w, float a) {
#ifdef HAS_FDOT2
    union { unsigned u; h2_t h; } ax, bw;
    ax.u = x; bw.u = w;
    return __builtin_amdgcn_fdot2(ax.h, bw.h, a, false);
#else
    union { unsigned u; _Float16 h[2]; } ax, bw;
    ax.u = x; bw.u = w;
    a = fmaf((float)ax.h[0], (float)bw.h[0], a);
    return fmaf((float)ax.h[1], (float)bw.h[1], a);
#endif
}
__device__ inline float dot8(uint4 x, uint4 w, float a) {
    a = dot2h(x.x, w.x, a); a = dot2h(x.y, w.y, a);
    a = dot2h(x.z, w.z, a); a = dot2h(x.w, w.w, a);
    return a;
}

// ---- generic implicit-GEMM conv -------------------------------------------
// OUTM: 0 = bf16 NHWC halo store, 3 = fp16 NHWC halo store.
template<int NR, int KW_, int SW, int CIC, int SPT, int NT, bool PHASED, int OUTM>
__global__ __launch_bounds__(256) void conv_mfma(
    const unsigned short* __restrict__ in, const unsigned short* __restrict__ wp,
    const float* __restrict__ bias, void* __restrict__ outp,
    int Hp, int Wp, int PS, int nchunks, int Cout, int ncog,
    int Hpo, int Wpo, int relu)
{
    constexpr int W_ST = SW * (SPT - 1) + KW_;
    constexpr int SLOTS_PP = CIC / 8;
    constexpr int ROW_SLOTS = W_ST * SLOTS_PP;
    constexpr int SEGS = (ROW_SLOTS + 63) / 64;
    constexpr int KT = NR * KW_;
    constexpr int CSTEPS = CIC / 32;
    __shared__ __align__(16) unsigned short sh[NR * W_ST * CIC];

    int t = threadIdx.x, lane = t & 63, wv = t >> 6;
    int bx = blockIdx.x;
    int ph = 0, pw = 0, owt = bx;
    if (PHASED) { int phs = bx & 3; ph = phs >> 1; pw = phs & 1; owt = bx >> 2; }
    int ohg = blockIdx.y;
    int bz = blockIdx.z; int nb = bz / ncog; int cog = bz % ncog;
    int ow0 = owt * SPT;
    int row0 = SW * ohg + (PHASED ? ph : 0);
    int col0 = SW * ow0 + (PHASED ? pw : 0);
    int coh = wv & 1;
    int sph = wv >> 1;
    int m = lane & 15, g = lane >> 4;

    if (PHASED) wp += (size_t)(ph * 2 + pw) * Cout * KT * CIC;

    f32x4_t acc[2][NT];
#pragma unroll
    for (int a = 0; a < 2; ++a)
#pragma unroll
        for (int u2 = 0; u2 < NT; ++u2) acc[a][u2] = (f32x4_t){0.f, 0.f, 0.f, 0.f};

    for (int ch = 0; ch < nchunks; ++ch) {
        if (ch) __syncthreads();
        for (int u_ = wv; u_ < NR * SEGS; u_ += 4) {
            int r = u_ / SEGS, seg = u_ - r * SEGS;
            int slot = seg * 64 + lane;
            int p = slot / SLOTS_PP;
            int uu = slot & (SLOTS_PP - 1);
            if (p < W_ST) {
                int su = (uu - (p & 7)) & (SLOTS_PP - 1);
                const unsigned short* gsrc = in +
                    (((size_t)nb * Hp + (row0 + r)) * Wp + (col0 + p)) * PS + ch * CIC + su * 8;
                unsigned short* ldst = sh + ((size_t)(r * ROW_SLOTS + seg * 64 + lane)) * 8;
                gl_lds16(gsrc, ldst);
            }
        }
        __syncthreads();
        int sbase = ch * (KT * CSTEPS);
#pragma unroll
        for (int tap = 0; tap < KT; ++tap) {
            const int r_l = tap / KW_, kwp = tap % KW_;
#pragma unroll
            for (int cs = 0; cs < CSTEPS; ++cs) {
                int s = sbase + tap * CSTEPS + cs;
                const uint4* wr = (const uint4*)wp + (size_t)(s * 4 + g) * Cout + cog * 64 + coh * 32 + m;
                FragU a0, a1;
                a0.u = wr[0];
                a1.u = wr[16];
#pragma unroll
                for (int u2 = 0; u2 < NT; ++u2) {
                    int sp_l = sph * (SPT / 2) + u2 * 16 + m;
                    int p = SW * sp_l + kwp;
                    int off = (cs * 32 + g * 8 + ((p & 7) << 3)) & (CIC - 1);
                    FragU bb;
                    bb.u = *(const uint4*)(sh + (size_t)(r_l * W_ST + p) * CIC + off);
                    acc[0][u2] = mfma16(a0.b, bb.b, acc[0][u2]);
                    acc[1][u2] = mfma16(a1.b, bb.b, acc[1][u2]);
                }
            }
        }
    }
#pragma unroll
    for (int a = 0; a < 2; ++a) {
        int co = cog * 64 + coh * 32 + a * 16 + g * 4;
        float4 bv = *(const float4*)(bias + co);
#pragma unroll
        for (int u2 = 0; u2 < NT; ++u2) {
            int ow = ow0 + sph * (SPT / 2) + u2 * 16 + m;
            float v0 = acc[a][u2][0] + bv.x;
            float v1 = acc[a][u2][1] + bv.y;
            float v2 = acc[a][u2][2] + bv.z;
            float v3 = acc[a][u2][3] + bv.w;
            if (relu) {
                v0 = fmaxf(v0, 0.f); v1 = fmaxf(v1, 0.f);
                v2 = fmaxf(v2, 0.f); v3 = fmaxf(v3, 0.f);
            }
            unsigned short* ob = (unsigned short*)outp;
            int oho = PHASED ? 2 * ohg + ph : ohg;
            int owo = PHASED ? 2 * ow + pw : ow;
            uint2 st;
            if constexpr (OUTM == 3) st = (uint2){pack2h(v0, v1), pack2h(v2, v3)};
            else                     st = (uint2){pack2(v0, v1), pack2(v2, v3)};
            *(uint2*)(ob + (((size_t)nb * Hpo + oho + 1) * Wpo + (owo + 1)) * 64
                      + (coh * 32 + a * 16 + g * 4)) = st;
        }
    }
}

// ---- enc4: 3x3 s1 conv 64->512 on 64x64, 128sp x 128co tiles, split z out --
// Input a3 padded NHWC bf16 [8,66,66,64]. Output zH/zL row-major [32768][512]
// + global ssq atomic. Grid 1024 linear, XCD swizzle.
__global__ __launch_bounds__(256) void k_enc4(
    const unsigned short* __restrict__ a3, const unsigned short* __restrict__ wp,
    const float* __restrict__ bias, unsigned short* __restrict__ zH,
    unsigned short* __restrict__ zL, float* __restrict__ ssqac)
{
    __shared__ __align__(16) unsigned short sh[16896];   // 4*528*8 = 33792 B = 128*132
    __shared__ float redd[4];
    int t = threadIdx.x, lane = t & 63, wv = t >> 6;
    int wc = wv & 1, wr = wv >> 1;
    int m = lane & 15, g = lane >> 4;
    int L = blockIdx.x;
    int xcd = L & 7, j = L >> 3;
    int cog = j & 3;
    int rt = (j >> 2) + xcd * 32;           // 0..255 row-tile
    int row0 = rt * 128;
    int n = row0 >> 12;
    int oh0 = (row0 & 4095) >> 6;           // even, rows oh0, oh0+1

    // stage 4 padded input rows x 66 px x 64 ch with 16B rotation
    const unsigned short* an = a3 + ((size_t)(n * 66 + oh0) * 66) * 64;
    for (int seg = wv; seg < 33; seg += 4) {
        int slot = seg * 64 + lane;
        if (slot < 2112) {
            int r = slot / 528, rest = slot - r * 528;
            int p = rest >> 3, uu = rest & 7;
            int su = (uu - p) & 7;
            gl_lds16(an + ((size_t)(r * 66 + p)) * 64 + su * 8, sh + (size_t)slot * 8);
        }
    }
    f32x4_t acc[4][4];
#pragma unroll
    for (int a = 0; a < 4; ++a)
#pragma unroll
        for (int b = 0; b < 4; ++b) acc[a][b] = (f32x4_t){0.f, 0.f, 0.f, 0.f};
    __syncthreads();

#pragma unroll
    for (int tap = 0; tap < 9; ++tap) {
        const int kh = tap / 3, kwp = tap % 3;
#pragma unroll
        for (int cs = 0; cs < 2; ++cs) {
            int s = tap * 2 + cs;
            const uint4* wr4 = (const uint4*)wp + (size_t)(s * 4 + g) * 512 + cog * 128 + wc * 64 + m;
            FragU A[4];
#pragma unroll
            for (int ci = 0; ci < 4; ++ci) A[ci].u = wr4[ci * 16];
#pragma unroll
            for (int si = 0; si < 4; ++si) {
                int sp_l = wr * 64 + si * 16 + m;
                int r_l = (sp_l >> 6) + kh;
                int px = (sp_l & 63) + kwp;
                int off = (cs * 4 + g + px) & 7;
                FragU B;
                B.u = *(const uint4*)(sh + ((size_t)(r_l * 528 + px * 8 + off)) * 8);
#pragma unroll
                for (int ci = 0; ci < 4; ++ci)
                    acc[ci][si] = mfma16(A[ci].b, B.b, acc[ci][si]);
            }
        }
    }
    // bias per ci
    float4 bv[4];
#pragma unroll
    for (int ci = 0; ci < 4; ++ci)
        bv[ci] = *(const float4*)(bias + cog * 128 + wc * 64 + ci * 16 + g * 4);

    // ---- H pass: split-high to LDS [row(128)][132 shorts], + ssq ----------
    __syncthreads();
    float ssql = 0.f;
#pragma unroll
    for (int ci = 0; ci < 4; ++ci) {
#pragma unroll
        for (int si = 0; si < 4; ++si) {
            float v0 = acc[ci][si][0] + bv[ci].x;
            float v1 = acc[ci][si][1] + bv[ci].y;
            float v2 = acc[ci][si][2] + bv[ci].z;
            float v3 = acc[ci][si][3] + bv[ci].w;
            ssql += v0 * v0 + v1 * v1 + v2 * v2 + v3 * v3;
            unsigned h0, l0, h1, l1;
            split2(v0, v1, h0, l0);
            split2(v2, v3, h1, l1);
            int row = wr * 64 + si * 16 + m;
            int col = wc * 64 + ci * 16 + g * 4;
            *(uint2*)(sh + (size_t)row * 132 + col) = (uint2){h0, h1};
        }
    }
    __syncthreads();
#pragma unroll
    for (int i = 0; i < 8; ++i) {
        int idx = i * 256 + t;
        int row = idx >> 4, c16 = idx & 15;
        uint4 v = *(const uint4*)(sh + (size_t)row * 132 + c16 * 8);
        *(uint4*)(zH + (size_t)(row0 + row) * 512 + cog * 128 + c16 * 8) = v;
    }
    // ---- L pass -----------------------------------------------------------
    __syncthreads();
#pragma unroll
    for (int ci = 0; ci < 4; ++ci) {
#pragma unroll
        for (int si = 0; si < 4; ++si) {
            float v0 = acc[ci][si][0] + bv[ci].x;
            float v1 = acc[ci][si][1] + bv[ci].y;
            float v2 = acc[ci][si][2] + bv[ci].z;
            float v3 = acc[ci][si][3] + bv[ci].w;
            unsigned h0, l0, h1, l1;
            split2(v0, v1, h0, l0);
            split2(v2, v3, h1, l1);
            int row = wr * 64 + si * 16 + m;
            int col = wc * 64 + ci * 16 + g * 4;
            *(uint2*)(sh + (size_t)row * 132 + col) = (uint2){l0, l1};
        }
    }
    __syncthreads();
#pragma unroll
    for (int i = 0; i < 8; ++i) {
        int idx = i * 256 + t;
        int row = idx >> 4, c16 = idx & 15;
        uint4 v = *(const uint4*)(sh + (size_t)row * 132 + c16 * 8);
        *(uint4*)(zL + (size_t)(row0 + row) * 512 + cog * 128 + c16 * 8) = v;
    }
    // ssq reduce
#pragma unroll
    for (int off = 1; off < 64; off <<= 1) ssql += __shfl_xor(ssql, off);
    if (lane == 0) redd[wv] = ssql;
    __syncthreads();
    if (t == 0) atomicAdd(ssqac, redd[0] + redd[1] + redd[2] + redd[3]);
}

// ---- halo zeroing ----------------------------------------------------------
__global__ __launch_bounds__(256) void k_halo(unsigned short* buf, int Hp, int Wp, int PS)
{
    int per = 2 * Wp + 2 * (Hp - 2);
    int chunks = PS >> 3;
    int total = per * chunks;
    int n = blockIdx.y;
    for (int i = blockIdx.x * 256 + threadIdx.x; i < total; i += gridDim.x * 256) {
        int pix = i / chunks, c = i - pix * chunks;
        int h, w;
        if (pix < Wp) { h = 0; w = pix; }
        else if (pix < 2 * Wp) { h = Hp - 1; w = pix - Wp; }
        else { int q = pix - 2 * Wp; h = 1 + (q >> 1); w = (q & 1) ? (Wp - 1) : 0; }
        uint4 zz = {0, 0, 0, 0};
        *(uint4*)(buf + (((size_t)n * Hp + h) * Wp + w) * PS + c * 8) = zz;
    }
}

// ---- weight prep: conv [co][ci][kh][kw] fp32 -> fragment-order bf16 --------
__global__ __launch_bounds__(256) void k_prep_conv(const float* __restrict__ w,
    unsigned short* __restrict__ o, int Cout, int Cin, int T, int CIC)
{
    int idx = blockIdx.x * 256 + threadIdx.x;
    if (idx >= Cout * Cin * T) return;
    int tap = idx % T; int r = idx / T; int ci = r % Cin; int co = r / Cin;
    int chunk = ci / CIC, cil = ci % CIC;
    int k = chunk * (T * CIC) + tap * CIC + cil;
    int s = k >> 5, g = (k >> 3) & 3, j = k & 7;
    o[((size_t)(s * 4 + g) * Cout + co) * 8 + j] = (unsigned short)bf16rne(w[idx]);
}

// ---- weight prep: convT [ci][co][4][4] -> per-phase 2x2 fragment order -----
__global__ __launch_bounds__(256) void k_prep_wT(const float* __restrict__ w,
    unsigned short* __restrict__ o)
{
    int idx = blockIdx.x * 256 + threadIdx.x;     // 65536
    int ci = idx & 63; int r = idx >> 6;
    int jw = r & 1; r >>= 1;
    int jh = r & 1; r >>= 1;
    int co = r & 63; r >>= 6;
    int pw = r & 1; int ph = (r >> 1) & 1;
    int kh = (1 - ph) + 2 * (1 - jh);
    int kw = (1 - pw) + 2 * (1 - jw);
    int k = (jh * 2 + jw) * 64 + ci;
    int s = k >> 5, g = (k >> 3) & 3, j = k & 7;
    o[(size_t)(ph * 2 + pw) * 16384 + ((size_t)(s * 4 + g) * 64 + co) * 8 + j] =
        (unsigned short)bf16rne(w[((ci * 64 + co) * 4 + kh) * 4 + kw]);
}

// ---- codebook -> per-colblock, per-K-step contiguous fragment slabs --------
__global__ __launch_bounds__(256) void k_prep_cb(const float* __restrict__ cb,
    unsigned short* __restrict__ cbFH, unsigned short* __restrict__ cbFL)
{
    int i = blockIdx.x * 256 + threadIdx.x;   // 262144
    int c = i & 511, k = i >> 9;
    float v = cb[i];
    unsigned h = bf16rne(v);
    float lo = v - __uint_as_float(h << 16);
    unsigned l = bf16rne(lo);
    int cblk = k >> 7, kl = k & 127, s = c >> 5, g = (c >> 3) & 3, j = c & 7;
    size_t off = ((((size_t)cblk * 16 + s) * 4 + g) * 128 + kl) * 8 + j;
    cbFH[off] = (unsigned short)h;
    cbFL[off] = (unsigned short)l;
}

// ---- 0.5*||c||^2 -----------------------------------------------------------
__global__ __launch_bounds__(64) void k_prep(const float* __restrict__ cb,
    float* __restrict__ cn2)
{
    int k = blockIdx.x; int t = threadIdx.x;
    float s = 0.f;
#pragma unroll
    for (int i = 0; i < 8; ++i) {
        float v = cb[k * 512 + t + i * 64];
        s = fmaf(v, v, s);
    }
#pragma unroll
    for (int off = 32; off > 0; off >>= 1) s += __shfl_xor(s, off);
    if (t == 0) cn2[k] = 0.5f * s;
}

// ---- enc conv1: Cin=1, 4x4 s2 p1, ReLU -> bf16 NHWC padded ----------------
__global__ __launch_bounds__(256) void k_conv1(const float* __restrict__ x,
    const float* __restrict__ w, const float* __restrict__ b, unsigned short* __restrict__ out)
{
    __shared__ float ws[1024];
    __shared__ float bs[64];
    int t = threadIdx.x;
#pragma unroll
    for (int i = 0; i < 4; ++i) ws[t + 256 * i] = w[t + 256 * i];
    if (t < 64) bs[t] = b[t];
    __syncthreads();
    int oh = blockIdx.x;
    int n = blockIdx.y;
    int ow = t;
    const float* xn = x + (size_t)n * 262144;
    float xv[16];
#pragma unroll
    for (int kh = 0; kh < 4; ++kh) {
        int ih = 2 * oh - 1 + kh;
        bool rok = (unsigned)ih < 512u;
        int ihc = min(max(ih, 0), 511);
#pragma unroll
        for (int kw = 0; kw < 4; ++kw) {
            int iw = 2 * ow - 1 + kw;
            bool ok = rok && ((unsigned)iw < 512u);
            int iwc = min(max(iw, 0), 511);
            float v = xn[ihc * 512 + iwc];
            xv[kh * 4 + kw] = ok ? v : 0.f;
        }
    }
    unsigned short* on = out + (((size_t)n * 258 + oh + 1) * 258 + (ow + 1)) * 64;
    unsigned uo[32];
#pragma unroll
    for (int co2 = 0; co2 < 32; ++co2) {
        float a0 = bs[2 * co2], a1 = bs[2 * co2 + 1];
#pragma unroll
        for (int q = 0; q < 16; ++q) {
            a0 = fmaf(xv[q], ws[(2 * co2) * 16 + q], a0);
            a1 = fmaf(xv[q], ws[(2 * co2 + 1) * 16 + q], a1);
        }
        uo[co2] = pack2(fmaxf(a0, 0.f), fmaxf(a1, 0.f));
    }
#pragma unroll
    for (int i = 0; i < 8; ++i) {
        uint4 st = {uo[4 * i], uo[4 * i + 1], uo[4 * i + 2], uo[4 * i + 3]};
        *(uint4*)(on + i * 8) = st;
    }
}

// ---- VQ distance GEMM: 128x128 tiles, split-bf16, B from L2, XCD swizzle ---
__global__ __launch_bounds__(256) void k_vqgemm(
    const unsigned short* __restrict__ zH, const unsigned short* __restrict__ zL,
    const unsigned short* __restrict__ cbFH, const unsigned short* __restrict__ cbFL,
    const float* __restrict__ cn2, float* __restrict__ candV, int* __restrict__ candI)
{
    __shared__ __align__(16) unsigned short shAH[5120];   // 128 rows x 40
    __shared__ __align__(16) unsigned short shAL[5120];
    __shared__ float cV[2][128];
    __shared__ int   cI[2][128];
    int t = threadIdx.x, lane = t & 63, wv = t >> 6;
    int wc = wv & 1, wr = wv >> 1;
    int m = lane & 15, g = lane >> 4;
    int L = blockIdx.x;
    int xcd = L & 7, kk = L >> 3;
    int cblk = kk & 3;
    int row0 = ((kk >> 2) + xcd * 32) * 128;

    f32x4_t acc[4][4];
#pragma unroll
    for (int a = 0; a < 4; ++a)
#pragma unroll
        for (int b = 0; b < 4; ++b) acc[a][b] = (f32x4_t){0.f, 0.f, 0.f, 0.f};

    const uint4* bH = (const uint4*)cbFH + (size_t)cblk * 8192;
    const uint4* bL = (const uint4*)cbFL + (size_t)cblk * 8192;

    for (int s = 0; s < 16; ++s) {
        __syncthreads();
        for (int q = t; q < 640; q += 256) {
            int r = q / 5, seg = q % 5, ss = seg & 3;
            size_t so = (size_t)(row0 + r) * 512 + s * 32 + ss * 8;
            gl_lds16(zH + so, shAH + q * 8);
            gl_lds16(zL + so, shAL + q * 8);
        }
        FragU Bh[4], Bl[4];
#pragma unroll
        for (int ni = 0; ni < 4; ++ni) {
            int i4 = (s * 4 + g) * 128 + wc * 64 + ni * 16 + m;
            Bh[ni].u = bH[i4];
            Bl[ni].u = bL[i4];
        }
        __syncthreads();
        FragU Ah[4], Al[4];
#pragma unroll
        for (int mi = 0; mi < 4; ++mi) {
            int row = wr * 64 + mi * 16 + m;
            Ah[mi].u = *(const uint4*)(shAH + row * 40 + g * 8);
            Al[mi].u = *(const uint4*)(shAL + row * 40 + g * 8);
        }
#pragma unroll
        for (int mi = 0; mi < 4; ++mi) {
#pragma unroll
            for (int ni = 0; ni < 4; ++ni) {
                acc[mi][ni] = mfma16(Ah[mi].b, Bh[ni].b, acc[mi][ni]);
                acc[mi][ni] = mfma16(Ah[mi].b, Bl[ni].b, acc[mi][ni]);
                acc[mi][ni] = mfma16(Al[mi].b, Bh[ni].b, acc[mi][ni]);
            }
        }
    }
    float bcn[4];
#pragma unroll
    for (int ni = 0; ni < 4; ++ni) bcn[ni] = cn2[cblk * 128 + wc * 64 + ni * 16 + m];
#pragma unroll
    for (int mi = 0; mi < 4; ++mi) {
#pragma unroll
        for (int r = 0; r < 4; ++r) {
            float best = -1e30f; int bi = 0;
#pragma unroll
            for (int ni = 0; ni < 4; ++ni) {
                float v = acc[mi][ni][r] - bcn[ni];
                int ix = cblk * 128 + wc * 64 + ni * 16 + m;
                if (v > best) { best = v; bi = ix; }
            }
#pragma unroll
            for (int off = 1; off < 16; off <<= 1) {
                float ov = __shfl_xor(best, off);
                int oi = __shfl_xor(bi, off);
                if (ov > best || (ov == best && oi < bi)) { best = ov; bi = oi; }
            }
            if (m == 0) {
                int rl = wr * 64 + mi * 16 + g * 4 + r;
                cV[wc][rl] = best;
                cI[wc][rl] = bi;
            }
        }
    }
    __syncthreads();
    if (t < 128) {
        float v0 = cV[0][t]; int i0 = cI[0][t];
        float v1 = cV[1][t]; int i1 = cI[1][t];
        if (v1 > v0 || (v1 == v0 && i1 < i0)) { v0 = v1; i0 = i1; }
        candV[(size_t)cblk * 32768 + row0 + t] = v0;
        candI[(size_t)cblk * 32768 + row0 + t] = i0;
    }
}

// ---- merge 4 candidates/row, emit idx + sum of max scores ------------------
__global__ __launch_bounds__(256) void k_vqred(const float* __restrict__ candV,
    const int* __restrict__ candI, int* __restrict__ vidx, float* __restrict__ ssum)
{
    __shared__ float redd[4];
    int t = threadIdx.x;
    int row = blockIdx.x * 256 + t;
    float b = candV[row]; int bi = candI[row];
#pragma unroll
    for (int cb = 1; cb < 4; ++cb) {
        float v = candV[cb * 32768 + row];
        int i = candI[cb * 32768 + row];
        if (v > b || (v == b && i < bi)) { b = v; bi = i; }
    }
    vidx[row] = bi;
#pragma unroll
    for (int off = 1; off < 64; off <<= 1) b += __shfl_xor(b, off);
    if ((t & 63) == 0) redd[t >> 6] = b;
    __syncthreads();
    if (t == 0) atomicAdd(ssum, redd[0] + redd[1] + redd[2] + redd[3]);
}

// ---- gather z_q -> padded NHWC bf16 [8,66,66,512] --------------------------
__global__ __launch_bounds__(256) void k_gather(const int* __restrict__ idx,
    const float* __restrict__ cb, unsigned short* __restrict__ zq)
{
    int t = threadIdx.x;
    int sp = blockIdx.x * 4 + (t >> 6);
    int lane = t & 63;
    int k = idx[sp];
    int n = sp >> 12, hw = sp & 4095, h = hw >> 6, w = hw & 63;
    const float* src = cb + (size_t)k * 512 + lane * 8;
    unsigned short* dst = zq + (((size_t)n * 66 + h + 1) * 66 + (w + 1)) * 512 + lane * 8;
    float4 v0 = *(const float4*)src, v1 = *(const float4*)(src + 4);
    uint4 st = {pack2(v0.x, v0.y), pack2(v0.z, v0.w), pack2(v1.x, v1.y), pack2(v1.z, v1.w)};
    *(uint4*)dst = st;
}

// ---- final conv-transpose 64 -> 1, sigmoid (LDS-staged, fp16 dot2) ---------
__global__ __launch_bounds__(256) void k_convt_final2(const unsigned short* __restrict__ xp,
    const float* __restrict__ w, const float* __restrict__ b, float* __restrict__ out)
{
    __shared__ __align__(16) unsigned short shx[3 * 1040 * 8];  // fp16 bits
    __shared__ __align__(16) unsigned wp[16][32];               // fp16 pairs [tap][c2]
    int t = threadIdx.x, lane = t & 63, wv = t >> 6;
    int bx = blockIdx.x, q = blockIdx.y, n = blockIdx.z;
    int colbase = bx * 128;
#pragma unroll
    for (int i = 0; i < 2; ++i) {
        int qq = t + i * 256;
        int tap = qq >> 5, c2 = qq & 31;
        wp[tap][c2] = pack2h(w[(2 * c2) * 16 + tap], w[(2 * c2 + 1) * 16 + tap]);
    }
    const unsigned short* an = xp + (size_t)n * 258 * 258 * 64;
    for (int u_ = wv; u_ < 51; u_ += 4) {
        int r = u_ / 17, seg = u_ % 17;
        int slot = seg * 64 + lane;
        if (slot < 1040) {
            int p = slot >> 3, uu = slot & 7;
            int su = (uu - p) & 7;
            int row = min(2 * q + r, 257);
            const unsigned short* gsrc = an + ((size_t)row * 258 + colbase + p) * 64 + su * 8;
            gl_lds16(gsrc, shx + ((size_t)(r * 1040 + slot)) * 8);
        }
    }
    __syncthreads();
    int ow = bx * 256 + t;
    int kwA = (ow + 1) & 1;
    int cA = ((ow + 1) >> 1) + 1 - colbase;
    int cB = cA - 1;
    float b0 = b[0];
    float acc0 = b0, acc1 = b0, acc2 = b0, acc3 = b0;
#pragma unroll
    for (int c8 = 0; c8 < 8; ++c8) {
        uint4 xr[3][2];
#pragma unroll
        for (int r = 0; r < 3; ++r) {
            xr[r][0] = *(const uint4*)(shx + (size_t)(r * 1040 + cB * 8 + ((c8 + cB) & 7)) * 8);
            xr[r][1] = *(const uint4*)(shx + (size_t)(r * 1040 + cA * 8 + ((c8 + cA) & 7)) * 8);
        }
        uint4 wA[4], wB[4];
#pragma unroll
        for (int kh = 0; kh < 4; ++kh) {
            wA[kh] = *(const uint4*)&wp[kh * 4 + kwA][c8 * 4];
            wB[kh] = *(const uint4*)&wp[kh * 4 + kwA + 2][c8 * 4];
        }
        acc0 = dot8(xr[1][1], wA[0], acc0); acc0 = dot8(xr[1][0], wB[0], acc0);
        acc0 = dot8(xr[0][1], wA[2], acc0); acc0 = dot8(xr[0][0], wB[2], acc0);
        acc1 = dot8(xr[1][1], wA[1], acc1); acc1 = dot8(xr[1][0], wB[1], acc1);
        acc1 = dot8(xr[0][1], wA[3], acc1); acc1 = dot8(xr[0][0], wB[3], acc1);
        acc2 = dot8(xr[2][1], wA[0], acc2); acc2 = dot8(xr[2][0], wB[0], acc2);
        acc2 = dot8(xr[1][1], wA[2], acc2); acc2 = dot8(xr[1][0], wB[2], acc2);
        acc3 = dot8(xr[2][1], wA[1], acc3); acc3 = dot8(xr[2][0], wB[1], acc3);
        acc3 = dot8(xr[1][1], wA[3], acc3); acc3 = dot8(xr[1][0], wB[3], acc3);
    }
    float accs[4] = {acc0, acc1, acc2, acc3};
    float* on = out + (size_t)n * 262144;
#pragma unroll
    for (int ro = 0; ro < 4; ++ro) {
        int oh = 4 * q - 1 + ro;
        if ((unsigned)oh < 512u)
            on[(size_t)oh * 512 + ow] = 1.0f / (1.0f + __expf(-accs[ro]));
    }
}

// ---- finalize loss: 1.25*(ssq - 2*scoresum)/N ------------------------------
__global__ void k_loss_final(const float* __restrict__ scal, float* __restrict__ out)
{
    if (threadIdx.x == 0 && blockIdx.x == 0)
        out[0] = 1.25f * (scal[0] - 2.f * scal[1]) * (1.0f / 16777216.0f);
}

// ---------------------------------------------------------------------------
extern "C" void kernel_launch(void* const* d_in, const int* in_sizes, int n_in,
                              void* d_out, int out_size, void* d_ws, size_t ws_size,
                              hipStream_t stream)
{
    const float* x      = (const float*)d_in[0];
    const float* enc_w1 = (const float*)d_in[1];
    const float* enc_b1 = (const float*)d_in[2];
    const float* enc_w2 = (const float*)d_in[3];
    const float* enc_b2 = (const float*)d_in[4];
    const float* enc_w3 = (const float*)d_in[5];
    const float* enc_b3 = (const float*)d_in[6];
    const float* enc_w4 = (const float*)d_in[7];
    const float* enc_b4 = (const float*)d_in[8];
    const float* cb     = (const float*)d_in[9];
    const float* dec_w1 = (const float*)d_in[10];
    const float* dec_b1 = (const float*)d_in[11];
    const float* tw1    = (const float*)d_in[12];
    const float* tb1    = (const float*)d_in[13];
    const float* tw2    = (const float*)d_in[14];
    const float* tb2    = (const float*)d_in[15];
    const float* tw3    = (const float*)d_in[16];
    const float* tb3    = (const float*)d_in[17];
    float* out = (float*)d_out;

    unsigned short* a1 = (unsigned short*)d_ws;        // 8*258*258*64
    unsigned short* a2 = a1 + 34076672;                // 8*130*130*64
    unsigned short* a3 = a2 + 8652800;                 // 8*66*66*64
    unsigned short* zH = a3 + 2230272;                 // 32768*512
    unsigned short* zL = zH + 16777216;                // 32768*512
    unsigned short* zq = zL + 16777216;                // 8*66*66*512
    unsigned short* d1 = zq + 17842176;                // 8*66*66*64
    unsigned short* wA2 = d1 + 2230272;                // 65536
    unsigned short* wA3 = wA2 + 65536;
    unsigned short* wB1 = wA3 + 65536;                 // 294912
    unsigned short* wB2 = wB1 + 294912;                // 294912
    unsigned short* wC1 = wB2 + 294912;                // 65536
    unsigned short* wC2 = wC1 + 65536;                 // 65536
    unsigned short* cbFH = wC2 + 65536;                // 262144
    unsigned short* cbFL = cbFH + 262144;              // 262144
    float* cn2 = (float*)(cbFL + 262144);              // 512
    int*   vidx = (int*)(cn2 + 512);                   // 32768
    float* candV = (float*)(vidx + 32768);             // 131072
    int*   candI = (int*)(candV + 131072);             // 131072
    float* scal = (float*)(candI + 131072);            // 2: [ssq, scoresum]

    hipMemsetAsync(scal, 0, 8, stream);

    // halos + preps
    k_halo<<<dim3(33, 8), 256, 0, stream>>>(a1, 258, 258, 64);
    k_halo<<<dim3(17, 8), 256, 0, stream>>>(a2, 130, 130, 64);
    k_halo<<<dim3(9, 8), 256, 0, stream>>>(a3, 66, 66, 64);
    k_halo<<<dim3(65, 8), 256, 0, stream>>>(zq, 66, 66, 512);
    k_halo<<<dim3(9, 8), 256, 0, stream>>>(d1, 66, 66, 64);
    k_prep<<<512, 64, 0, stream>>>(cb, cn2);
    k_prep_cb<<<1024, 256, 0, stream>>>(cb, cbFH, cbFL);
    k_prep_conv<<<256, 256, 0, stream>>>(enc_w2, wA2, 64, 64, 16, 64);
    k_prep_conv<<<256, 256, 0, stream>>>(enc_w3, wA3, 64, 64, 16, 64);
    k_prep_conv<<<1152, 256, 0, stream>>>(enc_w4, wB1, 512, 64, 9, 64);
    k_prep_conv<<<1152, 256, 0, stream>>>(dec_w1, wB2, 64, 512, 9, 128);
    k_prep_wT<<<256, 256, 0, stream>>>(tw1, wC1);
    k_prep_wT<<<256, 256, 0, stream>>>(tw2, wC2);

    // pipeline
    k_conv1<<<dim3(256, 8), 256, 0, stream>>>(x, enc_w1, enc_b1, a1);
    conv_mfma<4, 4, 2, 64, 32, 1, false, 0><<<dim3(4, 128, 8), 256, 0, stream>>>(
        a1, wA2, enc_b2, a2, 258, 258, 64, 1, 64, 1, 130, 130, 1);
    conv_mfma<4, 4, 2, 64, 32, 1, false, 0><<<dim3(2, 64, 8), 256, 0, stream>>>(
        a2, wA3, enc_b3, a3, 130, 130, 64, 1, 64, 1, 66, 66, 1);
    k_enc4<<<1024, 256, 0, stream>>>(a3, wB1, enc_b4, zH, zL, scal);
    k_vqgemm<<<1024, 256, 0, stream>>>(zH, zL, cbFH, cbFL, cn2, candV, candI);
    k_vqred<<<128, 256, 0, stream>>>(candV, candI, vidx, scal + 1);
    k_gather<<<8192, 256, 0, stream>>>(vidx, cb, zq);
    conv_mfma<3, 3, 1, 128, 64, 2, false, 0><<<dim3(1, 64, 8), 256, 0, stream>>>(
        zq, wB2, dec_b1, d1, 66, 66, 512, 4, 64, 1, 66, 66, 1);
    conv_mfma<2, 2, 1, 64, 64, 2, true, 0><<<dim3(4, 64, 8), 256, 0, stream>>>(
        d1, wC1, tb1, a2, 66, 66, 64, 1, 64, 1, 130, 130, 1);
    conv_mfma<2, 2, 1, 64, 64, 2, true, 3><<<dim3(8, 128, 8), 256, 0, stream>>>(
        a2, wC2, tb2, a1, 130, 130, 64, 1, 64, 1, 258, 258, 1);
    k_convt_final2<<<dim3(2, 129, 8), 256, 0, stream>>>(a1, tw3, tb3, out);
    k_loss_final<<<1, 64, 0, stream>>>(scal, out + 2097152);
}

// Round 8
// 501.632 us; speedup vs baseline: 4.2862x; 1.0235x over previous
//
#include <hip/hip_runtime.h>
#include <math.h>

// ---------------------------------------------------------------------------
// VQ-VAE forward, bf16-MFMA. Round 8: barrier-free vqgemm (z in K-slab
// layout, A/B direct from L2), consolidated halo+prep dispatches.
// ---------------------------------------------------------------------------

typedef __bf16 bf16x8_t __attribute__((ext_vector_type(8)));
typedef float f32x4_t __attribute__((ext_vector_type(4)));
typedef _Float16 h2_t __attribute__((ext_vector_type(2)));

union FragU { uint4 u; bf16x8_t b; };

__device__ inline f32x4_t mfma16(bf16x8_t a, bf16x8_t b, f32x4_t c) {
    return __builtin_amdgcn_mfma_f32_16x16x32_bf16(a, b, c, 0, 0, 0);
}

__device__ inline void gl_lds16(const void* g, void* l) {
    __builtin_amdgcn_global_load_lds((const __attribute__((address_space(1))) void*)g,
                                     (__attribute__((address_space(3))) void*)l, 16, 0, 0);
}

__device__ inline unsigned bf16rne(float f) {
    unsigned u = __float_as_uint(f);
    u += 0x7FFFu + ((u >> 16) & 1u);
    return u >> 16;
}
__device__ inline unsigned pack2(float lo, float hi) {
    return bf16rne(lo) | (bf16rne(hi) << 16);
}
__device__ inline unsigned pack2h(float lo, float hi) {
    union { h2_t h; unsigned u; } r;
    r.h[0] = (_Float16)lo; r.h[1] = (_Float16)hi;
    return r.u;
}
__device__ inline float bl(unsigned u) { return __uint_as_float(u << 16); }
__device__ inline float bh(unsigned u) { return __uint_as_float(u & 0xffff0000u); }
__device__ inline void split2(float x, float y, unsigned& h, unsigned& l) {
    unsigned hx = bf16rne(x), hy = bf16rne(y);
    float rx = x - __uint_as_float(hx << 16);
    float ry = y - __uint_as_float(hy << 16);
    h = hx | (hy << 16);
    l = bf16rne(rx) | (bf16rne(ry) << 16);
}

#if defined(__has_builtin)
#if __has_builtin(__builtin_amdgcn_fdot2)
#define HAS_FDOT2 1
#endif
#endif

__device__ inline float dot2h(unsigned x, unsigned w, float a) {
#ifdef HAS_FDOT2
    union { unsigned u; h2_t h; } ax, bw;
    ax.u = x; bw.u = w;
    return __builtin_amdgcn_fdot2(ax.h, bw.h, a, false);
#else
    union { unsigned u; _Float16 h[2]; } ax, bw;
    ax.u = x; bw.u = w;
    a = fmaf((float)ax.h[0], (float)bw.h[0], a);
    return fmaf((float)ax.h[1], (float)bw.h[1], a);
#endif
}
__device__ inline float dot8(uint4 x, uint4 w, float a) {
    a = dot2h(x.x, w.x, a); a = dot2h(x.y, w.y, a);
    a = dot2h(x.z, w.z, a); a = dot2h(x.w, w.w, a);
    return a;
}

// ---- generic implicit-GEMM conv -------------------------------------------
// OUTM: 0 = bf16 NHWC halo store, 3 = fp16 NHWC halo store.
template<int NR, int KW_, int SW, int CIC, int SPT, int NT, bool PHASED, int OUTM>
__global__ __launch_bounds__(256) void conv_mfma(
    const unsigned short* __restrict__ in, const unsigned short* __restrict__ wp,
    const float* __restrict__ bias, void* __restrict__ outp,
    int Hp, int Wp, int PS, int nchunks, int Cout, int ncog,
    int Hpo, int Wpo, int relu)
{
    constexpr int W_ST = SW * (SPT - 1) + KW_;
    constexpr int SLOTS_PP = CIC / 8;
    constexpr int ROW_SLOTS = W_ST * SLOTS_PP;
    constexpr int SEGS = (ROW_SLOTS + 63) / 64;
    constexpr int KT = NR * KW_;
    constexpr int CSTEPS = CIC / 32;
    __shared__ __align__(16) unsigned short sh[NR * W_ST * CIC];

    int t = threadIdx.x, lane = t & 63, wv = t >> 6;
    int bx = blockIdx.x;
    int ph = 0, pw = 0, owt = bx;
    if (PHASED) { int phs = bx & 3; ph = phs >> 1; pw = phs & 1; owt = bx >> 2; }
    int ohg = blockIdx.y;
    int bz = blockIdx.z; int nb = bz / ncog; int cog = bz % ncog;
    int ow0 = owt * SPT;
    int row0 = SW * ohg + (PHASED ? ph : 0);
    int col0 = SW * ow0 + (PHASED ? pw : 0);
    int coh = wv & 1;
    int sph = wv >> 1;
    int m = lane & 15, g = lane >> 4;

    if (PHASED) wp += (size_t)(ph * 2 + pw) * Cout * KT * CIC;

    f32x4_t acc[2][NT];
#pragma unroll
    for (int a = 0; a < 2; ++a)
#pragma unroll
        for (int u2 = 0; u2 < NT; ++u2) acc[a][u2] = (f32x4_t){0.f, 0.f, 0.f, 0.f};

    for (int ch = 0; ch < nchunks; ++ch) {
        if (ch) __syncthreads();
        for (int u_ = wv; u_ < NR * SEGS; u_ += 4) {
            int r = u_ / SEGS, seg = u_ - r * SEGS;
            int slot = seg * 64 + lane;
            int p = slot / SLOTS_PP;
            int uu = slot & (SLOTS_PP - 1);
            if (p < W_ST) {
                int su = (uu - (p & 7)) & (SLOTS_PP - 1);
                const unsigned short* gsrc = in +
                    (((size_t)nb * Hp + (row0 + r)) * Wp + (col0 + p)) * PS + ch * CIC + su * 8;
                unsigned short* ldst = sh + ((size_t)(r * ROW_SLOTS + seg * 64 + lane)) * 8;
                gl_lds16(gsrc, ldst);
            }
        }
        __syncthreads();
        int sbase = ch * (KT * CSTEPS);
#pragma unroll
        for (int tap = 0; tap < KT; ++tap) {
            const int r_l = tap / KW_, kwp = tap % KW_;
#pragma unroll
            for (int cs = 0; cs < CSTEPS; ++cs) {
                int s = sbase + tap * CSTEPS + cs;
                const uint4* wr = (const uint4*)wp + (size_t)(s * 4 + g) * Cout + cog * 64 + coh * 32 + m;
                FragU a0, a1;
                a0.u = wr[0];
                a1.u = wr[16];
#pragma unroll
                for (int u2 = 0; u2 < NT; ++u2) {
                    int sp_l = sph * (SPT / 2) + u2 * 16 + m;
                    int p = SW * sp_l + kwp;
                    int off = (cs * 32 + g * 8 + ((p & 7) << 3)) & (CIC - 1);
                    FragU bb;
                    bb.u = *(const uint4*)(sh + (size_t)(r_l * W_ST + p) * CIC + off);
                    acc[0][u2] = mfma16(a0.b, bb.b, acc[0][u2]);
                    acc[1][u2] = mfma16(a1.b, bb.b, acc[1][u2]);
                }
            }
        }
    }
#pragma unroll
    for (int a = 0; a < 2; ++a) {
        int co = cog * 64 + coh * 32 + a * 16 + g * 4;
        float4 bv = *(const float4*)(bias + co);
#pragma unroll
        for (int u2 = 0; u2 < NT; ++u2) {
            int ow = ow0 + sph * (SPT / 2) + u2 * 16 + m;
            float v0 = acc[a][u2][0] + bv.x;
            float v1 = acc[a][u2][1] + bv.y;
            float v2 = acc[a][u2][2] + bv.z;
            float v3 = acc[a][u2][3] + bv.w;
            if (relu) {
                v0 = fmaxf(v0, 0.f); v1 = fmaxf(v1, 0.f);
                v2 = fmaxf(v2, 0.f); v3 = fmaxf(v3, 0.f);
            }
            unsigned short* ob = (unsigned short*)outp;
            int oho = PHASED ? 2 * ohg + ph : ohg;
            int owo = PHASED ? 2 * ow + pw : ow;
            uint2 st;
            if constexpr (OUTM == 3) st = (uint2){pack2h(v0, v1), pack2h(v2, v3)};
            else                     st = (uint2){pack2(v0, v1), pack2(v2, v3)};
            *(uint2*)(ob + (((size_t)nb * Hpo + oho + 1) * Wpo + (owo + 1)) * 64
                      + (coh * 32 + a * 16 + g * 4)) = st;
        }
    }
}

// ---- enc4: 3x3 s1 conv 64->512 on 64x64, 128sp x 128co tiles ---------------
// Output: K-slab split layout zH/zL [s(16)][row(32768)][32] + global ssq.
__global__ __launch_bounds__(256) void k_enc4(
    const unsigned short* __restrict__ a3, const unsigned short* __restrict__ wp,
    const float* __restrict__ bias, unsigned short* __restrict__ zH,
    unsigned short* __restrict__ zL, float* __restrict__ ssqac)
{
    __shared__ __align__(16) unsigned short sh[16896];   // 4*528*8 = 33792 B = 128*132
    __shared__ float redd[4];
    int t = threadIdx.x, lane = t & 63, wv = t >> 6;
    int wc = wv & 1, wr = wv >> 1;
    int m = lane & 15, g = lane >> 4;
    int L = blockIdx.x;
    int xcd = L & 7, j = L >> 3;
    int cog = j & 3;
    int rt = (j >> 2) + xcd * 32;           // 0..255 row-tile
    int row0 = rt * 128;
    int n = row0 >> 12;
    int oh0 = (row0 & 4095) >> 6;           // even, rows oh0, oh0+1

    const unsigned short* an = a3 + ((size_t)(n * 66 + oh0) * 66) * 64;
    for (int seg = wv; seg < 33; seg += 4) {
        int slot = seg * 64 + lane;
        if (slot < 2112) {
            int r = slot / 528, rest = slot - r * 528;
            int p = rest >> 3, uu = rest & 7;
            int su = (uu - p) & 7;
            gl_lds16(an + ((size_t)(r * 66 + p)) * 64 + su * 8, sh + (size_t)slot * 8);
        }
    }
    f32x4_t acc[4][4];
#pragma unroll
    for (int a = 0; a < 4; ++a)
#pragma unroll
        for (int b = 0; b < 4; ++b) acc[a][b] = (f32x4_t){0.f, 0.f, 0.f, 0.f};
    __syncthreads();

#pragma unroll
    for (int tap = 0; tap < 9; ++tap) {
        const int kh = tap / 3, kwp = tap % 3;
#pragma unroll
        for (int cs = 0; cs < 2; ++cs) {
            int s = tap * 2 + cs;
            const uint4* wr4 = (const uint4*)wp + (size_t)(s * 4 + g) * 512 + cog * 128 + wc * 64 + m;
            FragU A[4];
#pragma unroll
            for (int ci = 0; ci < 4; ++ci) A[ci].u = wr4[ci * 16];
#pragma unroll
            for (int si = 0; si < 4; ++si) {
                int sp_l = wr * 64 + si * 16 + m;
                int r_l = (sp_l >> 6) + kh;
                int px = (sp_l & 63) + kwp;
                int off = (cs * 4 + g + px) & 7;
                FragU B;
                B.u = *(const uint4*)(sh + ((size_t)(r_l * 528 + px * 8 + off)) * 8);
#pragma unroll
                for (int ci = 0; ci < 4; ++ci)
                    acc[ci][si] = mfma16(A[ci].b, B.b, acc[ci][si]);
            }
        }
    }
    float4 bv[4];
#pragma unroll
    for (int ci = 0; ci < 4; ++ci)
        bv[ci] = *(const float4*)(bias + cog * 128 + wc * 64 + ci * 16 + g * 4);

    // ---- H pass: split-high via LDS transpose, + ssq ----------------------
    __syncthreads();
    float ssql = 0.f;
#pragma unroll
    for (int ci = 0; ci < 4; ++ci) {
#pragma unroll
        for (int si = 0; si < 4; ++si) {
            float v0 = acc[ci][si][0] + bv[ci].x;
            float v1 = acc[ci][si][1] + bv[ci].y;
            float v2 = acc[ci][si][2] + bv[ci].z;
            float v3 = acc[ci][si][3] + bv[ci].w;
            ssql += v0 * v0 + v1 * v1 + v2 * v2 + v3 * v3;
            unsigned h0, l0, h1, l1;
            split2(v0, v1, h0, l0);
            split2(v2, v3, h1, l1);
            int row = wr * 64 + si * 16 + m;
            int col = wc * 64 + ci * 16 + g * 4;
            *(uint2*)(sh + (size_t)row * 132 + col) = (uint2){h0, h1};
        }
    }
    __syncthreads();
#pragma unroll
    for (int i = 0; i < 8; ++i) {
        int idx = i * 256 + t;
        int row = idx >> 4, c16 = idx & 15;
        uint4 v = *(const uint4*)(sh + (size_t)row * 132 + c16 * 8);
        int col = cog * 128 + c16 * 8;
        int sblk = col >> 5, off = col & 31;
        *(uint4*)(zH + ((size_t)sblk * 32768 + row0 + row) * 32 + off) = v;
    }
    // ---- L pass -----------------------------------------------------------
    __syncthreads();
#pragma unroll
    for (int ci = 0; ci < 4; ++ci) {
#pragma unroll
        for (int si = 0; si < 4; ++si) {
            float v0 = acc[ci][si][0] + bv[ci].x;
            float v1 = acc[ci][si][1] + bv[ci].y;
            float v2 = acc[ci][si][2] + bv[ci].z;
            float v3 = acc[ci][si][3] + bv[ci].w;
            unsigned h0, l0, h1, l1;
            split2(v0, v1, h0, l0);
            split2(v2, v3, h1, l1);
            int row = wr * 64 + si * 16 + m;
            int col = wc * 64 + ci * 16 + g * 4;
            *(uint2*)(sh + (size_t)row * 132 + col) = (uint2){l0, l1};
        }
    }
    __syncthreads();
#pragma unroll
    for (int i = 0; i < 8; ++i) {
        int idx = i * 256 + t;
        int row = idx >> 4, c16 = idx & 15;
        uint4 v = *(const uint4*)(sh + (size_t)row * 132 + c16 * 8);
        int col = cog * 128 + c16 * 8;
        int sblk = col >> 5, off = col & 31;
        *(uint4*)(zL + ((size_t)sblk * 32768 + row0 + row) * 32 + off) = v;
    }
#pragma unroll
    for (int off = 1; off < 64; off <<= 1) ssql += __shfl_xor(ssql, off);
    if (lane == 0) redd[wv] = ssql;
    __syncthreads();
    if (t == 0) atomicAdd(ssqac, redd[0] + redd[1] + redd[2] + redd[3]);
}

// ---- all halo zeroing in one dispatch --------------------------------------
__global__ __launch_bounds__(256) void k_halo_all(
    unsigned short* a1, unsigned short* a2, unsigned short* a3,
    unsigned short* zq, unsigned short* d1)
{
    unsigned short* buf; int Hp, Wp, PS;
    switch (blockIdx.z) {
        case 0: buf = a1; Hp = 258; Wp = 258; PS = 64; break;
        case 1: buf = a2; Hp = 130; Wp = 130; PS = 64; break;
        case 2: buf = a3; Hp = 66; Wp = 66; PS = 64; break;
        case 3: buf = zq; Hp = 66; Wp = 66; PS = 512; break;
        default: buf = d1; Hp = 66; Wp = 66; PS = 64; break;
    }
    int per = 2 * Wp + 2 * (Hp - 2);
    int chunks = PS >> 3;
    int total = per * chunks;
    int n = blockIdx.y;
    for (int i = blockIdx.x * 256 + threadIdx.x; i < total; i += gridDim.x * 256) {
        int pix = i / chunks, c = i - pix * chunks;
        int h, w;
        if (pix < Wp) { h = 0; w = pix; }
        else if (pix < 2 * Wp) { h = Hp - 1; w = pix - Wp; }
        else { int q = pix - 2 * Wp; h = 1 + (q >> 1); w = (q & 1) ? (Wp - 1) : 0; }
        uint4 zz = {0, 0, 0, 0};
        *(uint4*)(buf + (((size_t)n * Hp + h) * Wp + w) * PS + c * 8) = zz;
    }
}

// ---- weight/codebook prep helpers ------------------------------------------
__device__ inline void prep_conv_dev(const float* __restrict__ w,
    unsigned short* __restrict__ o, int Cout, int Cin, int T, int CIC, int idx)
{
    if (idx >= Cout * Cin * T) return;
    int tap = idx % T; int r = idx / T; int ci = r % Cin; int co = r / Cin;
    int chunk = ci / CIC, cil = ci % CIC;
    int k = chunk * (T * CIC) + tap * CIC + cil;
    int s = k >> 5, g = (k >> 3) & 3, j = k & 7;
    o[((size_t)(s * 4 + g) * Cout + co) * 8 + j] = (unsigned short)bf16rne(w[idx]);
}

__device__ inline void prep_wT_dev(const float* __restrict__ w,
    unsigned short* __restrict__ o, int idx)
{
    if (idx >= 65536) return;
    int ci = idx & 63; int r = idx >> 6;
    int jw = r & 1; r >>= 1;
    int jh = r & 1; r >>= 1;
    int co = r & 63; r >>= 6;
    int pw = r & 1; int ph = (r >> 1) & 1;
    int kh = (1 - ph) + 2 * (1 - jh);
    int kw = (1 - pw) + 2 * (1 - jw);
    int k = (jh * 2 + jw) * 64 + ci;
    int s = k >> 5, g = (k >> 3) & 3, j = k & 7;
    o[(size_t)(ph * 2 + pw) * 16384 + ((size_t)(s * 4 + g) * 64 + co) * 8 + j] =
        (unsigned short)bf16rne(w[((ci * 64 + co) * 4 + kh) * 4 + kw]);
}

// ---- all weight/cb/cn2/scal prep in one dispatch: grid (1152, 8) -----------
__global__ __launch_bounds__(256) void k_prep_all(
    const float* __restrict__ enc_w2, const float* __restrict__ enc_w3,
    const float* __restrict__ enc_w4, const float* __restrict__ dec_w1,
    const float* __restrict__ tw1, const float* __restrict__ tw2,
    const float* __restrict__ cb,
    unsigned short* __restrict__ wA2, unsigned short* __restrict__ wA3,
    unsigned short* __restrict__ wB1, unsigned short* __restrict__ wB2,
    unsigned short* __restrict__ wC1, unsigned short* __restrict__ wC2,
    unsigned short* __restrict__ cbFH, unsigned short* __restrict__ cbFL,
    float* __restrict__ cn2, float* __restrict__ scal)
{
    int idx = blockIdx.x * 256 + threadIdx.x;
    switch (blockIdx.y) {
    case 0: prep_conv_dev(enc_w2, wA2, 64, 64, 16, 64, idx); break;
    case 1: prep_conv_dev(enc_w3, wA3, 64, 64, 16, 64, idx); break;
    case 2: prep_conv_dev(enc_w4, wB1, 512, 64, 9, 64, idx); break;
    case 3: prep_conv_dev(dec_w1, wB2, 64, 512, 9, 128, idx); break;
    case 4: prep_wT_dev(tw1, wC1, idx); break;
    case 5: prep_wT_dev(tw2, wC2, idx); break;
    case 6: {
        if (idx < 262144) {
            int c = idx & 511, k = idx >> 9;
            float v = cb[idx];
            unsigned h = bf16rne(v);
            float lo = v - __uint_as_float(h << 16);
            unsigned l = bf16rne(lo);
            int cblk = k >> 7, kl = k & 127, s = c >> 5, g = (c >> 3) & 3, j = c & 7;
            size_t off = ((((size_t)cblk * 16 + s) * 4 + g) * 128 + kl) * 8 + j;
            cbFH[off] = (unsigned short)h;
            cbFL[off] = (unsigned short)l;
        }
    } break;
    default: {
        int code = blockIdx.x * 4 + (threadIdx.x >> 6);
        if (code < 512) {
            int l = threadIdx.x & 63;
            float s = 0.f;
#pragma unroll
            for (int i = 0; i < 8; ++i) {
                float v = cb[code * 512 + l + i * 64];
                s = fmaf(v, v, s);
            }
#pragma unroll
            for (int off = 32; off > 0; off >>= 1) s += __shfl_xor(s, off);
            if (l == 0) cn2[code] = 0.5f * s;
        }
        if (blockIdx.x == 0 && threadIdx.x == 0) { scal[0] = 0.f; scal[1] = 0.f; }
    } break;
    }
}

// ---- enc conv1: Cin=1, 4x4 s2 p1, ReLU -> bf16 NHWC padded ----------------
__global__ __launch_bounds__(256) void k_conv1(const float* __restrict__ x,
    const float* __restrict__ w, const float* __restrict__ b, unsigned short* __restrict__ out)
{
    __shared__ float ws[1024];
    __shared__ float bs[64];
    int t = threadIdx.x;
#pragma unroll
    for (int i = 0; i < 4; ++i) ws[t + 256 * i] = w[t + 256 * i];
    if (t < 64) bs[t] = b[t];
    __syncthreads();
    int oh = blockIdx.x;
    int n = blockIdx.y;
    int ow = t;
    const float* xn = x + (size_t)n * 262144;
    float xv[16];
#pragma unroll
    for (int kh = 0; kh < 4; ++kh) {
        int ih = 2 * oh - 1 + kh;
        bool rok = (unsigned)ih < 512u;
        int ihc = min(max(ih, 0), 511);
#pragma unroll
        for (int kw = 0; kw < 4; ++kw) {
            int iw = 2 * ow - 1 + kw;
            bool ok = rok && ((unsigned)iw < 512u);
            int iwc = min(max(iw, 0), 511);
            float v = xn[ihc * 512 + iwc];
            xv[kh * 4 + kw] = ok ? v : 0.f;
        }
    }
    unsigned short* on = out + (((size_t)n * 258 + oh + 1) * 258 + (ow + 1)) * 64;
    unsigned uo[32];
#pragma unroll
    for (int co2 = 0; co2 < 32; ++co2) {
        float a0 = bs[2 * co2], a1 = bs[2 * co2 + 1];
#pragma unroll
        for (int q = 0; q < 16; ++q) {
            a0 = fmaf(xv[q], ws[(2 * co2) * 16 + q], a0);
            a1 = fmaf(xv[q], ws[(2 * co2 + 1) * 16 + q], a1);
        }
        uo[co2] = pack2(fmaxf(a0, 0.f), fmaxf(a1, 0.f));
    }
#pragma unroll
    for (int i = 0; i < 8; ++i) {
        uint4 st = {uo[4 * i], uo[4 * i + 1], uo[4 * i + 2], uo[4 * i + 3]};
        *(uint4*)(on + i * 8) = st;
    }
}

// ---- VQ distance GEMM: barrier-free, A and B direct from L2 ----------------
// z in K-slab layout [s][row][32]; B in fragment slabs. 128x128 per block,
// XCD swizzle groups the 4 col-blocks of a row tile on one XCD.
__global__ __launch_bounds__(256) void k_vqgemm(
    const unsigned short* __restrict__ zH, const unsigned short* __restrict__ zL,
    const unsigned short* __restrict__ cbFH, const unsigned short* __restrict__ cbFL,
    const float* __restrict__ cn2, float* __restrict__ candV, int* __restrict__ candI)
{
    __shared__ float cV[2][128];
    __shared__ int   cI[2][128];
    int t = threadIdx.x, lane = t & 63, wv = t >> 6;
    int wc = wv & 1, wr = wv >> 1;
    int m = lane & 15, g = lane >> 4;
    int L = blockIdx.x;
    int xcd = L & 7, kk = L >> 3;
    int cblk = kk & 3;
    int row0 = ((kk >> 2) + xcd * 32) * 128;

    f32x4_t acc[4][4];
#pragma unroll
    for (int a = 0; a < 4; ++a)
#pragma unroll
        for (int b = 0; b < 4; ++b) acc[a][b] = (f32x4_t){0.f, 0.f, 0.f, 0.f};

    const uint4* bH = (const uint4*)cbFH + (size_t)cblk * 8192;
    const uint4* bL = (const uint4*)cbFL + (size_t)cblk * 8192;

    for (int s = 0; s < 16; ++s) {
        const uint4* aH = (const uint4*)(zH + ((size_t)s * 32768 + row0) * 32);
        const uint4* aL = (const uint4*)(zL + ((size_t)s * 32768 + row0) * 32);
        FragU Ah[4], Al[4], Bh[4], Bl[4];
#pragma unroll
        for (int mi = 0; mi < 4; ++mi) {
            int ro = wr * 64 + mi * 16 + m;
            Ah[mi].u = aH[ro * 4 + g];
            Al[mi].u = aL[ro * 4 + g];
        }
#pragma unroll
        for (int ni = 0; ni < 4; ++ni) {
            int i4 = (s * 4 + g) * 128 + wc * 64 + ni * 16 + m;
            Bh[ni].u = bH[i4];
            Bl[ni].u = bL[i4];
        }
#pragma unroll
        for (int mi = 0; mi < 4; ++mi) {
#pragma unroll
            for (int ni = 0; ni < 4; ++ni) {
                acc[mi][ni] = mfma16(Ah[mi].b, Bh[ni].b, acc[mi][ni]);
                acc[mi][ni] = mfma16(Ah[mi].b, Bl[ni].b, acc[mi][ni]);
                acc[mi][ni] = mfma16(Al[mi].b, Bh[ni].b, acc[mi][ni]);
            }
        }
    }
    float bcn[4];
#pragma unroll
    for (int ni = 0; ni < 4; ++ni) bcn[ni] = cn2[cblk * 128 + wc * 64 + ni * 16 + m];
#pragma unroll
    for (int mi = 0; mi < 4; ++mi) {
#pragma unroll
        for (int r = 0; r < 4; ++r) {
            float best = -1e30f; int bi = 0;
#pragma unroll
            for (int ni = 0; ni < 4; ++ni) {
                float v = acc[mi][ni][r] - bcn[ni];
                int ix = cblk * 128 + wc * 64 + ni * 16 + m;
                if (v > best) { best = v; bi = ix; }
            }
#pragma unroll
            for (int off = 1; off < 16; off <<= 1) {
                float ov = __shfl_xor(best, off);
                int oi = __shfl_xor(bi, off);
                if (ov > best || (ov == best && oi < bi)) { best = ov; bi = oi; }
            }
            if (m == 0) {
                int rl = wr * 64 + mi * 16 + g * 4 + r;
                cV[wc][rl] = best;
                cI[wc][rl] = bi;
            }
        }
    }
    __syncthreads();
    if (t < 128) {
        float v0 = cV[0][t]; int i0 = cI[0][t];
        float v1 = cV[1][t]; int i1 = cI[1][t];
        if (v1 > v0 || (v1 == v0 && i1 < i0)) { v0 = v1; i0 = i1; }
        candV[(size_t)cblk * 32768 + row0 + t] = v0;
        candI[(size_t)cblk * 32768 + row0 + t] = i0;
    }
}

// ---- merge 4 candidates/row, emit idx + sum of max scores ------------------
__global__ __launch_bounds__(256) void k_vqred(const float* __restrict__ candV,
    const int* __restrict__ candI, int* __restrict__ vidx, float* __restrict__ ssum)
{
    __shared__ float redd[4];
    int t = threadIdx.x;
    int row = blockIdx.x * 256 + t;
    float b = candV[row]; int bi = candI[row];
#pragma unroll
    for (int cb = 1; cb < 4; ++cb) {
        float v = candV[cb * 32768 + row];
        int i = candI[cb * 32768 + row];
        if (v > b || (v == b && i < bi)) { b = v; bi = i; }
    }
    vidx[row] = bi;
#pragma unroll
    for (int off = 1; off < 64; off <<= 1) b += __shfl_xor(b, off);
    if ((t & 63) == 0) redd[t >> 6] = b;
    __syncthreads();
    if (t == 0) atomicAdd(ssum, redd[0] + redd[1] + redd[2] + redd[3]);
}

// ---- gather z_q -> padded NHWC bf16 [8,66,66,512] --------------------------
__global__ __launch_bounds__(256) void k_gather(const int* __restrict__ idx,
    const float* __restrict__ cb, unsigned short* __restrict__ zq)
{
    int t = threadIdx.x;
    int sp = blockIdx.x * 4 + (t >> 6);
    int lane = t & 63;
    int k = idx[sp];
    int n = sp >> 12, hw = sp & 4095, h = hw >> 6, w = hw & 63;
    const float* src = cb + (size_t)k * 512 + lane * 8;
    unsigned short* dst = zq + (((size_t)n * 66 + h + 1) * 66 + (w + 1)) * 512 + lane * 8;
    float4 v0 = *(const float4*)src, v1 = *(const float4*)(src + 4);
    uint4 st = {pack2(v0.x, v0.y), pack2(v0.z, v0.w), pack2(v1.x, v1.y), pack2(v1.z, v1.w)};
    *(uint4*)dst = st;
}

// ---- final conv-transpose 64 -> 1, sigmoid (LDS-staged, fp16 dot2) ---------
__global__ __launch_bounds__(256) void k_convt_final2(const unsigned short* __restrict__ xp,
    const float* __restrict__ w, const float* __restrict__ b, float* __restrict__ out)
{
    __shared__ __align__(16) unsigned short shx[3 * 1040 * 8];  // fp16 bits
    __shared__ __align__(16) unsigned wp[16][32];               // fp16 pairs [tap][c2]
    int t = threadIdx.x, lane = t & 63, wv = t >> 6;
    int bx = blockIdx.x, q = blockIdx.y, n = blockIdx.z;
    int colbase = bx * 128;
#pragma unroll
    for (int i = 0; i < 2; ++i) {
        int qq = t + i * 256;
        int tap = qq >> 5, c2 = qq & 31;
        wp[tap][c2] = pack2h(w[(2 * c2) * 16 + tap], w[(2 * c2 + 1) * 16 + tap]);
    }
    const unsigned short* an = xp + (size_t)n * 258 * 258 * 64;
    for (int u_ = wv; u_ < 51; u_ += 4) {
        int r = u_ / 17, seg = u_ % 17;
        int slot = seg * 64 + lane;
        if (slot < 1040) {
            int p = slot >> 3, uu = slot & 7;
            int su = (uu - p) & 7;
            int row = min(2 * q + r, 257);
            const unsigned short* gsrc = an + ((size_t)row * 258 + colbase + p) * 64 + su * 8;
            gl_lds16(gsrc, shx + ((size_t)(r * 1040 + slot)) * 8);
        }
    }
    __syncthreads();
    int ow = bx * 256 + t;
    int kwA = (ow + 1) & 1;
    int cA = ((ow + 1) >> 1) + 1 - colbase;
    int cB = cA - 1;
    float b0 = b[0];
    float acc0 = b0, acc1 = b0, acc2 = b0, acc3 = b0;
#pragma unroll
    for (int c8 = 0; c8 < 8; ++c8) {
        uint4 xr[3][2];
#pragma unroll
        for (int r = 0; r < 3; ++r) {
            xr[r][0] = *(const uint4*)(shx + (size_t)(r * 1040 + cB * 8 + ((c8 + cB) & 7)) * 8);
            xr[r][1] = *(const uint4*)(shx + (size_t)(r * 1040 + cA * 8 + ((c8 + cA) & 7)) * 8);
        }
        uint4 wA[4], wB[4];
#pragma unroll
        for (int kh = 0; kh < 4; ++kh) {
            wA[kh] = *(const uint4*)&wp[kh * 4 + kwA][c8 * 4];
            wB[kh] = *(const uint4*)&wp[kh * 4 + kwA + 2][c8 * 4];
        }
        acc0 = dot8(xr[1][1], wA[0], acc0); acc0 = dot8(xr[1][0], wB[0], acc0);
        acc0 = dot8(xr[0][1], wA[2], acc0); acc0 = dot8(xr[0][0], wB[2], acc0);
        acc1 = dot8(xr[1][1], wA[1], acc1); acc1 = dot8(xr[1][0], wB[1], acc1);
        acc1 = dot8(xr[0][1], wA[3], acc1); acc1 = dot8(xr[0][0], wB[3], acc1);
        acc2 = dot8(xr[2][1], wA[0], acc2); acc2 = dot8(xr[2][0], wB[0], acc2);
        acc2 = dot8(xr[1][1], wA[2], acc2); acc2 = dot8(xr[1][0], wB[2], acc2);
        acc3 = dot8(xr[2][1], wA[1], acc3); acc3 = dot8(xr[2][0], wB[1], acc3);
        acc3 = dot8(xr[1][1], wA[3], acc3); acc3 = dot8(xr[1][0], wB[3], acc3);
    }
    float accs[4] = {acc0, acc1, acc2, acc3};
    float* on = out + (size_t)n * 262144;
#pragma unroll
    for (int ro = 0; ro < 4; ++ro) {
        int oh = 4 * q - 1 + ro;
        if ((unsigned)oh < 512u)
            on[(size_t)oh * 512 + ow] = 1.0f / (1.0f + __expf(-accs[ro]));
    }
}

// ---- finalize loss: 1.25*(ssq - 2*scoresum)/N ------------------------------
__global__ void k_loss_final(const float* __restrict__ scal, float* __restrict__ out)
{
    if (threadIdx.x == 0 && blockIdx.x == 0)
        out[0] = 1.25f * (scal[0] - 2.f * scal[1]) * (1.0f / 16777216.0f);
}

// ---------------------------------------------------------------------------
extern "C" void kernel_launch(void* const* d_in, const int* in_sizes, int n_in,
                              void* d_out, int out_size, void* d_ws, size_t ws_size,
                              hipStream_t stream)
{
    const float* x      = (const float*)d_in[0];
    const float* enc_w1 = (const float*)d_in[1];
    const float* enc_b1 = (const float*)d_in[2];
    const float* enc_w2 = (const float*)d_in[3];
    const float* enc_b2 = (const float*)d_in[4];
    const float* enc_w3 = (const float*)d_in[5];
    const float* enc_b3 = (const float*)d_in[6];
    const float* enc_w4 = (const float*)d_in[7];
    const float* enc_b4 = (const float*)d_in[8];
    const float* cb     = (const float*)d_in[9];
    const float* dec_w1 = (const float*)d_in[10];
    const float* dec_b1 = (const float*)d_in[11];
    const float* tw1    = (const float*)d_in[12];
    const float* tb1    = (const float*)d_in[13];
    const float* tw2    = (const float*)d_in[14];
    const float* tb2    = (const float*)d_in[15];
    const float* tw3    = (const float*)d_in[16];
    const float* tb3    = (const float*)d_in[17];
    float* out = (float*)d_out;

    unsigned short* a1 = (unsigned short*)d_ws;        // 8*258*258*64
    unsigned short* a2 = a1 + 34076672;                // 8*130*130*64
    unsigned short* a3 = a2 + 8652800;                 // 8*66*66*64
    unsigned short* zH = a3 + 2230272;                 // 16*32768*32
    unsigned short* zL = zH + 16777216;                // 16*32768*32
    unsigned short* zq = zL + 16777216;                // 8*66*66*512
    unsigned short* d1 = zq + 17842176;                // 8*66*66*64
    unsigned short* wA2 = d1 + 2230272;                // 65536
    unsigned short* wA3 = wA2 + 65536;
    unsigned short* wB1 = wA3 + 65536;                 // 294912
    unsigned short* wB2 = wB1 + 294912;                // 294912
    unsigned short* wC1 = wB2 + 294912;                // 65536
    unsigned short* wC2 = wC1 + 65536;                 // 65536
    unsigned short* cbFH = wC2 + 65536;                // 262144
    unsigned short* cbFL = cbFH + 262144;              // 262144
    float* cn2 = (float*)(cbFL + 262144);              // 512
    int*   vidx = (int*)(cn2 + 512);                   // 32768
    float* candV = (float*)(vidx + 32768);             // 131072
    int*   candI = (int*)(candV + 131072);             // 131072
    float* scal = (float*)(candI + 131072);            // 2: [ssq, scoresum]

    // consolidated halos + preps (also zeroes scal)
    k_halo_all<<<dim3(65, 8, 5), 256, 0, stream>>>(a1, a2, a3, zq, d1);
    k_prep_all<<<dim3(1152, 8), 256, 0, stream>>>(
        enc_w2, enc_w3, enc_w4, dec_w1, tw1, tw2, cb,
        wA2, wA3, wB1, wB2, wC1, wC2, cbFH, cbFL, cn2, scal);

    // pipeline
    k_conv1<<<dim3(256, 8), 256, 0, stream>>>(x, enc_w1, enc_b1, a1);
    conv_mfma<4, 4, 2, 64, 32, 1, false, 0><<<dim3(4, 128, 8), 256, 0, stream>>>(
        a1, wA2, enc_b2, a2, 258, 258, 64, 1, 64, 1, 130, 130, 1);
    conv_mfma<4, 4, 2, 64, 32, 1, false, 0><<<dim3(2, 64, 8), 256, 0, stream>>>(
        a2, wA3, enc_b3, a3, 130, 130, 64, 1, 64, 1, 66, 66, 1);
    k_enc4<<<1024, 256, 0, stream>>>(a3, wB1, enc_b4, zH, zL, scal);
    k_vqgemm<<<1024, 256, 0, stream>>>(zH, zL, cbFH, cbFL, cn2, candV, candI);
    k_vqred<<<128, 256, 0, stream>>>(candV, candI, vidx, scal + 1);
    k_gather<<<8192, 256, 0, stream>>>(vidx, cb, zq);
    conv_mfma<3, 3, 1, 128, 64, 2, false, 0><<<dim3(1, 64, 8), 256, 0, stream>>>(
        zq, wB2, dec_b1, d1, 66, 66, 512, 4, 64, 1, 66, 66, 1);
    conv_mfma<2, 2, 1, 64, 64, 2, true, 0><<<dim3(4, 64, 8), 256, 0, stream>>>(
        d1, wC1, tb1, a2, 66, 66, 64, 1, 64, 1, 130, 130, 1);
    conv_mfma<2, 2, 1, 64, 64, 2, true, 3><<<dim3(8, 128, 8), 256, 0, stream>>>(
        a2, wC2, tb2, a1, 130, 130, 64, 1, 64, 1, 258, 258, 1);
    k_convt_final2<<<dim3(2, 129, 8), 256, 0, stream>>>(a1, tw3, tb3, out);
    k_loss_final<<<1, 64, 0, stream>>>(scal, out + 2097152);
}